// Round 1
// 1187.947 us; speedup vs baseline: 1.0976x; 1.0976x over previous
//
#include <hip/hip_runtime.h>
#include <cmath>

// ---------------------------------------------------------------------------
// Performer (FAVOR+) attention, fp32, MI355X.
// Algebra: ratio cancels; k-side stabilizer S applied post-hoc (exp range safe);
// q-side rowmax applied post-hoc. See derivation in session notes.
//   qph = exp(qd - diag_q)                (unstabilized)
//   U[m][e] = sum_n exp(kd - diag_k) v ;  u[m] = sum_n exp(kd - diag_k)
//   ctx'[m][e] = (e^-S U + eps sv[e]) / L ; kmean'[m] = e^-S u / L + eps
//   out = (A + eps e^{rm} Sc) / (B + eps e^{rm} Sk),
//     A = qph . ctx', B = qph . kmean', Sc = sum_m ctx', Sk = sum_m kmean'
//
// R1 changes (latency/occupancy attack):
//  - pass_q: qT/qph LDS union (44->35.7 KB -> 4 blocks/CU), ctx+PT prefetch
//  - k-side: main/tail/sv fused into ONE kernel (grid x=7) with a shared
//    35.1 KB LDS pool; kT/kp union in both main and tail paths
//  - __launch_bounds__(256,4) to pin 4 waves/SIMD
// ---------------------------------------------------------------------------

namespace {
constexpr float NORM       = 0.35355339059327379f; // 64^-0.25
constexpr float DIAG_SCALE = 0.0625f;              // 0.5 * 64^-0.5
constexpr float EPSV       = 1e-4f;
constexpr float INV_L      = 1.0f / 4096.0f;

// workspace layout (float offsets)
constexpr size_t OFF_PT  = 0;                          // PT[64][272] (normalized, zero-padded m>=266)
constexpr size_t OFF_U   = OFF_PT + (size_t)64 * 272;  // U[32][272][64]
constexpr size_t OFF_u   = OFF_U + (size_t)32 * 272 * 64; // u[32][272]
constexpr size_t OFF_SV  = OFF_u + (size_t)32 * 272;   // sv[32][64]
constexpr size_t OFF_SC  = OFF_SV + (size_t)32 * 64;   // Sc[32][64]
constexpr size_t OFF_SK  = OFF_SC + (size_t)32 * 64;   // Sk[32]
constexpr size_t OFF_S   = OFF_SK + 32;                // S (1, encoded uint)
constexpr size_t OFF_CTX = OFF_S + 4;                  // ctx_ext[32][272][68] (col64=kmean', 65..67=0)
constexpr size_t WS_FLOATS = OFF_CTX + (size_t)32 * 272 * 68;
} // namespace

__device__ __forceinline__ unsigned fenc(float f) {
  unsigned u = __float_as_uint(f);
  return (u & 0x80000000u) ? ~u : (u | 0x80000000u);
}
__device__ __forceinline__ float fdec(unsigned u) {
  return (u & 0x80000000u) ? __uint_as_float(u ^ 0x80000000u) : __uint_as_float(~u);
}

// --------------------------- K0: setup -------------------------------------
__global__ __launch_bounds__(256) void setup_kernel(const float* __restrict__ P,
                                                    float* __restrict__ ws) {
  const int t = threadIdx.x;
  const int elem = blockIdx.x * 256 + t; // < 64*272 exactly (grid 68)
  const int td = elem / 272, mm = elem % 272;
  ws[OFF_PT + (size_t)td * 272 + mm] = (mm < 266) ? NORM * P[mm * 64 + td] : 0.0f;
  if (blockIdx.x == 0 && t == 0) ((unsigned*)(ws + OFF_S))[0] = 0x007FFFFFu; // enc(-inf)
}

// --------------------------- K1: fused k-side pass ---------------------------
// grid (7, 32, 4):
//   x in [0,4)  : main k-pass, m-block = x (m in [0,256))
//   x == 4      : tail k-pass (m in [256,266))
//   x in {5,6}  : sv accumulation (nz = (x-5)*4 + z)
// Shared LDS pool carved per path; main/tail both union kT with kp -> 35.1 KB.
__global__ __launch_bounds__(256, 4) void pass_k_fused(const float* __restrict__ kg,
                                                       const float* __restrict__ vg,
                                                       float* __restrict__ ws) {
  __shared__ __align__(16) float pool[8832]; // 35328 B

  const int t = threadIdx.x;
  const int mb = blockIdx.x, bh = blockIdx.y, bz = blockIdx.z;

  if (mb >= 5) {
    // ---- sv: sv[bh][e] += sum over 512 rows of v ----
    const int nz = (mb - 5) * 4 + bz;
    const int e = t & 63, wv = t >> 6;
    const float* vp = vg + ((size_t)bh * 4096 + (size_t)nz * 512) * 64;
    float s = 0.f;
    for (int i = 0; i < 128; ++i) s += vp[(wv * 128 + i) * 64 + e];
    atomicAdd(ws + OFF_SV + bh * 64 + e, s);
    return;
  }

  float* kTp  = pool;         // kT[td][row] stride 68   (then reused as kp)
  float* vS   = pool + 4352;  // vS[row][e]  stride 68
  float* diag = pool + 8704;  // [64]
  float* redb = pool + 8768;  // [4]

  const int lane = t & 63, wv = t >> 6;
  const size_t base = ((size_t)bh * 4096 + (size_t)bz * 1024) * 64;

  if (mb == 4) {
    // =================== tail path: m in [256, 272) ===================
    const int m4 = t & 3, rg1 = t >> 2;          // GEMM1: 1 row, 4 m's
    const int eg = (t >> 2) & 15, rs = t >> 6;   // GEMM2: 4m x 4e x 4 n-quarters

    float acc2[4][4];
#pragma unroll
    for (int i = 0; i < 4; ++i) { acc2[i][0] = acc2[i][1] = acc2[i][2] = acc2[i][3] = 0.f; }
    float uacc[4] = {0, 0, 0, 0};
    float smax = -INFINITY;

    const float* ptt = ws + OFF_PT + 256 + m4 * 4;

    for (int sc = 0; sc < 16; ++sc) {
      const float* kgp = kg + base + (size_t)sc * 64 * 64;
      const float* vgp = vg + base + (size_t)sc * 64 * 64;
      __syncthreads(); // previous iter's LDS reads complete
#pragma unroll
      for (int i = 0; i < 16; ++i) {
        const int row = i * 4 + wv;
        const float kv = kgp[row * 64 + lane];
        kTp[lane * 68 + row] = kv;
        vS[row * 68 + lane] = vgp[row * 64 + lane];
        float sq = kv * kv;
#pragma unroll
        for (int o = 32; o > 0; o >>= 1) sq += __shfl_xor(sq, o);
        if (lane == 0) diag[row] = sq * DIAG_SCALE;
      }
      __syncthreads();
      // GEMM1 (reads kTp as kT) with PT prefetch
      float a1[4] = {0, 0, 0, 0};
      float4 pr = *(const float4*)(ptt);
#pragma unroll 4
      for (int td = 0; td < 64; ++td) {
        const float4 prc = pr;
        if (td < 63) pr = *(const float4*)(ptt + (size_t)(td + 1) * 272);
        const float kv = kTp[td * 68 + rg1];
        a1[0] = fmaf(kv, prc.x, a1[0]);
        a1[1] = fmaf(kv, prc.y, a1[1]);
        a1[2] = fmaf(kv, prc.z, a1[2]);
        a1[3] = fmaf(kv, prc.w, a1[3]);
      }
      // smax + exp, kept in regs
      float vals[4];
      {
        const float dg = diag[rg1];
#pragma unroll
        for (int j = 0; j < 4; ++j) {
          const int m = 256 + m4 * 4 + j;
          float e = 0.f;
          if (m < 266) {
            smax = fmaxf(smax, a1[j]);
            e = __expf(a1[j] - dg);
          }
          vals[j] = e;
        }
      }
      __syncthreads(); // all kT reads done -> safe to overwrite with kp
      {
        float4 st;
        st.x = vals[0]; st.y = vals[1]; st.z = vals[2]; st.w = vals[3];
        *(float4*)(kTp + rg1 * 20 + m4 * 4) = st; // kp[row][m_local] stride 20
      }
      __syncthreads(); // kp ready
      // GEMM2
#pragma unroll 2
      for (int nn = 0; nn < 16; ++nn) {
        const int n = rs * 16 + nn;
        const float4 kk4 = *(const float4*)(kTp + n * 20 + m4 * 4);
        const float4 vv4 = *(const float4*)(vS + n * 68 + eg * 4);
        const float kk[4] = {kk4.x, kk4.y, kk4.z, kk4.w};
        const float vv[4] = {vv4.x, vv4.y, vv4.z, vv4.w};
#pragma unroll
        for (int i = 0; i < 4; ++i)
#pragma unroll
          for (int j = 0; j < 4; ++j) acc2[i][j] = fmaf(kk[i], vv[j], acc2[i][j]);
        if (eg == 0) {
#pragma unroll
          for (int i = 0; i < 4; ++i) uacc[i] += kk[i];
        }
      }
    }
    {
      float* Ub = ws + OFF_U + ((size_t)bh * 272 + 256 + m4 * 4) * 64 + eg * 4;
#pragma unroll
      for (int i = 0; i < 4; ++i)
#pragma unroll
        for (int j = 0; j < 4; ++j) atomicAdd(Ub + (size_t)i * 64 + j, acc2[i][j]);
      if (eg == 0) {
#pragma unroll
        for (int i = 0; i < 4; ++i)
          atomicAdd(ws + OFF_u + (size_t)bh * 272 + 256 + m4 * 4 + i, uacc[i]);
      }
    }
#pragma unroll
    for (int o = 32; o > 0; o >>= 1) smax = fmaxf(smax, __shfl_xor(smax, o));
    if (lane == 0) redb[wv] = smax;
    __syncthreads();
    if (t == 0) {
      const float m = fmaxf(fmaxf(redb[0], redb[1]), fmaxf(redb[2], redb[3]));
      atomicMax((unsigned*)(ws + OFF_S), fenc(m));
    }
    return;
  }

  // =================== main path: m-block mb, m in [0,256) ===================
  const int mq = t & 15, rg = t >> 4;          // GEMM1: 16 m-quads x 16 row-groups(4)
  const int mo = t & 7, eo = (t >> 3) & 7;     // GEMM2: 8 m-octs x 8 e-octs
  const int rs = t >> 6;                       // GEMM2: n quarter (= wave id)

  float acc2[8][8];
#pragma unroll
  for (int i = 0; i < 8; ++i)
#pragma unroll
    for (int j = 0; j < 8; ++j) acc2[i][j] = 0.f;
  float uacc[8] = {0, 0, 0, 0, 0, 0, 0, 0};
  float smax = -INFINITY;

  const float* ptp = ws + OFF_PT + mb * 64 + mq * 4;

  for (int sc = 0; sc < 16; ++sc) {
    const float* kgp = kg + base + (size_t)sc * 64 * 64;
    const float* vgp = vg + base + (size_t)sc * 64 * 64;
    __syncthreads(); // previous iter's LDS reads complete
#pragma unroll
    for (int i = 0; i < 16; ++i) {
      const int row = i * 4 + wv;
      const float kv = kgp[row * 64 + lane];
      kTp[lane * 68 + row] = kv;
      vS[row * 68 + lane] = vgp[row * 64 + lane];
      float sq = kv * kv;
#pragma unroll
      for (int o = 32; o > 0; o >>= 1) sq += __shfl_xor(sq, o);
      if (lane == 0) diag[row] = sq * DIAG_SCALE;
    }
    __syncthreads();
    // GEMM1: kd[rows 4][m 4], PT prefetched one iter ahead
    float a1[4][4];
#pragma unroll
    for (int i = 0; i < 4; ++i) { a1[i][0] = a1[i][1] = a1[i][2] = a1[i][3] = 0.f; }
    float4 pr = *(const float4*)(ptp);
#pragma unroll 4
    for (int td = 0; td < 64; ++td) {
      const float4 prc = pr;
      if (td < 63) pr = *(const float4*)(ptp + (size_t)(td + 1) * 272);
      const float4 kr4 = *(const float4*)(kTp + td * 68 + rg * 4);
      const float kk[4] = {kr4.x, kr4.y, kr4.z, kr4.w};
      const float pp[4] = {prc.x, prc.y, prc.z, prc.w};
#pragma unroll
      for (int i = 0; i < 4; ++i)
#pragma unroll
        for (int j = 0; j < 4; ++j) a1[i][j] = fmaf(kk[i], pp[j], a1[i][j]);
    }
    // smax on raw kd, then exp in-place (regs)
#pragma unroll
    for (int i = 0; i < 4; ++i) {
      const float dg = diag[rg * 4 + i];
      smax = fmaxf(smax, fmaxf(fmaxf(a1[i][0], a1[i][1]), fmaxf(a1[i][2], a1[i][3])));
      a1[i][0] = __expf(a1[i][0] - dg);
      a1[i][1] = __expf(a1[i][1] - dg);
      a1[i][2] = __expf(a1[i][2] - dg);
      a1[i][3] = __expf(a1[i][3] - dg);
    }
    __syncthreads(); // all kT reads done -> safe to overwrite with kp
#pragma unroll
    for (int i = 0; i < 4; ++i) {
      float4 st;
      st.x = a1[i][0]; st.y = a1[i][1]; st.z = a1[i][2]; st.w = a1[i][3];
      *(float4*)(kTp + (rg * 4 + i) * 68 + mq * 4) = st; // kp[row][m] stride 68
    }
    __syncthreads(); // kp ready
    // GEMM2: U_partial[8m][8e] += kp^T * v over this sub-chunk (n split by wave)
#pragma unroll 2
    for (int nn = 0; nn < 16; ++nn) {
      const int n = rs * 16 + nn;
      const float4 ka = *(const float4*)(kTp + n * 68 + mo * 8);
      const float4 kb = *(const float4*)(kTp + n * 68 + mo * 8 + 4);
      const float4 va = *(const float4*)(vS + n * 68 + eo * 8);
      const float4 vb = *(const float4*)(vS + n * 68 + eo * 8 + 4);
      const float kk[8] = {ka.x, ka.y, ka.z, ka.w, kb.x, kb.y, kb.z, kb.w};
      const float vv[8] = {va.x, va.y, va.z, va.w, vb.x, vb.y, vb.z, vb.w};
#pragma unroll
      for (int i = 0; i < 8; ++i)
#pragma unroll
        for (int j = 0; j < 8; ++j) acc2[i][j] = fmaf(kk[i], vv[j], acc2[i][j]);
      if (eo == 0) {
#pragma unroll
        for (int i = 0; i < 8; ++i) uacc[i] += kk[i];
      }
    }
  }
  // writeback
  {
    float* Ub = ws + OFF_U + ((size_t)bh * 272 + mb * 64 + mo * 8) * 64 + eo * 8;
#pragma unroll
    for (int i = 0; i < 8; ++i)
#pragma unroll
      for (int j = 0; j < 8; ++j) atomicAdd(Ub + (size_t)i * 64 + j, acc2[i][j]);
    if (eo == 0) {
#pragma unroll
      for (int i = 0; i < 8; ++i)
        atomicAdd(ws + OFF_u + (size_t)bh * 272 + mb * 64 + mo * 8 + i, uacc[i]);
    }
  }
#pragma unroll
  for (int o = 32; o > 0; o >>= 1) smax = fmaxf(smax, __shfl_xor(smax, o));
  if (lane == 0) redb[wv] = smax;
  __syncthreads();
  if (t == 0) {
    const float m = fmaxf(fmaxf(redb[0], redb[1]), fmaxf(redb[2], redb[3]));
    atomicMax((unsigned*)(ws + OFF_S), fenc(m));
  }
}

// --------------------------- K3: combine -> ctx_ext, Sc, Sk -----------------
__global__ __launch_bounds__(256) void combine_kernel(float* __restrict__ ws) {
  __shared__ float red[256];
  const int t = threadIdx.x;
  const int bh = blockIdx.x;
  const float S = fdec(((unsigned*)(ws + OFF_S))[0]);
  const float es = __expf(-S);
  const int e = t & 63, mr = t >> 6;
  const float svv = ws[OFF_SV + bh * 64 + e];
  float scp = 0.f;
  for (int mm = mr; mm < 272; mm += 4) {
    float val = 0.f;
    if (mm < 266)
      val = (es * ws[OFF_U + ((size_t)bh * 272 + mm) * 64 + e] + EPSV * svv) * INV_L;
    ws[OFF_CTX + ((size_t)bh * 272 + mm) * 68 + e] = val;
    scp += val;
  }
  red[t] = scp;
  __syncthreads();
  if (t < 64) ws[OFF_SC + bh * 64 + t] = red[t] + red[t + 64] + red[t + 128] + red[t + 192];
  __syncthreads();
  float skp = 0.f;
  for (int mm = t; mm < 272; mm += 256) {
    float km = 0.f;
    if (mm < 266) km = es * ws[OFF_u + (size_t)bh * 272 + mm] * INV_L + EPSV;
    float* cx = ws + OFF_CTX + ((size_t)bh * 272 + mm) * 68;
    cx[64] = km; cx[65] = 0.f; cx[66] = 0.f; cx[67] = 0.f;
    skp += km;
  }
  red[t] = skp;
  __syncthreads();
  for (int s = 128; s > 0; s >>= 1) {
    if (t < s) red[t] += red[t + s];
    __syncthreads();
  }
  if (t == 0) ws[OFF_SK + bh] = red[0];
}

// --------------------------- K4: q-pass -> out ------------------------------
// LDS: uni[8832] = qT[64][36] during GEMM1, then qph[32][276] for GEMM2.
// 35.7 KB total -> 4 blocks/CU.
__global__ __launch_bounds__(256, 4) void pass_q(const float* __restrict__ qg,
                                                 float* __restrict__ outg,
                                                 const float* __restrict__ ws) {
  __shared__ __align__(16) float uni[8832];
  __shared__ float diag[32];
  __shared__ unsigned rmx[32];
  __shared__ float Bl[32];

  const int t = threadIdx.x;
  const int nt = blockIdx.x, bh = blockIdx.y;
  const int lane = t & 63, wv = t >> 6;
  const float* qgp = qg + ((size_t)bh * 4096 + (size_t)nt * 32) * 64;

  if (t < 32) rmx[t] = 0x007FFFFFu; // enc(-inf)

  // stage 32 rows (transposed, into uni-as-qT stride 36) + diag
#pragma unroll
  for (int i = 0; i < 8; ++i) {
    const int row = i * 4 + wv;
    const float qv = qgp[row * 64 + lane];
    uni[lane * 36 + row] = qv;
    float sq = qv * qv;
#pragma unroll
    for (int o = 32; o > 0; o >>= 1) sq += __shfl_xor(sq, o);
    if (lane == 0) diag[row] = sq * DIAG_SCALE;
  }
  __syncthreads();

  // GEMM1 main: mq = lane (64 quads, m<256); rows wv*8..wv*8+7; PT prefetched
  const int mq = t & 63;
  float a1[8][4];
#pragma unroll
  for (int i = 0; i < 8; ++i) { a1[i][0] = a1[i][1] = a1[i][2] = a1[i][3] = 0.f; }
  {
    const float* ptm = ws + OFF_PT + mq * 4;
    float4 pr = *(const float4*)(ptm);
#pragma unroll 2
    for (int td = 0; td < 64; ++td) {
      const float4 prc = pr;
      if (td < 63) pr = *(const float4*)(ptm + (size_t)(td + 1) * 272);
      const float pp[4] = {prc.x, prc.y, prc.z, prc.w};
      const float4 q0 = *(const float4*)(uni + td * 36 + wv * 8);
      const float4 q1 = *(const float4*)(uni + td * 36 + wv * 8 + 4);
      const float qq[8] = {q0.x, q0.y, q0.z, q0.w, q1.x, q1.y, q1.z, q1.w};
#pragma unroll
      for (int i = 0; i < 8; ++i)
#pragma unroll
        for (int j = 0; j < 4; ++j) a1[i][j] = fmaf(qq[i], pp[j], a1[i][j]);
    }
  }
  // GEMM1 tail: m_t = 256 + (t&15), rows (t>>4)*2 + {0,1}; PT prefetched
  float at[2] = {0.f, 0.f};
  const int mt = 256 + (t & 15);
  const int r2 = (t >> 4) * 2;
  {
    const float* ptt = ws + OFF_PT + mt;
    float pv = ptt[0];
#pragma unroll 4
    for (int td = 0; td < 64; ++td) {
      const float pvc = pv;
      if (td < 63) pv = ptt[(size_t)(td + 1) * 272];
      const float2 q2 = *(const float2*)(uni + td * 36 + r2);
      at[0] = fmaf(q2.x, pvc, at[0]);
      at[1] = fmaf(q2.y, pvc, at[1]);
    }
  }
  __syncthreads(); // all qT reads complete -> uni can be rewritten as qph

  // rowmax (raw qd): main butterfly + tail group-reduce, into LDS atomicMax
#pragma unroll
  for (int i = 0; i < 8; ++i) {
    float lm = fmaxf(fmaxf(a1[i][0], a1[i][1]), fmaxf(a1[i][2], a1[i][3]));
#pragma unroll
    for (int o = 32; o > 0; o >>= 1) lm = fmaxf(lm, __shfl_xor(lm, o));
    if (lane == i) atomicMax(&rmx[wv * 8 + i], fenc(lm));
  }
#pragma unroll
  for (int s = 0; s < 2; ++s) {
    float v = (mt < 266) ? at[s] : -INFINITY;
#pragma unroll
    for (int o = 8; o > 0; o >>= 1) v = fmaxf(v, __shfl_xor(v, o));
    if ((t & 15) == 0) atomicMax(&rmx[r2 + s], fenc(v));
  }
  // exp (unstabilized) + store qph into uni (stride 276)
#pragma unroll
  for (int i = 0; i < 8; ++i) {
    const int row = wv * 8 + i;
    const float dg = diag[row];
    float4 st;
    st.x = __expf(a1[i][0] - dg);
    st.y = __expf(a1[i][1] - dg);
    st.z = __expf(a1[i][2] - dg);
    st.w = __expf(a1[i][3] - dg);
    *(float4*)(uni + row * 276 + mq * 4) = st;
  }
#pragma unroll
  for (int s = 0; s < 2; ++s) {
    const int row = r2 + s;
    uni[row * 276 + mt] = (mt < 266) ? __expf(at[s] - diag[row]) : 0.f;
  }
  __syncthreads();

  // GEMM2: A[2 rows][4 cols] + B; ctx_ext from global (L2-resident, 74KB/head)
  // one-iteration-ahead register prefetch of the 4 ctx rows (+ kmean col)
  const int cq = t & 15, rg2 = t >> 4;
  const float* ctxg = ws + OFF_CTX + (size_t)bh * 272 * 68;
  const float* crow = ctxg + cq * 4;
  float acc[2][4] = {{0, 0, 0, 0}, {0, 0, 0, 0}};
  float accB[2] = {0.f, 0.f};
  float4 cp[4];
  float cbp[4] = {0.f, 0.f, 0.f, 0.f};
#pragma unroll
  for (int u = 0; u < 4; ++u) {
    cp[u] = *(const float4*)(crow + (size_t)u * 68);
    if (cq == 0) cbp[u] = ctxg[(size_t)u * 68 + 64];
  }
  for (int m4i = 0; m4i < 68; ++m4i) {
    const int mm = m4i * 4;
    float4 cc[4];
    float cbc[4];
#pragma unroll
    for (int u = 0; u < 4; ++u) { cc[u] = cp[u]; cbc[u] = cbp[u]; }
    if (m4i < 67) {
#pragma unroll
      for (int u = 0; u < 4; ++u) {
        cp[u] = *(const float4*)(crow + (size_t)(mm + 4 + u) * 68);
        if (cq == 0) cbp[u] = ctxg[(size_t)(mm + 4 + u) * 68 + 64];
      }
    }
    const float4 qa4 = *(const float4*)(uni + (rg2 * 2) * 276 + mm);
    const float4 qb4 = *(const float4*)(uni + (rg2 * 2 + 1) * 276 + mm);
    const float qa[4] = {qa4.x, qa4.y, qa4.z, qa4.w};
    const float qb[4] = {qb4.x, qb4.y, qb4.z, qb4.w};
#pragma unroll
    for (int u4 = 0; u4 < 4; ++u4) {
      acc[0][0] = fmaf(qa[u4], cc[u4].x, acc[0][0]);
      acc[0][1] = fmaf(qa[u4], cc[u4].y, acc[0][1]);
      acc[0][2] = fmaf(qa[u4], cc[u4].z, acc[0][2]);
      acc[0][3] = fmaf(qa[u4], cc[u4].w, acc[0][3]);
      acc[1][0] = fmaf(qb[u4], cc[u4].x, acc[1][0]);
      acc[1][1] = fmaf(qb[u4], cc[u4].y, acc[1][1]);
      acc[1][2] = fmaf(qb[u4], cc[u4].z, acc[1][2]);
      acc[1][3] = fmaf(qb[u4], cc[u4].w, acc[1][3]);
    }
    if (cq == 0) {
#pragma unroll
      for (int u4 = 0; u4 < 4; ++u4) {
        accB[0] = fmaf(qa[u4], cbc[u4], accB[0]);
        accB[1] = fmaf(qb[u4], cbc[u4], accB[1]);
      }
    }
  }
  if (cq == 0) {
    Bl[rg2 * 2] = accB[0];
    Bl[rg2 * 2 + 1] = accB[1];
  }
  __syncthreads();

  const float4 sc4 = *(const float4*)(ws + OFF_SC + bh * 64 + cq * 4);
  const float skv = ws[OFF_SK + bh];
  float* op = outg + ((size_t)bh * 4096 + (size_t)nt * 32) * 64;
#pragma unroll
  for (int i = 0; i < 2; ++i) {
    const int row = rg2 * 2 + i;
    const float rm = fdec(rmx[row]);
    const float tt = EPSV * __expf(rm);
    const float inv = 1.0f / (Bl[row] + tt * skv);
    float4 o;
    o.x = (acc[i][0] + tt * sc4.x) * inv;
    o.y = (acc[i][1] + tt * sc4.y) * inv;
    o.z = (acc[i][2] + tt * sc4.z) * inv;
    o.w = (acc[i][3] + tt * sc4.w) * inv;
    *(float4*)(op + row * 64 + cq * 4) = o;
  }
}

// --------------------------- launch -----------------------------------------
extern "C" void kernel_launch(void* const* d_in, const int* in_sizes, int n_in,
                              void* d_out, int out_size, void* d_ws, size_t ws_size,
                              hipStream_t stream) {
  (void)in_sizes; (void)n_in; (void)out_size; (void)ws_size;
  const float* q = (const float*)d_in[0];
  const float* k = (const float*)d_in[1];
  const float* v = (const float*)d_in[2];
  const float* P = (const float*)d_in[3];
  float* out = (float*)d_out;
  float* ws = (float*)d_ws;

  hipMemsetAsync(d_ws, 0, WS_FLOATS * sizeof(float), stream);
  setup_kernel<<<68, 256, 0, stream>>>(P, ws);
  pass_k_fused<<<dim3(7, 32, 4), 256, 0, stream>>>(k, v, ws);
  combine_kernel<<<32, 256, 0, stream>>>(ws);
  pass_q<<<dim3(128, 32), 256, 0, stream>>>(q, out, ws);
}

// Round 2
// 752.964 us; speedup vs baseline: 1.7317x; 1.5777x over previous
//
#include <hip/hip_runtime.h>
#include <cmath>

// ---------------------------------------------------------------------------
// Performer (FAVOR+) attention, fp32, MI355X.
// Algebra: ratio cancels; k-side stabilizer S applied post-hoc (exp range safe);
// q-side rowmax applied post-hoc.
//   qph = exp(qd - diag_q)                (unstabilized)
//   U[m][e] = sum_n exp(kd - diag_k) v ;  u[m] = sum_n exp(kd - diag_k)
//   ctx'[m][e] = (e^-S U + eps sv[e]) / L ; kmean'[m] = e^-S u / L + eps
//   out = (A + eps e^{rm} Sc) / (B + eps e^{rm} Sk)
//
// R2 changes (latency attack on pass_k_fused + pass_q):
//  - k-side: z-split 4->8 (1024 main blocks -> 3/CU), PT staged in LDS once,
//    all staging via global_load_lds (no transpose, no shuffle-diag: diag
//    accumulated as k^2 inside GEMM1), 4-wave U-fold in LDS before atomics
//    (16K -> 4K atomics/block).
//  - pass_q: GLDS q staging, diag-in-registers, GEMM1 with 2-buffer PT ring
//    (8 PT rows in flight), GEMM2 ctx ring-2.
// ---------------------------------------------------------------------------

namespace {
constexpr float NORM       = 0.35355339059327379f; // 64^-0.25
constexpr float DIAG_SCALE = 0.0625f;              // 0.5 * 64^-0.5
constexpr float EPSV       = 1e-4f;
constexpr float INV_L      = 1.0f / 4096.0f;

// workspace layout (float offsets)
constexpr size_t OFF_PT  = 0;                          // PT[64][272]
constexpr size_t OFF_U   = OFF_PT + (size_t)64 * 272;  // U[32][272][64]
constexpr size_t OFF_u   = OFF_U + (size_t)32 * 272 * 64; // u[32][272]
constexpr size_t OFF_SV  = OFF_u + (size_t)32 * 272;   // sv[32][64]
constexpr size_t OFF_SC  = OFF_SV + (size_t)32 * 64;   // Sc[32][64]
constexpr size_t OFF_SK  = OFF_SC + (size_t)32 * 64;   // Sk[32]
constexpr size_t OFF_S   = OFF_SK + 32;                // S (1, encoded uint)
constexpr size_t OFF_CTX = OFF_S + 4;                  // ctx_ext[32][272][68]
constexpr size_t WS_FLOATS = OFF_CTX + (size_t)32 * 272 * 68;
} // namespace

__device__ __forceinline__ unsigned fenc(float f) {
  unsigned u = __float_as_uint(f);
  return (u & 0x80000000u) ? ~u : (u | 0x80000000u);
}
__device__ __forceinline__ float fdec(unsigned u) {
  return (u & 0x80000000u) ? __uint_as_float(u ^ 0x80000000u) : __uint_as_float(~u);
}

// async global->LDS: per-lane global src, wave-uniform LDS base (+lane*size)
__device__ __forceinline__ void glds4(const float* g, float* l) {
  __builtin_amdgcn_global_load_lds((const __attribute__((address_space(1))) void*)g,
                                   (__attribute__((address_space(3))) void*)l, 4, 0, 0);
}
__device__ __forceinline__ void glds16(const float* g, float* l) {
  __builtin_amdgcn_global_load_lds((const __attribute__((address_space(1))) void*)g,
                                   (__attribute__((address_space(3))) void*)l, 16, 0, 0);
}

// --------------------------- K0: setup -------------------------------------
__global__ __launch_bounds__(256) void setup_kernel(const float* __restrict__ P,
                                                    float* __restrict__ ws) {
  const int t = threadIdx.x;
  const int elem = blockIdx.x * 256 + t; // < 64*272 exactly (grid 68)
  const int td = elem / 272, mm = elem % 272;
  ws[OFF_PT + (size_t)td * 272 + mm] = (mm < 266) ? NORM * P[mm * 64 + td] : 0.0f;
  if (blockIdx.x == 0 && t == 0) ((unsigned*)(ws + OFF_S))[0] = 0x007FFFFFu; // enc(-inf)
}

// --------------------------- K1: fused k-side pass ---------------------------
// grid (7, 32, 8):
//   x in [0,4)  : main k-pass, m-block = x (m in [0,256)), 512 rows per z
//   x == 4      : tail k-pass (m in [256,266)), 512 rows per z
//   x in {5,6}  : sv accumulation, 256 rows per (x,z)
__global__ __launch_bounds__(256, 3) void pass_k_fused(const float* __restrict__ kg,
                                                       const float* __restrict__ vg,
                                                       float* __restrict__ ws) {
  __shared__ __align__(16) float pool[12544]; // PTs[4096] | kS[64][68] | vS[64][64]
  __shared__ float redb[4];

  const int t = threadIdx.x;
  const int mb = blockIdx.x, bh = blockIdx.y, bz = blockIdx.z;
  const int lane = t & 63, wv = t >> 6;

  if (mb >= 5) {
    // ---- sv: sv[bh][e] += sum over 256 rows of v ----
    const int nz = (mb - 5) * 8 + bz;
    const float* vp = vg + ((size_t)bh * 4096 + (size_t)nz * 256) * 64;
    float s = 0.f;
    for (int i = 0; i < 64; ++i) s += vp[(wv * 64 + i) * 64 + lane];
    atomicAdd(ws + OFF_SV + bh * 64 + lane, s);
    return;
  }

  float* PTs = pool;          // main: PT tile [td 64][m 64]; tail: PT_t[td 64][16]
  float* kS  = pool + 4096;   // k rows [row 64][d] stride 68; reused as kp
  float* vS  = pool + 8448;   // v rows [row 64][e 64] stride 64

  const size_t base = ((size_t)bh * 4096 + (size_t)bz * 512) * 64;

  if (mb == 4) {
    // =================== tail path: m in [256, 272) ===================
    const int m4 = t & 3, rg1 = t >> 2;          // GEMM1: 1 row, 4 m's
    const int eg = (t >> 2) & 15, rs = t >> 6;   // GEMM2: 4m x 4e x 4 n-quarters

    // stage PT_t[64][16] once
    {
      const int td = t >> 2, m4i = t & 3;
      *(float4*)(PTs + td * 16 + m4i * 4) =
          *(const float4*)(ws + OFF_PT + (size_t)td * 272 + 256 + m4i * 4);
    }

    float acc2[4][4];
#pragma unroll
    for (int i = 0; i < 4; ++i) { acc2[i][0] = acc2[i][1] = acc2[i][2] = acc2[i][3] = 0.f; }
    float uacc[4] = {0, 0, 0, 0};
    float smax = -INFINITY;

    for (int sc = 0; sc < 8; ++sc) {
      const float* kgp = kg + base + (size_t)sc * 64 * 64;
      const float* vgp = vg + base + (size_t)sc * 64 * 64;
      __syncthreads(); // previous iter's LDS reads complete
      {
        const int r0 = wv * 16;
#pragma unroll
        for (int r = 0; r < 16; ++r) glds4(kgp + (r0 + r) * 64 + lane, kS + (r0 + r) * 68);
#pragma unroll
        for (int r4 = 0; r4 < 4; ++r4)
          glds16(vgp + (r0 + r4 * 4) * 64 + lane * 4, vS + (r0 + r4 * 4) * 64);
      }
      __syncthreads(); // staged
      // GEMM1: row rg1, m-quad m4; diag accumulated as k^2
      float a1[4] = {0, 0, 0, 0};
      float sqt = 0.f;
#pragma unroll
      for (int tb = 0; tb < 16; ++tb) {
        const int td = tb * 4;
        const float4 kv4 = *(const float4*)(kS + rg1 * 68 + td);
        float4 pt4[4];
#pragma unroll
        for (int u = 0; u < 4; ++u) pt4[u] = *(const float4*)(PTs + (td + u) * 16 + m4 * 4);
        const float kk[4] = {kv4.x, kv4.y, kv4.z, kv4.w};
#pragma unroll
        for (int u = 0; u < 4; ++u) {
          sqt = fmaf(kk[u], kk[u], sqt);
          const float* pu = (const float*)&pt4[u];
          a1[0] = fmaf(kk[u], pu[0], a1[0]);
          a1[1] = fmaf(kk[u], pu[1], a1[1]);
          a1[2] = fmaf(kk[u], pu[2], a1[2]);
          a1[3] = fmaf(kk[u], pu[3], a1[3]);
        }
      }
      float vals[4];
      {
        const float dg = sqt * DIAG_SCALE;
#pragma unroll
        for (int j = 0; j < 4; ++j) {
          const int m = 256 + m4 * 4 + j;
          float e = 0.f;
          if (m < 266) {
            smax = fmaxf(smax, a1[j]);
            e = __expf(a1[j] - dg);
          }
          vals[j] = e;
        }
      }
      __syncthreads(); // all kS reads done -> overwrite with kp (stride 20)
      {
        float4 st;
        st.x = vals[0]; st.y = vals[1]; st.z = vals[2]; st.w = vals[3];
        *(float4*)(kS + rg1 * 20 + m4 * 4) = st;
      }
      __syncthreads(); // kp ready
#pragma unroll 2
      for (int nn = 0; nn < 16; ++nn) {
        const int n = rs * 16 + nn;
        const float4 kk4 = *(const float4*)(kS + n * 20 + m4 * 4);
        const float4 vv4 = *(const float4*)(vS + n * 64 + eg * 4);
        const float kk[4] = {kk4.x, kk4.y, kk4.z, kk4.w};
        const float vv[4] = {vv4.x, vv4.y, vv4.z, vv4.w};
#pragma unroll
        for (int i = 0; i < 4; ++i)
#pragma unroll
          for (int j = 0; j < 4; ++j) acc2[i][j] = fmaf(kk[i], vv[j], acc2[i][j]);
        if (eg == 0) {
#pragma unroll
          for (int i = 0; i < 4; ++i) uacc[i] += kk[i];
        }
      }
    }
    {
      float* Ub = ws + OFF_U + ((size_t)bh * 272 + 256 + m4 * 4) * 64 + eg * 4;
#pragma unroll
      for (int i = 0; i < 4; ++i)
#pragma unroll
        for (int j = 0; j < 4; ++j) atomicAdd(Ub + (size_t)i * 64 + j, acc2[i][j]);
      if (eg == 0) {
#pragma unroll
        for (int i = 0; i < 4; ++i)
          atomicAdd(ws + OFF_u + (size_t)bh * 272 + 256 + m4 * 4 + i, uacc[i]);
      }
    }
#pragma unroll
    for (int o = 32; o > 0; o >>= 1) smax = fmaxf(smax, __shfl_xor(smax, o));
    if (lane == 0) redb[wv] = smax;
    __syncthreads();
    if (t == 0) {
      const float m = fmaxf(fmaxf(redb[0], redb[1]), fmaxf(redb[2], redb[3]));
      atomicMax((unsigned*)(ws + OFF_S), fenc(m));
    }
    return;
  }

  // =================== main path: m-block mb, m in [0,256) ===================
  const int mq = t & 15, rg = t >> 4;          // GEMM1: 16 m-quads x 16 row-groups(4)
  const int mo = t & 7, eo = (t >> 3) & 7;     // GEMM2: 8 m-octs x 8 e-octs
  const int rs = t >> 6;                       // GEMM2: n quarter (= wave id)

  // stage PTs[td 64][m 64] once (invariant over sc)
#pragma unroll
  for (int c = 0; c < 4; ++c) {
    const int f4 = c * 256 + t;
    const int td = f4 >> 4, mi = f4 & 15;
    *(float4*)(PTs + td * 64 + mi * 4) =
        *(const float4*)(ws + OFF_PT + (size_t)td * 272 + mb * 64 + mi * 4);
  }

  float acc2[8][8];
#pragma unroll
  for (int i = 0; i < 8; ++i)
#pragma unroll
    for (int j = 0; j < 8; ++j) acc2[i][j] = 0.f;
  float uacc[8] = {0, 0, 0, 0, 0, 0, 0, 0};
  float smax = -INFINITY;

  for (int sc = 0; sc < 8; ++sc) {
    const float* kgp = kg + base + (size_t)sc * 64 * 64;
    const float* vgp = vg + base + (size_t)sc * 64 * 64;
    __syncthreads(); // previous iter's LDS reads complete (also covers PTs staging)
    {
      const int r0 = wv * 16;
#pragma unroll
      for (int r = 0; r < 16; ++r) glds4(kgp + (r0 + r) * 64 + lane, kS + (r0 + r) * 68);
#pragma unroll
      for (int r4 = 0; r4 < 4; ++r4)
        glds16(vgp + (r0 + r4 * 4) * 64 + lane * 4, vS + (r0 + r4 * 4) * 64);
    }
    __syncthreads(); // staged (vmcnt drained by barrier)

    // GEMM1: kd[rows 4][m 4]; diag accumulated as k^2 in-loop
    float a1[4][4];
#pragma unroll
    for (int i = 0; i < 4; ++i) { a1[i][0] = a1[i][1] = a1[i][2] = a1[i][3] = 0.f; }
    float sq[4] = {0, 0, 0, 0};
#pragma unroll
    for (int tb = 0; tb < 16; ++tb) {
      const int td = tb * 4;
      float4 kr[4];
      float4 pp[4];
#pragma unroll
      for (int i = 0; i < 4; ++i) kr[i] = *(const float4*)(kS + (rg * 4 + i) * 68 + td);
#pragma unroll
      for (int u = 0; u < 4; ++u) pp[u] = *(const float4*)(PTs + (td + u) * 64 + mq * 4);
#pragma unroll
      for (int u = 0; u < 4; ++u) {
        const float* pu = (const float*)&pp[u];
#pragma unroll
        for (int i = 0; i < 4; ++i) {
          const float kv = ((const float*)&kr[i])[u];
          sq[i] = fmaf(kv, kv, sq[i]);
#pragma unroll
          for (int j = 0; j < 4; ++j) a1[i][j] = fmaf(kv, pu[j], a1[i][j]);
        }
      }
    }
    // smax on raw kd, then exp in-place
#pragma unroll
    for (int i = 0; i < 4; ++i) {
      const float dg = sq[i] * DIAG_SCALE;
      smax = fmaxf(smax, fmaxf(fmaxf(a1[i][0], a1[i][1]), fmaxf(a1[i][2], a1[i][3])));
      a1[i][0] = __expf(a1[i][0] - dg);
      a1[i][1] = __expf(a1[i][1] - dg);
      a1[i][2] = __expf(a1[i][2] - dg);
      a1[i][3] = __expf(a1[i][3] - dg);
    }
    __syncthreads(); // all kS reads done -> overwrite with kp
#pragma unroll
    for (int i = 0; i < 4; ++i) {
      float4 st;
      st.x = a1[i][0]; st.y = a1[i][1]; st.z = a1[i][2]; st.w = a1[i][3];
      *(float4*)(kS + (rg * 4 + i) * 68 + mq * 4) = st; // kp[row][m] stride 68
    }
    __syncthreads(); // kp ready
    // GEMM2: U_partial[8m][8e] += kp^T * v (n split by wave)
#pragma unroll 2
    for (int nn = 0; nn < 16; ++nn) {
      const int n = rs * 16 + nn;
      const float4 ka = *(const float4*)(kS + n * 68 + mo * 8);
      const float4 kb = *(const float4*)(kS + n * 68 + mo * 8 + 4);
      const float4 va = *(const float4*)(vS + n * 64 + eo * 8);
      const float4 vb = *(const float4*)(vS + n * 64 + eo * 8 + 4);
      const float kk[8] = {ka.x, ka.y, ka.z, ka.w, kb.x, kb.y, kb.z, kb.w};
      const float vv[8] = {va.x, va.y, va.z, va.w, vb.x, vb.y, vb.z, vb.w};
#pragma unroll
      for (int i = 0; i < 8; ++i)
#pragma unroll
        for (int j = 0; j < 8; ++j) acc2[i][j] = fmaf(kk[i], vv[j], acc2[i][j]);
      if (eo == 0) {
#pragma unroll
        for (int i = 0; i < 8; ++i) uacc[i] += kk[i];
      }
    }
  }

  // ---- epilogue: fold 4 waves' acc2 in LDS, then spread atomics ----
  __syncthreads(); // all GEMM2 reads done; kS/vS/PTs free as scratch
  {
    float* A = kS;  // col-major [idx 64][lane 64]
    float* B = PTs; // col-major [idx 64][lane 64]
    if (wv == 1) {
#pragma unroll
      for (int i = 0; i < 8; ++i)
#pragma unroll
        for (int j = 0; j < 8; ++j) A[(i * 8 + j) * 64 + lane] = acc2[i][j];
    }
    if (wv == 3) {
#pragma unroll
      for (int i = 0; i < 8; ++i)
#pragma unroll
        for (int j = 0; j < 8; ++j) B[(i * 8 + j) * 64 + lane] = acc2[i][j];
    }
    __syncthreads();
    if (wv == 0) {
#pragma unroll
      for (int i = 0; i < 8; ++i)
#pragma unroll
        for (int j = 0; j < 8; ++j) acc2[i][j] += A[(i * 8 + j) * 64 + lane];
    }
    if (wv == 2) {
#pragma unroll
      for (int i = 0; i < 8; ++i)
#pragma unroll
        for (int j = 0; j < 8; ++j) acc2[i][j] += B[(i * 8 + j) * 64 + lane];
    }
    __syncthreads();
    if (wv == 2) {
#pragma unroll
      for (int i = 0; i < 8; ++i)
#pragma unroll
        for (int j = 0; j < 8; ++j) A[(i * 8 + j) * 64 + lane] = acc2[i][j];
    }
    __syncthreads();
    if (wv == 0) {
#pragma unroll
      for (int i = 0; i < 8; ++i)
#pragma unroll
        for (int j = 0; j < 8; ++j) {
          acc2[i][j] += A[(i * 8 + j) * 64 + lane];
          A[(i * 8 + j) * 64 + lane] = acc2[i][j];
        }
    }
    __syncthreads();
    // spread atomics: 16 per thread, 4096 per block
    {
      const int l = t & 63, idxb = (t >> 6) * 16;
      float* Ub = ws + OFF_U + ((size_t)bh * 272 + mb * 64) * 64;
#pragma unroll
      for (int c = 0; c < 16; ++c) {
        const int idx = idxb + c;
        const int ml = (l & 7) * 8 + (idx >> 3);
        const int e  = (l >> 3) * 8 + (idx & 7);
        atomicAdd(Ub + (size_t)ml * 64 + e, A[idx * 64 + l]);
      }
    }
    if (eo == 0) {
#pragma unroll
      for (int i = 0; i < 8; ++i)
        atomicAdd(ws + OFF_u + (size_t)bh * 272 + mb * 64 + mo * 8 + i, uacc[i]);
    }
  }
#pragma unroll
  for (int o = 32; o > 0; o >>= 1) smax = fmaxf(smax, __shfl_xor(smax, o));
  if (lane == 0) redb[wv] = smax;
  __syncthreads();
  if (t == 0) {
    const float m = fmaxf(fmaxf(redb[0], redb[1]), fmaxf(redb[2], redb[3]));
    atomicMax((unsigned*)(ws + OFF_S), fenc(m));
  }
}

// --------------------------- K3: combine -> ctx_ext, Sc, Sk -----------------
__global__ __launch_bounds__(256) void combine_kernel(float* __restrict__ ws) {
  __shared__ float red[256];
  const int t = threadIdx.x;
  const int bh = blockIdx.x;
  const float S = fdec(((unsigned*)(ws + OFF_S))[0]);
  const float es = __expf(-S);
  const int e = t & 63, mr = t >> 6;
  const float svv = ws[OFF_SV + bh * 64 + e];
  float scp = 0.f;
  for (int mm = mr; mm < 272; mm += 4) {
    float val = 0.f;
    if (mm < 266)
      val = (es * ws[OFF_U + ((size_t)bh * 272 + mm) * 64 + e] + EPSV * svv) * INV_L;
    ws[OFF_CTX + ((size_t)bh * 272 + mm) * 68 + e] = val;
    scp += val;
  }
  red[t] = scp;
  __syncthreads();
  if (t < 64) ws[OFF_SC + bh * 64 + t] = red[t] + red[t + 64] + red[t + 128] + red[t + 192];
  __syncthreads();
  float skp = 0.f;
  for (int mm = t; mm < 272; mm += 256) {
    float km = 0.f;
    if (mm < 266) km = es * ws[OFF_u + (size_t)bh * 272 + mm] * INV_L + EPSV;
    float* cx = ws + OFF_CTX + ((size_t)bh * 272 + mm) * 68;
    cx[64] = km; cx[65] = 0.f; cx[66] = 0.f; cx[67] = 0.f;
    skp += km;
  }
  red[t] = skp;
  __syncthreads();
  for (int s = 128; s > 0; s >>= 1) {
    if (t < s) red[t] += red[t + s];
    __syncthreads();
  }
  if (t == 0) ws[OFF_SK + bh] = red[0];
}

// --------------------------- K4: q-pass -> out ------------------------------
// LDS: uni = qS[32][68] during GEMM1 (GLDS-staged), then qph[32][276].
__global__ __launch_bounds__(256, 4) void pass_q(const float* __restrict__ qg,
                                                 float* __restrict__ outg,
                                                 const float* __restrict__ ws) {
  __shared__ __align__(16) float uni[8832];
  __shared__ unsigned rmx[32];
  __shared__ float Bl[32];

  const int t = threadIdx.x;
  const int nt = blockIdx.x, bh = blockIdx.y;
  const int lane = t & 63, wv = t >> 6;
  const float* qgp = qg + ((size_t)bh * 4096 + (size_t)nt * 32) * 64;

  if (t < 32) rmx[t] = 0x007FFFFFu; // enc(-inf)

  // stage qS[32][68] via GLDS (rows wv*8..wv*8+7)
#pragma unroll
  for (int r = 0; r < 8; ++r)
    glds4(qgp + (wv * 8 + r) * 64 + lane, uni + (wv * 8 + r) * 68);
  __syncthreads();

  // GEMM1 main: mq = lane (64 m-quads, m<256); rows wv*8..+7; PT ring-2 (8 rows)
  const int mq = t & 63;
  float a1[8][4];
  float sq[8] = {0, 0, 0, 0, 0, 0, 0, 0};
#pragma unroll
  for (int i = 0; i < 8; ++i) { a1[i][0] = a1[i][1] = a1[i][2] = a1[i][3] = 0.f; }
  {
    const float* ptm = ws + OFF_PT + mq * 4;
    float4 pfA[4], pfB[4];
#pragma unroll
    for (int u = 0; u < 4; ++u) {
      pfA[u] = *(const float4*)(ptm + (size_t)u * 272);
      pfB[u] = *(const float4*)(ptm + (size_t)(4 + u) * 272);
    }
#pragma unroll
    for (int tb = 0; tb < 16; tb += 2) {
      {
        const int td = tb * 4;
#pragma unroll
        for (int i = 0; i < 8; ++i) {
          const float4 q4 = *(const float4*)(uni + (wv * 8 + i) * 68 + td);
          const float qv[4] = {q4.x, q4.y, q4.z, q4.w};
#pragma unroll
          for (int u = 0; u < 4; ++u) {
            sq[i] = fmaf(qv[u], qv[u], sq[i]);
            const float* pu = (const float*)&pfA[u];
#pragma unroll
            for (int j = 0; j < 4; ++j) a1[i][j] = fmaf(qv[u], pu[j], a1[i][j]);
          }
        }
        if (tb < 14) {
#pragma unroll
          for (int u = 0; u < 4; ++u) pfA[u] = *(const float4*)(ptm + (size_t)(td + 8 + u) * 272);
        }
      }
      {
        const int td = tb * 4 + 4;
#pragma unroll
        for (int i = 0; i < 8; ++i) {
          const float4 q4 = *(const float4*)(uni + (wv * 8 + i) * 68 + td);
          const float qv[4] = {q4.x, q4.y, q4.z, q4.w};
#pragma unroll
          for (int u = 0; u < 4; ++u) {
            sq[i] = fmaf(qv[u], qv[u], sq[i]);
            const float* pu = (const float*)&pfB[u];
#pragma unroll
            for (int j = 0; j < 4; ++j) a1[i][j] = fmaf(qv[u], pu[j], a1[i][j]);
          }
        }
        if (tb < 14) {
#pragma unroll
          for (int u = 0; u < 4; ++u) pfB[u] = *(const float4*)(ptm + (size_t)(td + 8 + u) * 272);
        }
      }
    }
  }
  // GEMM1 tail: m_t = 256 + (t&15), rows r2, r2+1; ring-2 scalar
  float at[2] = {0.f, 0.f};
  float sqt[2] = {0.f, 0.f};
  const int mt = 256 + (t & 15);
  const int r2 = (t >> 4) * 2;
  {
    const float* ptt = ws + OFF_PT + mt;
    float ptA[4], ptB[4];
#pragma unroll
    for (int u = 0; u < 4; ++u) {
      ptA[u] = ptt[(size_t)u * 272];
      ptB[u] = ptt[(size_t)(4 + u) * 272];
    }
#pragma unroll
    for (int tb = 0; tb < 16; tb += 2) {
      {
        const int td = tb * 4;
        const float4 qx4 = *(const float4*)(uni + r2 * 68 + td);
        const float4 qy4 = *(const float4*)(uni + (r2 + 1) * 68 + td);
        const float qx[4] = {qx4.x, qx4.y, qx4.z, qx4.w};
        const float qy[4] = {qy4.x, qy4.y, qy4.z, qy4.w};
#pragma unroll
        for (int u = 0; u < 4; ++u) {
          sqt[0] = fmaf(qx[u], qx[u], sqt[0]);
          sqt[1] = fmaf(qy[u], qy[u], sqt[1]);
          at[0] = fmaf(qx[u], ptA[u], at[0]);
          at[1] = fmaf(qy[u], ptA[u], at[1]);
        }
        if (tb < 14) {
#pragma unroll
          for (int u = 0; u < 4; ++u) ptA[u] = ptt[(size_t)(td + 8 + u) * 272];
        }
      }
      {
        const int td = tb * 4 + 4;
        const float4 qx4 = *(const float4*)(uni + r2 * 68 + td);
        const float4 qy4 = *(const float4*)(uni + (r2 + 1) * 68 + td);
        const float qx[4] = {qx4.x, qx4.y, qx4.z, qx4.w};
        const float qy[4] = {qy4.x, qy4.y, qy4.z, qy4.w};
#pragma unroll
        for (int u = 0; u < 4; ++u) {
          sqt[0] = fmaf(qx[u], qx[u], sqt[0]);
          sqt[1] = fmaf(qy[u], qy[u], sqt[1]);
          at[0] = fmaf(qx[u], ptB[u], at[0]);
          at[1] = fmaf(qy[u], ptB[u], at[1]);
        }
        if (tb < 14) {
#pragma unroll
          for (int u = 0; u < 4; ++u) ptB[u] = ptt[(size_t)(td + 8 + u) * 272];
        }
      }
    }
  }
  __syncthreads(); // all qS reads complete -> uni can be rewritten as qph

  // rowmax (raw qd): main butterfly + tail group-reduce, into LDS atomicMax
#pragma unroll
  for (int i = 0; i < 8; ++i) {
    float lm = fmaxf(fmaxf(a1[i][0], a1[i][1]), fmaxf(a1[i][2], a1[i][3]));
#pragma unroll
    for (int o = 32; o > 0; o >>= 1) lm = fmaxf(lm, __shfl_xor(lm, o));
    if (lane == i) atomicMax(&rmx[wv * 8 + i], fenc(lm));
  }
#pragma unroll
  for (int s = 0; s < 2; ++s) {
    float v = (mt < 266) ? at[s] : -INFINITY;
#pragma unroll
    for (int o = 8; o > 0; o >>= 1) v = fmaxf(v, __shfl_xor(v, o));
    if ((t & 15) == 0) atomicMax(&rmx[r2 + s], fenc(v));
  }
  // exp (unstabilized, diag from registers) + store qph
#pragma unroll
  for (int i = 0; i < 8; ++i) {
    const int row = wv * 8 + i;
    const float dg = sq[i] * DIAG_SCALE;
    float4 st;
    st.x = __expf(a1[i][0] - dg);
    st.y = __expf(a1[i][1] - dg);
    st.z = __expf(a1[i][2] - dg);
    st.w = __expf(a1[i][3] - dg);
    *(float4*)(uni + row * 276 + mq * 4) = st;
  }
#pragma unroll
  for (int s = 0; s < 2; ++s) {
    const int row = r2 + s;
    uni[row * 276 + mt] = (mt < 266) ? __expf(at[s] - sqt[s] * DIAG_SCALE) : 0.f;
  }
  __syncthreads();

  // GEMM2: A[2 rows][4 cols] + B; ctx_ext from global (L2-resident), ring-2
  const int cq = t & 15, rg2 = t >> 4;
  const float* ctxg = ws + OFF_CTX + (size_t)bh * 272 * 68;
  const float* crow = ctxg + cq * 4;
  float acc[2][4] = {{0, 0, 0, 0}, {0, 0, 0, 0}};
  float accB[2] = {0.f, 0.f};
  float4 cpA[4], cpB[4];
  float cbA[4] = {0, 0, 0, 0}, cbB[4] = {0, 0, 0, 0};
#pragma unroll
  for (int u = 0; u < 4; ++u) {
    cpA[u] = *(const float4*)(crow + (size_t)u * 68);
    cpB[u] = *(const float4*)(crow + (size_t)(4 + u) * 68);
  }
  if (cq == 0) {
#pragma unroll
    for (int u = 0; u < 4; ++u) {
      cbA[u] = ctxg[(size_t)u * 68 + 64];
      cbB[u] = ctxg[(size_t)(4 + u) * 68 + 64];
    }
  }
  for (int mm = 0; mm < 272; mm += 8) {
    // half A: columns mm..mm+3
    {
      const float4 qa4 = *(const float4*)(uni + (rg2 * 2) * 276 + mm);
      const float4 qb4 = *(const float4*)(uni + (rg2 * 2 + 1) * 276 + mm);
      const float qa[4] = {qa4.x, qa4.y, qa4.z, qa4.w};
      const float qb[4] = {qb4.x, qb4.y, qb4.z, qb4.w};
#pragma unroll
      for (int u = 0; u < 4; ++u) {
        const float* cc = (const float*)&cpA[u];
        acc[0][0] = fmaf(qa[u], cc[0], acc[0][0]);
        acc[0][1] = fmaf(qa[u], cc[1], acc[0][1]);
        acc[0][2] = fmaf(qa[u], cc[2], acc[0][2]);
        acc[0][3] = fmaf(qa[u], cc[3], acc[0][3]);
        acc[1][0] = fmaf(qb[u], cc[0], acc[1][0]);
        acc[1][1] = fmaf(qb[u], cc[1], acc[1][1]);
        acc[1][2] = fmaf(qb[u], cc[2], acc[1][2]);
        acc[1][3] = fmaf(qb[u], cc[3], acc[1][3]);
      }
      if (cq == 0) {
#pragma unroll
        for (int u = 0; u < 4; ++u) {
          accB[0] = fmaf(qa[u], cbA[u], accB[0]);
          accB[1] = fmaf(qb[u], cbA[u], accB[1]);
        }
      }
      if (mm + 8 < 272) {
#pragma unroll
        for (int u = 0; u < 4; ++u) cpA[u] = *(const float4*)(crow + (size_t)(mm + 8 + u) * 68);
        if (cq == 0) {
#pragma unroll
          for (int u = 0; u < 4; ++u) cbA[u] = ctxg[(size_t)(mm + 8 + u) * 68 + 64];
        }
      }
    }
    // half B: columns mm+4..mm+7
    {
      const int m2 = mm + 4;
      const float4 qa4 = *(const float4*)(uni + (rg2 * 2) * 276 + m2);
      const float4 qb4 = *(const float4*)(uni + (rg2 * 2 + 1) * 276 + m2);
      const float qa[4] = {qa4.x, qa4.y, qa4.z, qa4.w};
      const float qb[4] = {qb4.x, qb4.y, qb4.z, qb4.w};
#pragma unroll
      for (int u = 0; u < 4; ++u) {
        const float* cc = (const float*)&cpB[u];
        acc[0][0] = fmaf(qa[u], cc[0], acc[0][0]);
        acc[0][1] = fmaf(qa[u], cc[1], acc[0][1]);
        acc[0][2] = fmaf(qa[u], cc[2], acc[0][2]);
        acc[0][3] = fmaf(qa[u], cc[3], acc[0][3]);
        acc[1][0] = fmaf(qb[u], cc[0], acc[1][0]);
        acc[1][1] = fmaf(qb[u], cc[1], acc[1][1]);
        acc[1][2] = fmaf(qb[u], cc[2], acc[1][2]);
        acc[1][3] = fmaf(qb[u], cc[3], acc[1][3]);
      }
      if (cq == 0) {
#pragma unroll
        for (int u = 0; u < 4; ++u) {
          accB[0] = fmaf(qa[u], cbB[u], accB[0]);
          accB[1] = fmaf(qb[u], cbB[u], accB[1]);
        }
      }
      if (m2 + 8 < 272) {
#pragma unroll
        for (int u = 0; u < 4; ++u) cpB[u] = *(const float4*)(crow + (size_t)(m2 + 8 + u) * 68);
        if (cq == 0) {
#pragma unroll
          for (int u = 0; u < 4; ++u) cbB[u] = ctxg[(size_t)(m2 + 8 + u) * 68 + 64];
        }
      }
    }
  }
  if (cq == 0) {
    Bl[rg2 * 2] = accB[0];
    Bl[rg2 * 2 + 1] = accB[1];
  }
  __syncthreads();

  const float4 sc4 = *(const float4*)(ws + OFF_SC + bh * 64 + cq * 4);
  const float skv = ws[OFF_SK + bh];
  float* op = outg + ((size_t)bh * 4096 + (size_t)nt * 32) * 64;
#pragma unroll
  for (int i = 0; i < 2; ++i) {
    const int row = rg2 * 2 + i;
    const float rm = fdec(rmx[row]);
    const float tt = EPSV * __expf(rm);
    const float inv = 1.0f / (Bl[row] + tt * skv);
    float4 o;
    o.x = (acc[i][0] + tt * sc4.x) * inv;
    o.y = (acc[i][1] + tt * sc4.y) * inv;
    o.z = (acc[i][2] + tt * sc4.z) * inv;
    o.w = (acc[i][3] + tt * sc4.w) * inv;
    *(float4*)(op + row * 64 + cq * 4) = o;
  }
}

// --------------------------- launch -----------------------------------------
extern "C" void kernel_launch(void* const* d_in, const int* in_sizes, int n_in,
                              void* d_out, int out_size, void* d_ws, size_t ws_size,
                              hipStream_t stream) {
  (void)in_sizes; (void)n_in; (void)out_size; (void)ws_size;
  const float* q = (const float*)d_in[0];
  const float* k = (const float*)d_in[1];
  const float* v = (const float*)d_in[2];
  const float* P = (const float*)d_in[3];
  float* out = (float*)d_out;
  float* ws = (float*)d_ws;

  // zero only the accumulated region [OFF_U, OFF_CTX)
  hipMemsetAsync((void*)(ws + OFF_U), 0, (OFF_CTX - OFF_U) * sizeof(float), stream);
  setup_kernel<<<68, 256, 0, stream>>>(P, ws);
  pass_k_fused<<<dim3(7, 32, 8), 256, 0, stream>>>(k, v, ws);
  combine_kernel<<<32, 256, 0, stream>>>(ws);
  pass_q<<<dim3(128, 32), 256, 0, stream>>>(q, out, ws);
}

// Round 3
// 748.640 us; speedup vs baseline: 1.7417x; 1.0058x over previous
//
#include <hip/hip_runtime.h>
#include <cmath>

// ---------------------------------------------------------------------------
// Performer (FAVOR+) attention, fp32, MI355X.
// Algebra: ratio cancels; k-side stabilizer S applied post-hoc (exp range safe);
// q-side rowmax applied post-hoc.
//   qph = exp(qd - diag_q)                (unstabilized)
//   U[m][e] = sum_n exp(kd - diag_k) v ;  u[m] = sum_n exp(kd - diag_k)
//   ctx'[m][e] = (e^-S U + eps sv[e]) / L ; kmean'[m] = e^-S u / L + eps
//   out = (A + eps e^{rm} Sc) / (B + eps e^{rm} Sk)
//
// R3 change (scratch-spill fix): R2 indexed register float4 arrays through
// pointer casts ((const float*)&v4[u])[j], which defeats SROA -> arrays in
// scratch -> 583 MB of scratch write traffic on pass_q (WRITE_SIZE counter)
// and low VGPR_Count (64). All inner products rewritten as explicit
// component FMAs, same accumulation order (bitwise-identical results).
// ---------------------------------------------------------------------------

namespace {
constexpr float NORM       = 0.35355339059327379f; // 64^-0.25
constexpr float DIAG_SCALE = 0.0625f;              // 0.5 * 64^-0.5
constexpr float EPSV       = 1e-4f;
constexpr float INV_L      = 1.0f / 4096.0f;

// workspace layout (float offsets)
constexpr size_t OFF_PT  = 0;                          // PT[64][272]
constexpr size_t OFF_U   = OFF_PT + (size_t)64 * 272;  // U[32][272][64]
constexpr size_t OFF_u   = OFF_U + (size_t)32 * 272 * 64; // u[32][272]
constexpr size_t OFF_SV  = OFF_u + (size_t)32 * 272;   // sv[32][64]
constexpr size_t OFF_SC  = OFF_SV + (size_t)32 * 64;   // Sc[32][64]
constexpr size_t OFF_SK  = OFF_SC + (size_t)32 * 64;   // Sk[32]
constexpr size_t OFF_S   = OFF_SK + 32;                // S (1, encoded uint)
constexpr size_t OFF_CTX = OFF_S + 4;                  // ctx_ext[32][272][68]
constexpr size_t WS_FLOATS = OFF_CTX + (size_t)32 * 272 * 68;
} // namespace

__device__ __forceinline__ unsigned fenc(float f) {
  unsigned u = __float_as_uint(f);
  return (u & 0x80000000u) ? ~u : (u | 0x80000000u);
}
__device__ __forceinline__ float fdec(unsigned u) {
  return (u & 0x80000000u) ? __uint_as_float(u ^ 0x80000000u) : __uint_as_float(~u);
}

// async global->LDS: per-lane global src, wave-uniform LDS base (+lane*size)
__device__ __forceinline__ void glds4(const float* g, float* l) {
  __builtin_amdgcn_global_load_lds((const __attribute__((address_space(1))) void*)g,
                                   (__attribute__((address_space(3))) void*)l, 4, 0, 0);
}
__device__ __forceinline__ void glds16(const float* g, float* l) {
  __builtin_amdgcn_global_load_lds((const __attribute__((address_space(1))) void*)g,
                                   (__attribute__((address_space(3))) void*)l, 16, 0, 0);
}

// --------------------------- K0: setup -------------------------------------
__global__ __launch_bounds__(256) void setup_kernel(const float* __restrict__ P,
                                                    float* __restrict__ ws) {
  const int t = threadIdx.x;
  const int elem = blockIdx.x * 256 + t; // < 64*272 exactly (grid 68)
  const int td = elem / 272, mm = elem % 272;
  ws[OFF_PT + (size_t)td * 272 + mm] = (mm < 266) ? NORM * P[mm * 64 + td] : 0.0f;
  if (blockIdx.x == 0 && t == 0) ((unsigned*)(ws + OFF_S))[0] = 0x007FFFFFu; // enc(-inf)
}

// per-row GEMM1 micro-step: row acc a1r[4] += K4 components * p0..p3, sq += K4.K4
// (explicit components only -- no pointer casts into register vectors)
#define KQ_ROW(A1R, SQ, K4, P0, P1, P2, P3)                                     \
  {                                                                             \
    SQ = fmaf((K4).x, (K4).x, SQ);                                              \
    SQ = fmaf((K4).y, (K4).y, SQ);                                              \
    SQ = fmaf((K4).z, (K4).z, SQ);                                              \
    SQ = fmaf((K4).w, (K4).w, SQ);                                              \
    A1R[0] = fmaf((K4).x, (P0).x, A1R[0]);                                      \
    A1R[1] = fmaf((K4).x, (P0).y, A1R[1]);                                      \
    A1R[2] = fmaf((K4).x, (P0).z, A1R[2]);                                      \
    A1R[3] = fmaf((K4).x, (P0).w, A1R[3]);                                      \
    A1R[0] = fmaf((K4).y, (P1).x, A1R[0]);                                      \
    A1R[1] = fmaf((K4).y, (P1).y, A1R[1]);                                      \
    A1R[2] = fmaf((K4).y, (P1).z, A1R[2]);                                      \
    A1R[3] = fmaf((K4).y, (P1).w, A1R[3]);                                      \
    A1R[0] = fmaf((K4).z, (P2).x, A1R[0]);                                      \
    A1R[1] = fmaf((K4).z, (P2).y, A1R[1]);                                      \
    A1R[2] = fmaf((K4).z, (P2).z, A1R[2]);                                      \
    A1R[3] = fmaf((K4).z, (P2).w, A1R[3]);                                      \
    A1R[0] = fmaf((K4).w, (P3).x, A1R[0]);                                      \
    A1R[1] = fmaf((K4).w, (P3).y, A1R[1]);                                      \
    A1R[2] = fmaf((K4).w, (P3).z, A1R[2]);                                      \
    A1R[3] = fmaf((K4).w, (P3).w, A1R[3]);                                      \
  }

// --------------------------- K1: fused k-side pass ---------------------------
// grid (7, 32, 8):
//   x in [0,4)  : main k-pass, m-block = x (m in [0,256)), 512 rows per z
//   x == 4      : tail k-pass (m in [256,266)), 512 rows per z
//   x in {5,6}  : sv accumulation, 256 rows per (x,z)
__global__ __launch_bounds__(256, 3) void pass_k_fused(const float* __restrict__ kg,
                                                       const float* __restrict__ vg,
                                                       float* __restrict__ ws) {
  __shared__ __align__(16) float pool[12544]; // PTs[4096] | kS[64][68] | vS[64][64]
  __shared__ float redb[4];

  const int t = threadIdx.x;
  const int mb = blockIdx.x, bh = blockIdx.y, bz = blockIdx.z;
  const int lane = t & 63, wv = t >> 6;

  if (mb >= 5) {
    // ---- sv: sv[bh][e] += sum over 256 rows of v ----
    const int nz = (mb - 5) * 8 + bz;
    const float* vp = vg + ((size_t)bh * 4096 + (size_t)nz * 256) * 64;
    float s = 0.f;
    for (int i = 0; i < 64; ++i) s += vp[(wv * 64 + i) * 64 + lane];
    atomicAdd(ws + OFF_SV + bh * 64 + lane, s);
    return;
  }

  float* PTs = pool;          // main: PT tile [td 64][m 64]; tail: PT_t[td 64][16]
  float* kS  = pool + 4096;   // k rows [row 64][d] stride 68; reused as kp
  float* vS  = pool + 8448;   // v rows [row 64][e 64] stride 64

  const size_t base = ((size_t)bh * 4096 + (size_t)bz * 512) * 64;

  if (mb == 4) {
    // =================== tail path: m in [256, 272) ===================
    const int m4 = t & 3, rg1 = t >> 2;          // GEMM1: 1 row, 4 m's
    const int eg = (t >> 2) & 15, rs = t >> 6;   // GEMM2: 4m x 4e x 4 n-quarters

    // stage PT_t[64][16] once
    {
      const int td = t >> 2, m4i = t & 3;
      *(float4*)(PTs + td * 16 + m4i * 4) =
          *(const float4*)(ws + OFF_PT + (size_t)td * 272 + 256 + m4i * 4);
    }

    float acc2[4][4];
#pragma unroll
    for (int i = 0; i < 4; ++i) { acc2[i][0] = acc2[i][1] = acc2[i][2] = acc2[i][3] = 0.f; }
    float uacc[4] = {0, 0, 0, 0};
    float smax = -INFINITY;

    for (int sc = 0; sc < 8; ++sc) {
      const float* kgp = kg + base + (size_t)sc * 64 * 64;
      const float* vgp = vg + base + (size_t)sc * 64 * 64;
      __syncthreads(); // previous iter's LDS reads complete
      {
        const int r0 = wv * 16;
#pragma unroll
        for (int r = 0; r < 16; ++r) glds4(kgp + (r0 + r) * 64 + lane, kS + (r0 + r) * 68);
#pragma unroll
        for (int r4 = 0; r4 < 4; ++r4)
          glds16(vgp + (r0 + r4 * 4) * 64 + lane * 4, vS + (r0 + r4 * 4) * 64);
      }
      __syncthreads(); // staged
      // GEMM1: row rg1, m-quad m4; diag accumulated as k^2
      float a1[4] = {0, 0, 0, 0};
      float sqt = 0.f;
#pragma unroll
      for (int tb = 0; tb < 16; ++tb) {
        const int td = tb * 4;
        const float4 kv4 = *(const float4*)(kS + rg1 * 68 + td);
        const float4 p0 = *(const float4*)(PTs + (td + 0) * 16 + m4 * 4);
        const float4 p1 = *(const float4*)(PTs + (td + 1) * 16 + m4 * 4);
        const float4 p2 = *(const float4*)(PTs + (td + 2) * 16 + m4 * 4);
        const float4 p3 = *(const float4*)(PTs + (td + 3) * 16 + m4 * 4);
        KQ_ROW(a1, sqt, kv4, p0, p1, p2, p3);
      }
      float vals[4];
      {
        const float dg = sqt * DIAG_SCALE;
#pragma unroll
        for (int j = 0; j < 4; ++j) {
          const int m = 256 + m4 * 4 + j;
          float e = 0.f;
          if (m < 266) {
            smax = fmaxf(smax, a1[j]);
            e = __expf(a1[j] - dg);
          }
          vals[j] = e;
        }
      }
      __syncthreads(); // all kS reads done -> overwrite with kp (stride 20)
      {
        float4 st;
        st.x = vals[0]; st.y = vals[1]; st.z = vals[2]; st.w = vals[3];
        *(float4*)(kS + rg1 * 20 + m4 * 4) = st;
      }
      __syncthreads(); // kp ready
#pragma unroll 2
      for (int nn = 0; nn < 16; ++nn) {
        const int n = rs * 16 + nn;
        const float4 kk4 = *(const float4*)(kS + n * 20 + m4 * 4);
        const float4 vv4 = *(const float4*)(vS + n * 64 + eg * 4);
        const float kk[4] = {kk4.x, kk4.y, kk4.z, kk4.w};
        const float vv[4] = {vv4.x, vv4.y, vv4.z, vv4.w};
#pragma unroll
        for (int i = 0; i < 4; ++i)
#pragma unroll
          for (int j = 0; j < 4; ++j) acc2[i][j] = fmaf(kk[i], vv[j], acc2[i][j]);
        if (eg == 0) {
#pragma unroll
          for (int i = 0; i < 4; ++i) uacc[i] += kk[i];
        }
      }
    }
    {
      float* Ub = ws + OFF_U + ((size_t)bh * 272 + 256 + m4 * 4) * 64 + eg * 4;
#pragma unroll
      for (int i = 0; i < 4; ++i)
#pragma unroll
        for (int j = 0; j < 4; ++j) atomicAdd(Ub + (size_t)i * 64 + j, acc2[i][j]);
      if (eg == 0) {
#pragma unroll
        for (int i = 0; i < 4; ++i)
          atomicAdd(ws + OFF_u + (size_t)bh * 272 + 256 + m4 * 4 + i, uacc[i]);
      }
    }
#pragma unroll
    for (int o = 32; o > 0; o >>= 1) smax = fmaxf(smax, __shfl_xor(smax, o));
    if (lane == 0) redb[wv] = smax;
    __syncthreads();
    if (t == 0) {
      const float m = fmaxf(fmaxf(redb[0], redb[1]), fmaxf(redb[2], redb[3]));
      atomicMax((unsigned*)(ws + OFF_S), fenc(m));
    }
    return;
  }

  // =================== main path: m-block mb, m in [0,256) ===================
  const int mq = t & 15, rg = t >> 4;          // GEMM1: 16 m-quads x 16 row-groups(4)
  const int mo = t & 7, eo = (t >> 3) & 7;     // GEMM2: 8 m-octs x 8 e-octs
  const int rs = t >> 6;                       // GEMM2: n quarter (= wave id)

  // stage PTs[td 64][m 64] once (invariant over sc)
#pragma unroll
  for (int c = 0; c < 4; ++c) {
    const int f4 = c * 256 + t;
    const int td = f4 >> 4, mi = f4 & 15;
    *(float4*)(PTs + td * 64 + mi * 4) =
        *(const float4*)(ws + OFF_PT + (size_t)td * 272 + mb * 64 + mi * 4);
  }

  float acc2[8][8];
#pragma unroll
  for (int i = 0; i < 8; ++i)
#pragma unroll
    for (int j = 0; j < 8; ++j) acc2[i][j] = 0.f;
  float uacc[8] = {0, 0, 0, 0, 0, 0, 0, 0};
  float smax = -INFINITY;

  for (int sc = 0; sc < 8; ++sc) {
    const float* kgp = kg + base + (size_t)sc * 64 * 64;
    const float* vgp = vg + base + (size_t)sc * 64 * 64;
    __syncthreads(); // previous iter's LDS reads complete (also covers PTs staging)
    {
      const int r0 = wv * 16;
#pragma unroll
      for (int r = 0; r < 16; ++r) glds4(kgp + (r0 + r) * 64 + lane, kS + (r0 + r) * 68);
#pragma unroll
      for (int r4 = 0; r4 < 4; ++r4)
        glds16(vgp + (r0 + r4 * 4) * 64 + lane * 4, vS + (r0 + r4 * 4) * 64);
    }
    __syncthreads(); // staged (vmcnt drained by barrier)

    // GEMM1: kd[rows 4][m 4]; diag accumulated as k^2 in-loop (components only)
    float a1[4][4];
#pragma unroll
    for (int i = 0; i < 4; ++i) { a1[i][0] = a1[i][1] = a1[i][2] = a1[i][3] = 0.f; }
    float sq[4] = {0, 0, 0, 0};
#pragma unroll
    for (int tb = 0; tb < 16; ++tb) {
      const int td = tb * 4;
      const float4 kA = *(const float4*)(kS + (rg * 4 + 0) * 68 + td);
      const float4 kB = *(const float4*)(kS + (rg * 4 + 1) * 68 + td);
      const float4 kC = *(const float4*)(kS + (rg * 4 + 2) * 68 + td);
      const float4 kD = *(const float4*)(kS + (rg * 4 + 3) * 68 + td);
      const float4 p0 = *(const float4*)(PTs + (td + 0) * 64 + mq * 4);
      const float4 p1 = *(const float4*)(PTs + (td + 1) * 64 + mq * 4);
      const float4 p2 = *(const float4*)(PTs + (td + 2) * 64 + mq * 4);
      const float4 p3 = *(const float4*)(PTs + (td + 3) * 64 + mq * 4);
      KQ_ROW(a1[0], sq[0], kA, p0, p1, p2, p3);
      KQ_ROW(a1[1], sq[1], kB, p0, p1, p2, p3);
      KQ_ROW(a1[2], sq[2], kC, p0, p1, p2, p3);
      KQ_ROW(a1[3], sq[3], kD, p0, p1, p2, p3);
    }
    // smax on raw kd, then exp in-place
#pragma unroll
    for (int i = 0; i < 4; ++i) {
      const float dg = sq[i] * DIAG_SCALE;
      smax = fmaxf(smax, fmaxf(fmaxf(a1[i][0], a1[i][1]), fmaxf(a1[i][2], a1[i][3])));
      a1[i][0] = __expf(a1[i][0] - dg);
      a1[i][1] = __expf(a1[i][1] - dg);
      a1[i][2] = __expf(a1[i][2] - dg);
      a1[i][3] = __expf(a1[i][3] - dg);
    }
    __syncthreads(); // all kS reads done -> overwrite with kp
#pragma unroll
    for (int i = 0; i < 4; ++i) {
      float4 st;
      st.x = a1[i][0]; st.y = a1[i][1]; st.z = a1[i][2]; st.w = a1[i][3];
      *(float4*)(kS + (rg * 4 + i) * 68 + mq * 4) = st; // kp[row][m] stride 68
    }
    __syncthreads(); // kp ready
    // GEMM2: U_partial[8m][8e] += kp^T * v (n split by wave)
#pragma unroll 2
    for (int nn = 0; nn < 16; ++nn) {
      const int n = rs * 16 + nn;
      const float4 ka = *(const float4*)(kS + n * 68 + mo * 8);
      const float4 kb = *(const float4*)(kS + n * 68 + mo * 8 + 4);
      const float4 va = *(const float4*)(vS + n * 64 + eo * 8);
      const float4 vb = *(const float4*)(vS + n * 64 + eo * 8 + 4);
      const float kk[8] = {ka.x, ka.y, ka.z, ka.w, kb.x, kb.y, kb.z, kb.w};
      const float vv[8] = {va.x, va.y, va.z, va.w, vb.x, vb.y, vb.z, vb.w};
#pragma unroll
      for (int i = 0; i < 8; ++i)
#pragma unroll
        for (int j = 0; j < 8; ++j) acc2[i][j] = fmaf(kk[i], vv[j], acc2[i][j]);
      if (eo == 0) {
#pragma unroll
        for (int i = 0; i < 8; ++i) uacc[i] += kk[i];
      }
    }
  }

  // ---- epilogue: fold 4 waves' acc2 in LDS, then spread atomics ----
  __syncthreads(); // all GEMM2 reads done; kS/vS/PTs free as scratch
  {
    float* A = kS;  // col-major [idx 64][lane 64]
    float* B = PTs; // col-major [idx 64][lane 64]
    if (wv == 1) {
#pragma unroll
      for (int i = 0; i < 8; ++i)
#pragma unroll
        for (int j = 0; j < 8; ++j) A[(i * 8 + j) * 64 + lane] = acc2[i][j];
    }
    if (wv == 3) {
#pragma unroll
      for (int i = 0; i < 8; ++i)
#pragma unroll
        for (int j = 0; j < 8; ++j) B[(i * 8 + j) * 64 + lane] = acc2[i][j];
    }
    __syncthreads();
    if (wv == 0) {
#pragma unroll
      for (int i = 0; i < 8; ++i)
#pragma unroll
        for (int j = 0; j < 8; ++j) acc2[i][j] += A[(i * 8 + j) * 64 + lane];
    }
    if (wv == 2) {
#pragma unroll
      for (int i = 0; i < 8; ++i)
#pragma unroll
        for (int j = 0; j < 8; ++j) acc2[i][j] += B[(i * 8 + j) * 64 + lane];
    }
    __syncthreads();
    if (wv == 2) {
#pragma unroll
      for (int i = 0; i < 8; ++i)
#pragma unroll
        for (int j = 0; j < 8; ++j) A[(i * 8 + j) * 64 + lane] = acc2[i][j];
    }
    __syncthreads();
    if (wv == 0) {
#pragma unroll
      for (int i = 0; i < 8; ++i)
#pragma unroll
        for (int j = 0; j < 8; ++j) {
          acc2[i][j] += A[(i * 8 + j) * 64 + lane];
          A[(i * 8 + j) * 64 + lane] = acc2[i][j];
        }
    }
    __syncthreads();
    // spread atomics: 16 per thread, 4096 per block
    {
      const int l = t & 63, idxb = (t >> 6) * 16;
      float* Ub = ws + OFF_U + ((size_t)bh * 272 + mb * 64) * 64;
#pragma unroll
      for (int c = 0; c < 16; ++c) {
        const int idx = idxb + c;
        const int ml = (l & 7) * 8 + (idx >> 3);
        const int e  = (l >> 3) * 8 + (idx & 7);
        atomicAdd(Ub + (size_t)ml * 64 + e, A[idx * 64 + l]);
      }
    }
    if (eo == 0) {
#pragma unroll
      for (int i = 0; i < 8; ++i)
        atomicAdd(ws + OFF_u + (size_t)bh * 272 + mb * 64 + mo * 8 + i, uacc[i]);
    }
  }
#pragma unroll
  for (int o = 32; o > 0; o >>= 1) smax = fmaxf(smax, __shfl_xor(smax, o));
  if (lane == 0) redb[wv] = smax;
  __syncthreads();
  if (t == 0) {
    const float m = fmaxf(fmaxf(redb[0], redb[1]), fmaxf(redb[2], redb[3]));
    atomicMax((unsigned*)(ws + OFF_S), fenc(m));
  }
}

// --------------------------- K3: combine -> ctx_ext, Sc, Sk -----------------
__global__ __launch_bounds__(256) void combine_kernel(float* __restrict__ ws) {
  __shared__ float red[256];
  const int t = threadIdx.x;
  const int bh = blockIdx.x;
  const float S = fdec(((unsigned*)(ws + OFF_S))[0]);
  const float es = __expf(-S);
  const int e = t & 63, mr = t >> 6;
  const float svv = ws[OFF_SV + bh * 64 + e];
  float scp = 0.f;
  for (int mm = mr; mm < 272; mm += 4) {
    float val = 0.f;
    if (mm < 266)
      val = (es * ws[OFF_U + ((size_t)bh * 272 + mm) * 64 + e] + EPSV * svv) * INV_L;
    ws[OFF_CTX + ((size_t)bh * 272 + mm) * 68 + e] = val;
    scp += val;
  }
  red[t] = scp;
  __syncthreads();
  if (t < 64) ws[OFF_SC + bh * 64 + t] = red[t] + red[t + 64] + red[t + 128] + red[t + 192];
  __syncthreads();
  float skp = 0.f;
  for (int mm = t; mm < 272; mm += 256) {
    float km = 0.f;
    if (mm < 266) km = es * ws[OFF_u + (size_t)bh * 272 + mm] * INV_L + EPSV;
    float* cx = ws + OFF_CTX + ((size_t)bh * 272 + mm) * 68;
    cx[64] = km; cx[65] = 0.f; cx[66] = 0.f; cx[67] = 0.f;
    skp += km;
  }
  red[t] = skp;
  __syncthreads();
  for (int s = 128; s > 0; s >>= 1) {
    if (t < s) red[t] += red[t + s];
    __syncthreads();
  }
  if (t == 0) ws[OFF_SK + bh] = red[0];
}

// --------------------------- K4: q-pass -> out ------------------------------
// LDS: uni = qS[32][68] during GEMM1 (GLDS-staged), then qph[32][276].
__global__ __launch_bounds__(256, 4) void pass_q(const float* __restrict__ qg,
                                                 float* __restrict__ outg,
                                                 const float* __restrict__ ws) {
  __shared__ __align__(16) float uni[8832];
  __shared__ unsigned rmx[32];
  __shared__ float Bl[32];

  const int t = threadIdx.x;
  const int nt = blockIdx.x, bh = blockIdx.y;
  const int lane = t & 63, wv = t >> 6;
  const float* qgp = qg + ((size_t)bh * 4096 + (size_t)nt * 32) * 64;

  if (t < 32) rmx[t] = 0x007FFFFFu; // enc(-inf)

  // stage qS[32][68] via GLDS (rows wv*8..wv*8+7)
#pragma unroll
  for (int r = 0; r < 8; ++r)
    glds4(qgp + (wv * 8 + r) * 64 + lane, uni + (wv * 8 + r) * 68);
  __syncthreads();

  // GEMM1 main: mq = lane (64 m-quads, m<256); rows wv*8..+7; PT ring-2 (8 rows)
  const int mq = t & 63;
  float a1[8][4];
  float sq[8] = {0, 0, 0, 0, 0, 0, 0, 0};
#pragma unroll
  for (int i = 0; i < 8; ++i) { a1[i][0] = a1[i][1] = a1[i][2] = a1[i][3] = 0.f; }
  {
    const float* ptm = ws + OFF_PT + mq * 4;
    float4 pfA0, pfA1, pfA2, pfA3, pfB0, pfB1, pfB2, pfB3;
    pfA0 = *(const float4*)(ptm + (size_t)0 * 272);
    pfA1 = *(const float4*)(ptm + (size_t)1 * 272);
    pfA2 = *(const float4*)(ptm + (size_t)2 * 272);
    pfA3 = *(const float4*)(ptm + (size_t)3 * 272);
    pfB0 = *(const float4*)(ptm + (size_t)4 * 272);
    pfB1 = *(const float4*)(ptm + (size_t)5 * 272);
    pfB2 = *(const float4*)(ptm + (size_t)6 * 272);
    pfB3 = *(const float4*)(ptm + (size_t)7 * 272);
#pragma unroll
    for (int tb = 0; tb < 16; tb += 2) {
      {
        const int td = tb * 4;
#pragma unroll
        for (int i = 0; i < 8; ++i) {
          const float4 q4 = *(const float4*)(uni + (wv * 8 + i) * 68 + td);
          KQ_ROW(a1[i], sq[i], q4, pfA0, pfA1, pfA2, pfA3);
        }
        if (tb < 14) {
          pfA0 = *(const float4*)(ptm + (size_t)(td + 8) * 272);
          pfA1 = *(const float4*)(ptm + (size_t)(td + 9) * 272);
          pfA2 = *(const float4*)(ptm + (size_t)(td + 10) * 272);
          pfA3 = *(const float4*)(ptm + (size_t)(td + 11) * 272);
        }
      }
      {
        const int td = tb * 4 + 4;
#pragma unroll
        for (int i = 0; i < 8; ++i) {
          const float4 q4 = *(const float4*)(uni + (wv * 8 + i) * 68 + td);
          KQ_ROW(a1[i], sq[i], q4, pfB0, pfB1, pfB2, pfB3);
        }
        if (tb < 14) {
          pfB0 = *(const float4*)(ptm + (size_t)(td + 8) * 272);
          pfB1 = *(const float4*)(ptm + (size_t)(td + 9) * 272);
          pfB2 = *(const float4*)(ptm + (size_t)(td + 10) * 272);
          pfB3 = *(const float4*)(ptm + (size_t)(td + 11) * 272);
        }
      }
    }
  }
  // GEMM1 tail: m_t = 256 + (t&15), rows r2, r2+1; ring-2 scalar
  float at[2] = {0.f, 0.f};
  float sqt[2] = {0.f, 0.f};
  const int mt = 256 + (t & 15);
  const int r2 = (t >> 4) * 2;
  {
    const float* ptt = ws + OFF_PT + mt;
    float ptA[4], ptB[4];
#pragma unroll
    for (int u = 0; u < 4; ++u) {
      ptA[u] = ptt[(size_t)u * 272];
      ptB[u] = ptt[(size_t)(4 + u) * 272];
    }
#pragma unroll
    for (int tb = 0; tb < 16; tb += 2) {
      {
        const int td = tb * 4;
        const float4 qx4 = *(const float4*)(uni + r2 * 68 + td);
        const float4 qy4 = *(const float4*)(uni + (r2 + 1) * 68 + td);
        const float qx[4] = {qx4.x, qx4.y, qx4.z, qx4.w};
        const float qy[4] = {qy4.x, qy4.y, qy4.z, qy4.w};
#pragma unroll
        for (int u = 0; u < 4; ++u) {
          sqt[0] = fmaf(qx[u], qx[u], sqt[0]);
          sqt[1] = fmaf(qy[u], qy[u], sqt[1]);
          at[0] = fmaf(qx[u], ptA[u], at[0]);
          at[1] = fmaf(qy[u], ptA[u], at[1]);
        }
        if (tb < 14) {
#pragma unroll
          for (int u = 0; u < 4; ++u) ptA[u] = ptt[(size_t)(td + 8 + u) * 272];
        }
      }
      {
        const int td = tb * 4 + 4;
        const float4 qx4 = *(const float4*)(uni + r2 * 68 + td);
        const float4 qy4 = *(const float4*)(uni + (r2 + 1) * 68 + td);
        const float qx[4] = {qx4.x, qx4.y, qx4.z, qx4.w};
        const float qy[4] = {qy4.x, qy4.y, qy4.z, qy4.w};
#pragma unroll
        for (int u = 0; u < 4; ++u) {
          sqt[0] = fmaf(qx[u], qx[u], sqt[0]);
          sqt[1] = fmaf(qy[u], qy[u], sqt[1]);
          at[0] = fmaf(qx[u], ptB[u], at[0]);
          at[1] = fmaf(qy[u], ptB[u], at[1]);
        }
        if (tb < 14) {
#pragma unroll
          for (int u = 0; u < 4; ++u) ptB[u] = ptt[(size_t)(td + 8 + u) * 272];
        }
      }
    }
  }
  __syncthreads(); // all qS reads complete -> uni can be rewritten as qph

  // rowmax (raw qd): main butterfly + tail group-reduce, into LDS atomicMax
#pragma unroll
  for (int i = 0; i < 8; ++i) {
    float lm = fmaxf(fmaxf(a1[i][0], a1[i][1]), fmaxf(a1[i][2], a1[i][3]));
#pragma unroll
    for (int o = 32; o > 0; o >>= 1) lm = fmaxf(lm, __shfl_xor(lm, o));
    if (lane == i) atomicMax(&rmx[wv * 8 + i], fenc(lm));
  }
#pragma unroll
  for (int s = 0; s < 2; ++s) {
    float v = (mt < 266) ? at[s] : -INFINITY;
#pragma unroll
    for (int o = 8; o > 0; o >>= 1) v = fmaxf(v, __shfl_xor(v, o));
    if ((t & 15) == 0) atomicMax(&rmx[r2 + s], fenc(v));
  }
  // exp (unstabilized, diag from registers) + store qph
#pragma unroll
  for (int i = 0; i < 8; ++i) {
    const int row = wv * 8 + i;
    const float dg = sq[i] * DIAG_SCALE;
    float4 st;
    st.x = __expf(a1[i][0] - dg);
    st.y = __expf(a1[i][1] - dg);
    st.z = __expf(a1[i][2] - dg);
    st.w = __expf(a1[i][3] - dg);
    *(float4*)(uni + row * 276 + mq * 4) = st;
  }
#pragma unroll
  for (int s = 0; s < 2; ++s) {
    const int row = r2 + s;
    uni[row * 276 + mt] = (mt < 266) ? __expf(at[s] - sqt[s] * DIAG_SCALE) : 0.f;
  }
  __syncthreads();

  // GEMM2: A[2 rows][4 cols] + B; ctx_ext from global (L2-resident), ring-2
  const int cq = t & 15, rg2 = t >> 4;
  const float* ctxg = ws + OFF_CTX + (size_t)bh * 272 * 68;
  const float* crow = ctxg + cq * 4;
  float acc[2][4] = {{0, 0, 0, 0}, {0, 0, 0, 0}};
  float accB[2] = {0.f, 0.f};
  float4 cpA0, cpA1, cpA2, cpA3, cpB0, cpB1, cpB2, cpB3;
  float cbA[4] = {0, 0, 0, 0}, cbB[4] = {0, 0, 0, 0};
  cpA0 = *(const float4*)(crow + (size_t)0 * 68);
  cpA1 = *(const float4*)(crow + (size_t)1 * 68);
  cpA2 = *(const float4*)(crow + (size_t)2 * 68);
  cpA3 = *(const float4*)(crow + (size_t)3 * 68);
  cpB0 = *(const float4*)(crow + (size_t)4 * 68);
  cpB1 = *(const float4*)(crow + (size_t)5 * 68);
  cpB2 = *(const float4*)(crow + (size_t)6 * 68);
  cpB3 = *(const float4*)(crow + (size_t)7 * 68);
  if (cq == 0) {
#pragma unroll
    for (int u = 0; u < 4; ++u) {
      cbA[u] = ctxg[(size_t)u * 68 + 64];
      cbB[u] = ctxg[(size_t)(4 + u) * 68 + 64];
    }
  }

// acc[2][4] += qa/qb scalar * C4 components (explicit components only)
#define PV_STEP(QA, QB, C4)                            \
  {                                                    \
    acc[0][0] = fmaf((QA), (C4).x, acc[0][0]);         \
    acc[0][1] = fmaf((QA), (C4).y, acc[0][1]);         \
    acc[0][2] = fmaf((QA), (C4).z, acc[0][2]);         \
    acc[0][3] = fmaf((QA), (C4).w, acc[0][3]);         \
    acc[1][0] = fmaf((QB), (C4).x, acc[1][0]);         \
    acc[1][1] = fmaf((QB), (C4).y, acc[1][1]);         \
    acc[1][2] = fmaf((QB), (C4).z, acc[1][2]);         \
    acc[1][3] = fmaf((QB), (C4).w, acc[1][3]);         \
  }

  for (int mm = 0; mm < 272; mm += 8) {
    // half A: columns mm..mm+3
    {
      const float4 qa4 = *(const float4*)(uni + (rg2 * 2) * 276 + mm);
      const float4 qb4 = *(const float4*)(uni + (rg2 * 2 + 1) * 276 + mm);
      const float qa[4] = {qa4.x, qa4.y, qa4.z, qa4.w};
      const float qb[4] = {qb4.x, qb4.y, qb4.z, qb4.w};
      PV_STEP(qa[0], qb[0], cpA0);
      PV_STEP(qa[1], qb[1], cpA1);
      PV_STEP(qa[2], qb[2], cpA2);
      PV_STEP(qa[3], qb[3], cpA3);
      if (cq == 0) {
#pragma unroll
        for (int u = 0; u < 4; ++u) {
          accB[0] = fmaf(qa[u], cbA[u], accB[0]);
          accB[1] = fmaf(qb[u], cbA[u], accB[1]);
        }
      }
      if (mm + 8 < 272) {
        cpA0 = *(const float4*)(crow + (size_t)(mm + 8) * 68);
        cpA1 = *(const float4*)(crow + (size_t)(mm + 9) * 68);
        cpA2 = *(const float4*)(crow + (size_t)(mm + 10) * 68);
        cpA3 = *(const float4*)(crow + (size_t)(mm + 11) * 68);
        if (cq == 0) {
#pragma unroll
          for (int u = 0; u < 4; ++u) cbA[u] = ctxg[(size_t)(mm + 8 + u) * 68 + 64];
        }
      }
    }
    // half B: columns mm+4..mm+7
    {
      const int m2 = mm + 4;
      const float4 qa4 = *(const float4*)(uni + (rg2 * 2) * 276 + m2);
      const float4 qb4 = *(const float4*)(uni + (rg2 * 2 + 1) * 276 + m2);
      const float qa[4] = {qa4.x, qa4.y, qa4.z, qa4.w};
      const float qb[4] = {qb4.x, qb4.y, qb4.z, qb4.w};
      PV_STEP(qa[0], qb[0], cpB0);
      PV_STEP(qa[1], qb[1], cpB1);
      PV_STEP(qa[2], qb[2], cpB2);
      PV_STEP(qa[3], qb[3], cpB3);
      if (cq == 0) {
#pragma unroll
        for (int u = 0; u < 4; ++u) {
          accB[0] = fmaf(qa[u], cbB[u], accB[0]);
          accB[1] = fmaf(qb[u], cbB[u], accB[1]);
        }
      }
      if (m2 + 8 < 272) {
        cpB0 = *(const float4*)(crow + (size_t)(m2 + 8) * 68);
        cpB1 = *(const float4*)(crow + (size_t)(m2 + 9) * 68);
        cpB2 = *(const float4*)(crow + (size_t)(m2 + 10) * 68);
        cpB3 = *(const float4*)(crow + (size_t)(m2 + 11) * 68);
        if (cq == 0) {
#pragma unroll
          for (int u = 0; u < 4; ++u) cbB[u] = ctxg[(size_t)(m2 + 8 + u) * 68 + 64];
        }
      }
    }
  }
  if (cq == 0) {
    Bl[rg2 * 2] = accB[0];
    Bl[rg2 * 2 + 1] = accB[1];
  }
  __syncthreads();

  const float4 sc4 = *(const float4*)(ws + OFF_SC + bh * 64 + cq * 4);
  const float skv = ws[OFF_SK + bh];
  float* op = outg + ((size_t)bh * 4096 + (size_t)nt * 32) * 64;
#pragma unroll
  for (int i = 0; i < 2; ++i) {
    const int row = rg2 * 2 + i;
    const float rm = fdec(rmx[row]);
    const float tt = EPSV * __expf(rm);
    const float inv = 1.0f / (Bl[row] + tt * skv);
    float4 o;
    o.x = (acc[i][0] + tt * sc4.x) * inv;
    o.y = (acc[i][1] + tt * sc4.y) * inv;
    o.z = (acc[i][2] + tt * sc4.z) * inv;
    o.w = (acc[i][3] + tt * sc4.w) * inv;
    *(float4*)(op + row * 64 + cq * 4) = o;
  }
}

// --------------------------- launch -----------------------------------------
extern "C" void kernel_launch(void* const* d_in, const int* in_sizes, int n_in,
                              void* d_out, int out_size, void* d_ws, size_t ws_size,
                              hipStream_t stream) {
  (void)in_sizes; (void)n_in; (void)out_size; (void)ws_size;
  const float* q = (const float*)d_in[0];
  const float* k = (const float*)d_in[1];
  const float* v = (const float*)d_in[2];
  const float* P = (const float*)d_in[3];
  float* out = (float*)d_out;
  float* ws = (float*)d_ws;

  // zero only the accumulated region [OFF_U, OFF_CTX)
  hipMemsetAsync((void*)(ws + OFF_U), 0, (OFF_CTX - OFF_U) * sizeof(float), stream);
  setup_kernel<<<68, 256, 0, stream>>>(P, ws);
  pass_k_fused<<<dim3(7, 32, 8), 256, 0, stream>>>(k, v, ws);
  combine_kernel<<<32, 256, 0, stream>>>(ws);
  pass_q<<<dim3(128, 32), 256, 0, stream>>>(q, out, ws);
}

// Round 4
// 678.962 us; speedup vs baseline: 1.9204x; 1.1026x over previous
//
#include <hip/hip_runtime.h>
#include <cmath>

// ---------------------------------------------------------------------------
// Performer (FAVOR+) attention, fp32, MI355X.
// Algebra: ratio cancels; k-side stabilizer S applied post-hoc (exp range safe);
// q-side rowmax applied post-hoc.
//   qph = exp(qd - diag_q)                (unstabilized)
//   U[m][e] = sum_n exp(kd - diag_k) v ;  u[m] = sum_n exp(kd - diag_k)
//   ctx'[m][e] = (e^-S U + eps sv[e]) / L ; kmean'[m] = e^-S u / L + eps
//   out = (A + eps e^{rm} Sc) / (B + eps e^{rm} Sk)
//
// R4 change (spill-cap fix): the 2nd __launch_bounds__ arg (",4"/",3") was
// translated into an 8-waves/SIMD register budget -> hard 64-VGPR cap ->
// ~460 MB of scratch traffic per pass (WRITE_SIZE counter) even after R3's
// pointer-cast fix. R0's plain __launch_bounds__(256) showed VGPR 68, zero
// scratch. Removed the occupancy hint everywhere; occupancy is now bounded
// by LDS (pass_q 35.8KB -> 4 blocks/CU, pass_k 49KB -> 3 blocks/CU).
// ---------------------------------------------------------------------------

namespace {
constexpr float NORM       = 0.35355339059327379f; // 64^-0.25
constexpr float DIAG_SCALE = 0.0625f;              // 0.5 * 64^-0.5
constexpr float EPSV       = 1e-4f;
constexpr float INV_L      = 1.0f / 4096.0f;

// workspace layout (float offsets)
constexpr size_t OFF_PT  = 0;                          // PT[64][272]
constexpr size_t OFF_U   = OFF_PT + (size_t)64 * 272;  // U[32][272][64]
constexpr size_t OFF_u   = OFF_U + (size_t)32 * 272 * 64; // u[32][272]
constexpr size_t OFF_SV  = OFF_u + (size_t)32 * 272;   // sv[32][64]
constexpr size_t OFF_SC  = OFF_SV + (size_t)32 * 64;   // Sc[32][64]
constexpr size_t OFF_SK  = OFF_SC + (size_t)32 * 64;   // Sk[32]
constexpr size_t OFF_S   = OFF_SK + 32;                // S (1, encoded uint)
constexpr size_t OFF_CTX = OFF_S + 4;                  // ctx_ext[32][272][68]
constexpr size_t WS_FLOATS = OFF_CTX + (size_t)32 * 272 * 68;
} // namespace

__device__ __forceinline__ unsigned fenc(float f) {
  unsigned u = __float_as_uint(f);
  return (u & 0x80000000u) ? ~u : (u | 0x80000000u);
}
__device__ __forceinline__ float fdec(unsigned u) {
  return (u & 0x80000000u) ? __uint_as_float(u ^ 0x80000000u) : __uint_as_float(~u);
}

// async global->LDS: per-lane global src, wave-uniform LDS base (+lane*size)
__device__ __forceinline__ void glds4(const float* g, float* l) {
  __builtin_amdgcn_global_load_lds((const __attribute__((address_space(1))) void*)g,
                                   (__attribute__((address_space(3))) void*)l, 4, 0, 0);
}
__device__ __forceinline__ void glds16(const float* g, float* l) {
  __builtin_amdgcn_global_load_lds((const __attribute__((address_space(1))) void*)g,
                                   (__attribute__((address_space(3))) void*)l, 16, 0, 0);
}

// --------------------------- K0: setup -------------------------------------
__global__ __launch_bounds__(256) void setup_kernel(const float* __restrict__ P,
                                                    float* __restrict__ ws) {
  const int t = threadIdx.x;
  const int elem = blockIdx.x * 256 + t; // < 64*272 exactly (grid 68)
  const int td = elem / 272, mm = elem % 272;
  ws[OFF_PT + (size_t)td * 272 + mm] = (mm < 266) ? NORM * P[mm * 64 + td] : 0.0f;
  if (blockIdx.x == 0 && t == 0) ((unsigned*)(ws + OFF_S))[0] = 0x007FFFFFu; // enc(-inf)
}

// per-row GEMM1 micro-step: row acc a1r[4] += K4 components * p0..p3, sq += K4.K4
// (explicit components only -- no pointer casts into register vectors)
#define KQ_ROW(A1R, SQ, K4, P0, P1, P2, P3)                                     \
  {                                                                             \
    SQ = fmaf((K4).x, (K4).x, SQ);                                              \
    SQ = fmaf((K4).y, (K4).y, SQ);                                              \
    SQ = fmaf((K4).z, (K4).z, SQ);                                              \
    SQ = fmaf((K4).w, (K4).w, SQ);                                              \
    A1R[0] = fmaf((K4).x, (P0).x, A1R[0]);                                      \
    A1R[1] = fmaf((K4).x, (P0).y, A1R[1]);                                      \
    A1R[2] = fmaf((K4).x, (P0).z, A1R[2]);                                      \
    A1R[3] = fmaf((K4).x, (P0).w, A1R[3]);                                      \
    A1R[0] = fmaf((K4).y, (P1).x, A1R[0]);                                      \
    A1R[1] = fmaf((K4).y, (P1).y, A1R[1]);                                      \
    A1R[2] = fmaf((K4).y, (P1).z, A1R[2]);                                      \
    A1R[3] = fmaf((K4).y, (P1).w, A1R[3]);                                      \
    A1R[0] = fmaf((K4).z, (P2).x, A1R[0]);                                      \
    A1R[1] = fmaf((K4).z, (P2).y, A1R[1]);                                      \
    A1R[2] = fmaf((K4).z, (P2).z, A1R[2]);                                      \
    A1R[3] = fmaf((K4).z, (P2).w, A1R[3]);                                      \
    A1R[0] = fmaf((K4).w, (P3).x, A1R[0]);                                      \
    A1R[1] = fmaf((K4).w, (P3).y, A1R[1]);                                      \
    A1R[2] = fmaf((K4).w, (P3).z, A1R[2]);                                      \
    A1R[3] = fmaf((K4).w, (P3).w, A1R[3]);                                      \
  }

// --------------------------- K1: fused k-side pass ---------------------------
// grid (7, 32, 8):
//   x in [0,4)  : main k-pass, m-block = x (m in [0,256)), 512 rows per z
//   x == 4      : tail k-pass (m in [256,266)), 512 rows per z
//   x in {5,6}  : sv accumulation, 256 rows per (x,z)
__global__ __launch_bounds__(256) void pass_k_fused(const float* __restrict__ kg,
                                                    const float* __restrict__ vg,
                                                    float* __restrict__ ws) {
  __shared__ __align__(16) float pool[12544]; // PTs[4096] | kS[64][68] | vS[64][64]
  __shared__ float redb[4];

  const int t = threadIdx.x;
  const int mb = blockIdx.x, bh = blockIdx.y, bz = blockIdx.z;
  const int lane = t & 63, wv = t >> 6;

  if (mb >= 5) {
    // ---- sv: sv[bh][e] += sum over 256 rows of v ----
    const int nz = (mb - 5) * 8 + bz;
    const float* vp = vg + ((size_t)bh * 4096 + (size_t)nz * 256) * 64;
    float s = 0.f;
    for (int i = 0; i < 64; ++i) s += vp[(wv * 64 + i) * 64 + lane];
    atomicAdd(ws + OFF_SV + bh * 64 + lane, s);
    return;
  }

  float* PTs = pool;          // main: PT tile [td 64][m 64]; tail: PT_t[td 64][16]
  float* kS  = pool + 4096;   // k rows [row 64][d] stride 68; reused as kp
  float* vS  = pool + 8448;   // v rows [row 64][e 64] stride 64

  const size_t base = ((size_t)bh * 4096 + (size_t)bz * 512) * 64;

  if (mb == 4) {
    // =================== tail path: m in [256, 272) ===================
    const int m4 = t & 3, rg1 = t >> 2;          // GEMM1: 1 row, 4 m's
    const int eg = (t >> 2) & 15, rs = t >> 6;   // GEMM2: 4m x 4e x 4 n-quarters

    // stage PT_t[64][16] once
    {
      const int td = t >> 2, m4i = t & 3;
      *(float4*)(PTs + td * 16 + m4i * 4) =
          *(const float4*)(ws + OFF_PT + (size_t)td * 272 + 256 + m4i * 4);
    }

    float acc2[4][4];
#pragma unroll
    for (int i = 0; i < 4; ++i) { acc2[i][0] = acc2[i][1] = acc2[i][2] = acc2[i][3] = 0.f; }
    float uacc[4] = {0, 0, 0, 0};
    float smax = -INFINITY;

    for (int sc = 0; sc < 8; ++sc) {
      const float* kgp = kg + base + (size_t)sc * 64 * 64;
      const float* vgp = vg + base + (size_t)sc * 64 * 64;
      __syncthreads(); // previous iter's LDS reads complete
      {
        const int r0 = wv * 16;
#pragma unroll
        for (int r = 0; r < 16; ++r) glds4(kgp + (r0 + r) * 64 + lane, kS + (r0 + r) * 68);
#pragma unroll
        for (int r4 = 0; r4 < 4; ++r4)
          glds16(vgp + (r0 + r4 * 4) * 64 + lane * 4, vS + (r0 + r4 * 4) * 64);
      }
      __syncthreads(); // staged
      // GEMM1: row rg1, m-quad m4; diag accumulated as k^2
      float a1[4] = {0, 0, 0, 0};
      float sqt = 0.f;
#pragma unroll
      for (int tb = 0; tb < 16; ++tb) {
        const int td = tb * 4;
        const float4 kv4 = *(const float4*)(kS + rg1 * 68 + td);
        const float4 p0 = *(const float4*)(PTs + (td + 0) * 16 + m4 * 4);
        const float4 p1 = *(const float4*)(PTs + (td + 1) * 16 + m4 * 4);
        const float4 p2 = *(const float4*)(PTs + (td + 2) * 16 + m4 * 4);
        const float4 p3 = *(const float4*)(PTs + (td + 3) * 16 + m4 * 4);
        KQ_ROW(a1, sqt, kv4, p0, p1, p2, p3);
      }
      float vals[4];
      {
        const float dg = sqt * DIAG_SCALE;
#pragma unroll
        for (int j = 0; j < 4; ++j) {
          const int m = 256 + m4 * 4 + j;
          float e = 0.f;
          if (m < 266) {
            smax = fmaxf(smax, a1[j]);
            e = __expf(a1[j] - dg);
          }
          vals[j] = e;
        }
      }
      __syncthreads(); // all kS reads done -> overwrite with kp (stride 20)
      {
        float4 st;
        st.x = vals[0]; st.y = vals[1]; st.z = vals[2]; st.w = vals[3];
        *(float4*)(kS + rg1 * 20 + m4 * 4) = st;
      }
      __syncthreads(); // kp ready
#pragma unroll 2
      for (int nn = 0; nn < 16; ++nn) {
        const int n = rs * 16 + nn;
        const float4 kk4 = *(const float4*)(kS + n * 20 + m4 * 4);
        const float4 vv4 = *(const float4*)(vS + n * 64 + eg * 4);
        const float kk[4] = {kk4.x, kk4.y, kk4.z, kk4.w};
        const float vv[4] = {vv4.x, vv4.y, vv4.z, vv4.w};
#pragma unroll
        for (int i = 0; i < 4; ++i)
#pragma unroll
          for (int j = 0; j < 4; ++j) acc2[i][j] = fmaf(kk[i], vv[j], acc2[i][j]);
        if (eg == 0) {
#pragma unroll
          for (int i = 0; i < 4; ++i) uacc[i] += kk[i];
        }
      }
    }
    {
      float* Ub = ws + OFF_U + ((size_t)bh * 272 + 256 + m4 * 4) * 64 + eg * 4;
#pragma unroll
      for (int i = 0; i < 4; ++i)
#pragma unroll
        for (int j = 0; j < 4; ++j) atomicAdd(Ub + (size_t)i * 64 + j, acc2[i][j]);
      if (eg == 0) {
#pragma unroll
        for (int i = 0; i < 4; ++i)
          atomicAdd(ws + OFF_u + (size_t)bh * 272 + 256 + m4 * 4 + i, uacc[i]);
      }
    }
#pragma unroll
    for (int o = 32; o > 0; o >>= 1) smax = fmaxf(smax, __shfl_xor(smax, o));
    if (lane == 0) redb[wv] = smax;
    __syncthreads();
    if (t == 0) {
      const float m = fmaxf(fmaxf(redb[0], redb[1]), fmaxf(redb[2], redb[3]));
      atomicMax((unsigned*)(ws + OFF_S), fenc(m));
    }
    return;
  }

  // =================== main path: m-block mb, m in [0,256) ===================
  const int mq = t & 15, rg = t >> 4;          // GEMM1: 16 m-quads x 16 row-groups(4)
  const int mo = t & 7, eo = (t >> 3) & 7;     // GEMM2: 8 m-octs x 8 e-octs
  const int rs = t >> 6;                       // GEMM2: n quarter (= wave id)

  // stage PTs[td 64][m 64] once (invariant over sc)
#pragma unroll
  for (int c = 0; c < 4; ++c) {
    const int f4 = c * 256 + t;
    const int td = f4 >> 4, mi = f4 & 15;
    *(float4*)(PTs + td * 64 + mi * 4) =
        *(const float4*)(ws + OFF_PT + (size_t)td * 272 + mb * 64 + mi * 4);
  }

  float acc2[8][8];
#pragma unroll
  for (int i = 0; i < 8; ++i)
#pragma unroll
    for (int j = 0; j < 8; ++j) acc2[i][j] = 0.f;
  float uacc[8] = {0, 0, 0, 0, 0, 0, 0, 0};
  float smax = -INFINITY;

  for (int sc = 0; sc < 8; ++sc) {
    const float* kgp = kg + base + (size_t)sc * 64 * 64;
    const float* vgp = vg + base + (size_t)sc * 64 * 64;
    __syncthreads(); // previous iter's LDS reads complete (also covers PTs staging)
    {
      const int r0 = wv * 16;
#pragma unroll
      for (int r = 0; r < 16; ++r) glds4(kgp + (r0 + r) * 64 + lane, kS + (r0 + r) * 68);
#pragma unroll
      for (int r4 = 0; r4 < 4; ++r4)
        glds16(vgp + (r0 + r4 * 4) * 64 + lane * 4, vS + (r0 + r4 * 4) * 64);
    }
    __syncthreads(); // staged (vmcnt drained by barrier)

    // GEMM1: kd[rows 4][m 4]; diag accumulated as k^2 in-loop (components only)
    float a1[4][4];
#pragma unroll
    for (int i = 0; i < 4; ++i) { a1[i][0] = a1[i][1] = a1[i][2] = a1[i][3] = 0.f; }
    float sq[4] = {0, 0, 0, 0};
#pragma unroll
    for (int tb = 0; tb < 16; ++tb) {
      const int td = tb * 4;
      const float4 kA = *(const float4*)(kS + (rg * 4 + 0) * 68 + td);
      const float4 kB = *(const float4*)(kS + (rg * 4 + 1) * 68 + td);
      const float4 kC = *(const float4*)(kS + (rg * 4 + 2) * 68 + td);
      const float4 kD = *(const float4*)(kS + (rg * 4 + 3) * 68 + td);
      const float4 p0 = *(const float4*)(PTs + (td + 0) * 64 + mq * 4);
      const float4 p1 = *(const float4*)(PTs + (td + 1) * 64 + mq * 4);
      const float4 p2 = *(const float4*)(PTs + (td + 2) * 64 + mq * 4);
      const float4 p3 = *(const float4*)(PTs + (td + 3) * 64 + mq * 4);
      KQ_ROW(a1[0], sq[0], kA, p0, p1, p2, p3);
      KQ_ROW(a1[1], sq[1], kB, p0, p1, p2, p3);
      KQ_ROW(a1[2], sq[2], kC, p0, p1, p2, p3);
      KQ_ROW(a1[3], sq[3], kD, p0, p1, p2, p3);
    }
    // smax on raw kd, then exp in-place
#pragma unroll
    for (int i = 0; i < 4; ++i) {
      const float dg = sq[i] * DIAG_SCALE;
      smax = fmaxf(smax, fmaxf(fmaxf(a1[i][0], a1[i][1]), fmaxf(a1[i][2], a1[i][3])));
      a1[i][0] = __expf(a1[i][0] - dg);
      a1[i][1] = __expf(a1[i][1] - dg);
      a1[i][2] = __expf(a1[i][2] - dg);
      a1[i][3] = __expf(a1[i][3] - dg);
    }
    __syncthreads(); // all kS reads done -> overwrite with kp
#pragma unroll
    for (int i = 0; i < 4; ++i) {
      float4 st;
      st.x = a1[i][0]; st.y = a1[i][1]; st.z = a1[i][2]; st.w = a1[i][3];
      *(float4*)(kS + (rg * 4 + i) * 68 + mq * 4) = st; // kp[row][m] stride 68
    }
    __syncthreads(); // kp ready
    // GEMM2: U_partial[8m][8e] += kp^T * v (n split by wave)
#pragma unroll 2
    for (int nn = 0; nn < 16; ++nn) {
      const int n = rs * 16 + nn;
      const float4 ka = *(const float4*)(kS + n * 68 + mo * 8);
      const float4 kb = *(const float4*)(kS + n * 68 + mo * 8 + 4);
      const float4 va = *(const float4*)(vS + n * 64 + eo * 8);
      const float4 vb = *(const float4*)(vS + n * 64 + eo * 8 + 4);
      const float kk[8] = {ka.x, ka.y, ka.z, ka.w, kb.x, kb.y, kb.z, kb.w};
      const float vv[8] = {va.x, va.y, va.z, va.w, vb.x, vb.y, vb.z, vb.w};
#pragma unroll
      for (int i = 0; i < 8; ++i)
#pragma unroll
        for (int j = 0; j < 8; ++j) acc2[i][j] = fmaf(kk[i], vv[j], acc2[i][j]);
      if (eo == 0) {
#pragma unroll
        for (int i = 0; i < 8; ++i) uacc[i] += kk[i];
      }
    }
  }

  // ---- epilogue: fold 4 waves' acc2 in LDS, then spread atomics ----
  __syncthreads(); // all GEMM2 reads done; kS/vS/PTs free as scratch
  {
    float* A = kS;  // col-major [idx 64][lane 64]
    float* B = PTs; // col-major [idx 64][lane 64]
    if (wv == 1) {
#pragma unroll
      for (int i = 0; i < 8; ++i)
#pragma unroll
        for (int j = 0; j < 8; ++j) A[(i * 8 + j) * 64 + lane] = acc2[i][j];
    }
    if (wv == 3) {
#pragma unroll
      for (int i = 0; i < 8; ++i)
#pragma unroll
        for (int j = 0; j < 8; ++j) B[(i * 8 + j) * 64 + lane] = acc2[i][j];
    }
    __syncthreads();
    if (wv == 0) {
#pragma unroll
      for (int i = 0; i < 8; ++i)
#pragma unroll
        for (int j = 0; j < 8; ++j) acc2[i][j] += A[(i * 8 + j) * 64 + lane];
    }
    if (wv == 2) {
#pragma unroll
      for (int i = 0; i < 8; ++i)
#pragma unroll
        for (int j = 0; j < 8; ++j) acc2[i][j] += B[(i * 8 + j) * 64 + lane];
    }
    __syncthreads();
    if (wv == 2) {
#pragma unroll
      for (int i = 0; i < 8; ++i)
#pragma unroll
        for (int j = 0; j < 8; ++j) A[(i * 8 + j) * 64 + lane] = acc2[i][j];
    }
    __syncthreads();
    if (wv == 0) {
#pragma unroll
      for (int i = 0; i < 8; ++i)
#pragma unroll
        for (int j = 0; j < 8; ++j) {
          acc2[i][j] += A[(i * 8 + j) * 64 + lane];
          A[(i * 8 + j) * 64 + lane] = acc2[i][j];
        }
    }
    __syncthreads();
    // spread atomics: 16 per thread, 4096 per block
    {
      const int l = t & 63, idxb = (t >> 6) * 16;
      float* Ub = ws + OFF_U + ((size_t)bh * 272 + mb * 64) * 64;
#pragma unroll
      for (int c = 0; c < 16; ++c) {
        const int idx = idxb + c;
        const int ml = (l & 7) * 8 + (idx >> 3);
        const int e  = (l >> 3) * 8 + (idx & 7);
        atomicAdd(Ub + (size_t)ml * 64 + e, A[idx * 64 + l]);
      }
    }
    if (eo == 0) {
#pragma unroll
      for (int i = 0; i < 8; ++i)
        atomicAdd(ws + OFF_u + (size_t)bh * 272 + mb * 64 + mo * 8 + i, uacc[i]);
    }
  }
#pragma unroll
  for (int o = 32; o > 0; o >>= 1) smax = fmaxf(smax, __shfl_xor(smax, o));
  if (lane == 0) redb[wv] = smax;
  __syncthreads();
  if (t == 0) {
    const float m = fmaxf(fmaxf(redb[0], redb[1]), fmaxf(redb[2], redb[3]));
    atomicMax((unsigned*)(ws + OFF_S), fenc(m));
  }
}

// --------------------------- K3: combine -> ctx_ext, Sc, Sk -----------------
__global__ __launch_bounds__(256) void combine_kernel(float* __restrict__ ws) {
  __shared__ float red[256];
  const int t = threadIdx.x;
  const int bh = blockIdx.x;
  const float S = fdec(((unsigned*)(ws + OFF_S))[0]);
  const float es = __expf(-S);
  const int e = t & 63, mr = t >> 6;
  const float svv = ws[OFF_SV + bh * 64 + e];
  float scp = 0.f;
  for (int mm = mr; mm < 272; mm += 4) {
    float val = 0.f;
    if (mm < 266)
      val = (es * ws[OFF_U + ((size_t)bh * 272 + mm) * 64 + e] + EPSV * svv) * INV_L;
    ws[OFF_CTX + ((size_t)bh * 272 + mm) * 68 + e] = val;
    scp += val;
  }
  red[t] = scp;
  __syncthreads();
  if (t < 64) ws[OFF_SC + bh * 64 + t] = red[t] + red[t + 64] + red[t + 128] + red[t + 192];
  __syncthreads();
  float skp = 0.f;
  for (int mm = t; mm < 272; mm += 256) {
    float km = 0.f;
    if (mm < 266) km = es * ws[OFF_u + (size_t)bh * 272 + mm] * INV_L + EPSV;
    float* cx = ws + OFF_CTX + ((size_t)bh * 272 + mm) * 68;
    cx[64] = km; cx[65] = 0.f; cx[66] = 0.f; cx[67] = 0.f;
    skp += km;
  }
  red[t] = skp;
  __syncthreads();
  for (int s = 128; s > 0; s >>= 1) {
    if (t < s) red[t] += red[t + s];
    __syncthreads();
  }
  if (t == 0) ws[OFF_SK + bh] = red[0];
}

// --------------------------- K4: q-pass -> out ------------------------------
// LDS: uni = qS[32][68] during GEMM1 (GLDS-staged), then qph[32][276].
__global__ __launch_bounds__(256) void pass_q(const float* __restrict__ qg,
                                              float* __restrict__ outg,
                                              const float* __restrict__ ws) {
  __shared__ __align__(16) float uni[8832];
  __shared__ unsigned rmx[32];
  __shared__ float Bl[32];

  const int t = threadIdx.x;
  const int nt = blockIdx.x, bh = blockIdx.y;
  const int lane = t & 63, wv = t >> 6;
  const float* qgp = qg + ((size_t)bh * 4096 + (size_t)nt * 32) * 64;

  if (t < 32) rmx[t] = 0x007FFFFFu; // enc(-inf)

  // stage qS[32][68] via GLDS (rows wv*8..wv*8+7)
#pragma unroll
  for (int r = 0; r < 8; ++r)
    glds4(qgp + (wv * 8 + r) * 64 + lane, uni + (wv * 8 + r) * 68);
  __syncthreads();

  // GEMM1 main: mq = lane (64 m-quads, m<256); rows wv*8..+7; PT ring-2 (8 rows)
  const int mq = t & 63;
  float a1[8][4];
  float sq[8] = {0, 0, 0, 0, 0, 0, 0, 0};
#pragma unroll
  for (int i = 0; i < 8; ++i) { a1[i][0] = a1[i][1] = a1[i][2] = a1[i][3] = 0.f; }
  {
    const float* ptm = ws + OFF_PT + mq * 4;
    float4 pfA0, pfA1, pfA2, pfA3, pfB0, pfB1, pfB2, pfB3;
    pfA0 = *(const float4*)(ptm + (size_t)0 * 272);
    pfA1 = *(const float4*)(ptm + (size_t)1 * 272);
    pfA2 = *(const float4*)(ptm + (size_t)2 * 272);
    pfA3 = *(const float4*)(ptm + (size_t)3 * 272);
    pfB0 = *(const float4*)(ptm + (size_t)4 * 272);
    pfB1 = *(const float4*)(ptm + (size_t)5 * 272);
    pfB2 = *(const float4*)(ptm + (size_t)6 * 272);
    pfB3 = *(const float4*)(ptm + (size_t)7 * 272);
#pragma unroll
    for (int tb = 0; tb < 16; tb += 2) {
      {
        const int td = tb * 4;
#pragma unroll
        for (int i = 0; i < 8; ++i) {
          const float4 q4 = *(const float4*)(uni + (wv * 8 + i) * 68 + td);
          KQ_ROW(a1[i], sq[i], q4, pfA0, pfA1, pfA2, pfA3);
        }
        if (tb < 14) {
          pfA0 = *(const float4*)(ptm + (size_t)(td + 8) * 272);
          pfA1 = *(const float4*)(ptm + (size_t)(td + 9) * 272);
          pfA2 = *(const float4*)(ptm + (size_t)(td + 10) * 272);
          pfA3 = *(const float4*)(ptm + (size_t)(td + 11) * 272);
        }
      }
      {
        const int td = tb * 4 + 4;
#pragma unroll
        for (int i = 0; i < 8; ++i) {
          const float4 q4 = *(const float4*)(uni + (wv * 8 + i) * 68 + td);
          KQ_ROW(a1[i], sq[i], q4, pfB0, pfB1, pfB2, pfB3);
        }
        if (tb < 14) {
          pfB0 = *(const float4*)(ptm + (size_t)(td + 8) * 272);
          pfB1 = *(const float4*)(ptm + (size_t)(td + 9) * 272);
          pfB2 = *(const float4*)(ptm + (size_t)(td + 10) * 272);
          pfB3 = *(const float4*)(ptm + (size_t)(td + 11) * 272);
        }
      }
    }
  }
  // GEMM1 tail: m_t = 256 + (t&15), rows r2, r2+1; ring-2 scalar
  float at[2] = {0.f, 0.f};
  float sqt[2] = {0.f, 0.f};
  const int mt = 256 + (t & 15);
  const int r2 = (t >> 4) * 2;
  {
    const float* ptt = ws + OFF_PT + mt;
    float ptA[4], ptB[4];
#pragma unroll
    for (int u = 0; u < 4; ++u) {
      ptA[u] = ptt[(size_t)u * 272];
      ptB[u] = ptt[(size_t)(4 + u) * 272];
    }
#pragma unroll
    for (int tb = 0; tb < 16; tb += 2) {
      {
        const int td = tb * 4;
        const float4 qx4 = *(const float4*)(uni + r2 * 68 + td);
        const float4 qy4 = *(const float4*)(uni + (r2 + 1) * 68 + td);
        const float qx[4] = {qx4.x, qx4.y, qx4.z, qx4.w};
        const float qy[4] = {qy4.x, qy4.y, qy4.z, qy4.w};
#pragma unroll
        for (int u = 0; u < 4; ++u) {
          sqt[0] = fmaf(qx[u], qx[u], sqt[0]);
          sqt[1] = fmaf(qy[u], qy[u], sqt[1]);
          at[0] = fmaf(qx[u], ptA[u], at[0]);
          at[1] = fmaf(qy[u], ptA[u], at[1]);
        }
        if (tb < 14) {
#pragma unroll
          for (int u = 0; u < 4; ++u) ptA[u] = ptt[(size_t)(td + 8 + u) * 272];
        }
      }
      {
        const int td = tb * 4 + 4;
        const float4 qx4 = *(const float4*)(uni + r2 * 68 + td);
        const float4 qy4 = *(const float4*)(uni + (r2 + 1) * 68 + td);
        const float qx[4] = {qx4.x, qx4.y, qx4.z, qx4.w};
        const float qy[4] = {qy4.x, qy4.y, qy4.z, qy4.w};
#pragma unroll
        for (int u = 0; u < 4; ++u) {
          sqt[0] = fmaf(qx[u], qx[u], sqt[0]);
          sqt[1] = fmaf(qy[u], qy[u], sqt[1]);
          at[0] = fmaf(qx[u], ptB[u], at[0]);
          at[1] = fmaf(qy[u], ptB[u], at[1]);
        }
        if (tb < 14) {
#pragma unroll
          for (int u = 0; u < 4; ++u) ptB[u] = ptt[(size_t)(td + 8 + u) * 272];
        }
      }
    }
  }
  __syncthreads(); // all qS reads complete -> uni can be rewritten as qph

  // rowmax (raw qd): main butterfly + tail group-reduce, into LDS atomicMax
#pragma unroll
  for (int i = 0; i < 8; ++i) {
    float lm = fmaxf(fmaxf(a1[i][0], a1[i][1]), fmaxf(a1[i][2], a1[i][3]));
#pragma unroll
    for (int o = 32; o > 0; o >>= 1) lm = fmaxf(lm, __shfl_xor(lm, o));
    if (lane == i) atomicMax(&rmx[wv * 8 + i], fenc(lm));
  }
#pragma unroll
  for (int s = 0; s < 2; ++s) {
    float v = (mt < 266) ? at[s] : -INFINITY;
#pragma unroll
    for (int o = 8; o > 0; o >>= 1) v = fmaxf(v, __shfl_xor(v, o));
    if ((t & 15) == 0) atomicMax(&rmx[r2 + s], fenc(v));
  }
  // exp (unstabilized, diag from registers) + store qph
#pragma unroll
  for (int i = 0; i < 8; ++i) {
    const int row = wv * 8 + i;
    const float dg = sq[i] * DIAG_SCALE;
    float4 st;
    st.x = __expf(a1[i][0] - dg);
    st.y = __expf(a1[i][1] - dg);
    st.z = __expf(a1[i][2] - dg);
    st.w = __expf(a1[i][3] - dg);
    *(float4*)(uni + row * 276 + mq * 4) = st;
  }
#pragma unroll
  for (int s = 0; s < 2; ++s) {
    const int row = r2 + s;
    uni[row * 276 + mt] = (mt < 266) ? __expf(at[s] - sqt[s] * DIAG_SCALE) : 0.f;
  }
  __syncthreads();

  // GEMM2: A[2 rows][4 cols] + B; ctx_ext from global (L2-resident), ring-2
  const int cq = t & 15, rg2 = t >> 4;
  const float* ctxg = ws + OFF_CTX + (size_t)bh * 272 * 68;
  const float* crow = ctxg + cq * 4;
  float acc[2][4] = {{0, 0, 0, 0}, {0, 0, 0, 0}};
  float accB[2] = {0.f, 0.f};
  float4 cpA0, cpA1, cpA2, cpA3, cpB0, cpB1, cpB2, cpB3;
  float cbA[4] = {0, 0, 0, 0}, cbB[4] = {0, 0, 0, 0};
  cpA0 = *(const float4*)(crow + (size_t)0 * 68);
  cpA1 = *(const float4*)(crow + (size_t)1 * 68);
  cpA2 = *(const float4*)(crow + (size_t)2 * 68);
  cpA3 = *(const float4*)(crow + (size_t)3 * 68);
  cpB0 = *(const float4*)(crow + (size_t)4 * 68);
  cpB1 = *(const float4*)(crow + (size_t)5 * 68);
  cpB2 = *(const float4*)(crow + (size_t)6 * 68);
  cpB3 = *(const float4*)(crow + (size_t)7 * 68);
  if (cq == 0) {
#pragma unroll
    for (int u = 0; u < 4; ++u) {
      cbA[u] = ctxg[(size_t)u * 68 + 64];
      cbB[u] = ctxg[(size_t)(4 + u) * 68 + 64];
    }
  }

// acc[2][4] += qa/qb scalar * C4 components (explicit components only)
#define PV_STEP(QA, QB, C4)                            \
  {                                                    \
    acc[0][0] = fmaf((QA), (C4).x, acc[0][0]);         \
    acc[0][1] = fmaf((QA), (C4).y, acc[0][1]);         \
    acc[0][2] = fmaf((QA), (C4).z, acc[0][2]);         \
    acc[0][3] = fmaf((QA), (C4).w, acc[0][3]);         \
    acc[1][0] = fmaf((QB), (C4).x, acc[1][0]);         \
    acc[1][1] = fmaf((QB), (C4).y, acc[1][1]);         \
    acc[1][2] = fmaf((QB), (C4).z, acc[1][2]);         \
    acc[1][3] = fmaf((QB), (C4).w, acc[1][3]);         \
  }

  for (int mm = 0; mm < 272; mm += 8) {
    // half A: columns mm..mm+3
    {
      const float4 qa4 = *(const float4*)(uni + (rg2 * 2) * 276 + mm);
      const float4 qb4 = *(const float4*)(uni + (rg2 * 2 + 1) * 276 + mm);
      const float qa[4] = {qa4.x, qa4.y, qa4.z, qa4.w};
      const float qb[4] = {qb4.x, qb4.y, qb4.z, qb4.w};
      PV_STEP(qa[0], qb[0], cpA0);
      PV_STEP(qa[1], qb[1], cpA1);
      PV_STEP(qa[2], qb[2], cpA2);
      PV_STEP(qa[3], qb[3], cpA3);
      if (cq == 0) {
#pragma unroll
        for (int u = 0; u < 4; ++u) {
          accB[0] = fmaf(qa[u], cbA[u], accB[0]);
          accB[1] = fmaf(qb[u], cbA[u], accB[1]);
        }
      }
      if (mm + 8 < 272) {
        cpA0 = *(const float4*)(crow + (size_t)(mm + 8) * 68);
        cpA1 = *(const float4*)(crow + (size_t)(mm + 9) * 68);
        cpA2 = *(const float4*)(crow + (size_t)(mm + 10) * 68);
        cpA3 = *(const float4*)(crow + (size_t)(mm + 11) * 68);
        if (cq == 0) {
#pragma unroll
          for (int u = 0; u < 4; ++u) cbA[u] = ctxg[(size_t)(mm + 8 + u) * 68 + 64];
        }
      }
    }
    // half B: columns mm+4..mm+7
    {
      const int m2 = mm + 4;
      const float4 qa4 = *(const float4*)(uni + (rg2 * 2) * 276 + m2);
      const float4 qb4 = *(const float4*)(uni + (rg2 * 2 + 1) * 276 + m2);
      const float qa[4] = {qa4.x, qa4.y, qa4.z, qa4.w};
      const float qb[4] = {qb4.x, qb4.y, qb4.z, qb4.w};
      PV_STEP(qa[0], qb[0], cpB0);
      PV_STEP(qa[1], qb[1], cpB1);
      PV_STEP(qa[2], qb[2], cpB2);
      PV_STEP(qa[3], qb[3], cpB3);
      if (cq == 0) {
#pragma unroll
        for (int u = 0; u < 4; ++u) {
          accB[0] = fmaf(qa[u], cbB[u], accB[0]);
          accB[1] = fmaf(qb[u], cbB[u], accB[1]);
        }
      }
      if (m2 + 8 < 272) {
        cpB0 = *(const float4*)(crow + (size_t)(m2 + 8) * 68);
        cpB1 = *(const float4*)(crow + (size_t)(m2 + 9) * 68);
        cpB2 = *(const float4*)(crow + (size_t)(m2 + 10) * 68);
        cpB3 = *(const float4*)(crow + (size_t)(m2 + 11) * 68);
        if (cq == 0) {
#pragma unroll
          for (int u = 0; u < 4; ++u) cbB[u] = ctxg[(size_t)(m2 + 8 + u) * 68 + 64];
        }
      }
    }
  }
  if (cq == 0) {
    Bl[rg2 * 2] = accB[0];
    Bl[rg2 * 2 + 1] = accB[1];
  }
  __syncthreads();

  const float4 sc4 = *(const float4*)(ws + OFF_SC + bh * 64 + cq * 4);
  const float skv = ws[OFF_SK + bh];
  float* op = outg + ((size_t)bh * 4096 + (size_t)nt * 32) * 64;
#pragma unroll
  for (int i = 0; i < 2; ++i) {
    const int row = rg2 * 2 + i;
    const float rm = fdec(rmx[row]);
    const float tt = EPSV * __expf(rm);
    const float inv = 1.0f / (Bl[row] + tt * skv);
    float4 o;
    o.x = (acc[i][0] + tt * sc4.x) * inv;
    o.y = (acc[i][1] + tt * sc4.y) * inv;
    o.z = (acc[i][2] + tt * sc4.z) * inv;
    o.w = (acc[i][3] + tt * sc4.w) * inv;
    *(float4*)(op + row * 64 + cq * 4) = o;
  }
}

// --------------------------- launch -----------------------------------------
extern "C" void kernel_launch(void* const* d_in, const int* in_sizes, int n_in,
                              void* d_out, int out_size, void* d_ws, size_t ws_size,
                              hipStream_t stream) {
  (void)in_sizes; (void)n_in; (void)out_size; (void)ws_size;
  const float* q = (const float*)d_in[0];
  const float* k = (const float*)d_in[1];
  const float* v = (const float*)d_in[2];
  const float* P = (const float*)d_in[3];
  float* out = (float*)d_out;
  float* ws = (float*)d_ws;

  // zero only the accumulated region [OFF_U, OFF_CTX)
  hipMemsetAsync((void*)(ws + OFF_U), 0, (OFF_CTX - OFF_U) * sizeof(float), stream);
  setup_kernel<<<68, 256, 0, stream>>>(P, ws);
  pass_k_fused<<<dim3(7, 32, 8), 256, 0, stream>>>(k, v, ws);
  combine_kernel<<<32, 256, 0, stream>>>(ws);
  pass_q<<<dim3(128, 32), 256, 0, stream>>>(q, out, ws);
}

// Round 5
// 569.189 us; speedup vs baseline: 2.2908x; 1.1929x over previous
//
#include <hip/hip_runtime.h>
#include <cmath>

// ---------------------------------------------------------------------------
// Performer (FAVOR+) attention, fp32, MI355X.
// Algebra: ratio cancels; k-side stabilizer S applied post-hoc (exp range safe);
// q-side rowmax applied post-hoc.
//   qph = exp(qd - diag_q)                (unstabilized)
//   U[m][e] = sum_n exp(kd - diag_k) v ;  u[m] = sum_n exp(kd - diag_k)
//   ctx'[m][e] = (e^-S U + eps sv[e]) / L ; kmean'[m] = e^-S u / L + eps
//   out = (A + eps e^{rm} Sc) / (B + eps e^{rm} Sk)
//
// R5 changes (instruction diet on both passes):
//  - pass_q GEMM2: 4rows x 4cols x m-split(2) per thread -> ctx/cb global
//    loads per thread 544 -> 272 total vec+scalar; partial-sum reduction
//    through the dead qph LDS region (stride-1, conflict-free).
//  - pass_q GEMM1 tail: PT[.,256:272) staged once into spare LDS (uni[2176..3200))
//    -> removes 64 scalar global loads per thread.
//  - k-side: sv pass folded into the tail path (m4==0 lanes accumulate
//    v-column sums); sv blocks removed (grid x 7 -> 5).
// ---------------------------------------------------------------------------

namespace {
constexpr float NORM       = 0.35355339059327379f; // 64^-0.25
constexpr float DIAG_SCALE = 0.0625f;              // 0.5 * 64^-0.5
constexpr float EPSV       = 1e-4f;
constexpr float INV_L      = 1.0f / 4096.0f;

// workspace layout (float offsets)
constexpr size_t OFF_PT  = 0;                          // PT[64][272]
constexpr size_t OFF_U   = OFF_PT + (size_t)64 * 272;  // U[32][272][64]
constexpr size_t OFF_u   = OFF_U + (size_t)32 * 272 * 64; // u[32][272]
constexpr size_t OFF_SV  = OFF_u + (size_t)32 * 272;   // sv[32][64]
constexpr size_t OFF_SC  = OFF_SV + (size_t)32 * 64;   // Sc[32][64]
constexpr size_t OFF_SK  = OFF_SC + (size_t)32 * 64;   // Sk[32]
constexpr size_t OFF_S   = OFF_SK + 32;                // S (1, encoded uint)
constexpr size_t OFF_CTX = OFF_S + 4;                  // ctx_ext[32][272][68]
constexpr size_t WS_FLOATS = OFF_CTX + (size_t)32 * 272 * 68;
} // namespace

__device__ __forceinline__ unsigned fenc(float f) {
  unsigned u = __float_as_uint(f);
  return (u & 0x80000000u) ? ~u : (u | 0x80000000u);
}
__device__ __forceinline__ float fdec(unsigned u) {
  return (u & 0x80000000u) ? __uint_as_float(u ^ 0x80000000u) : __uint_as_float(~u);
}

// async global->LDS: per-lane global src, wave-uniform LDS base (+lane*size)
__device__ __forceinline__ void glds4(const float* g, float* l) {
  __builtin_amdgcn_global_load_lds((const __attribute__((address_space(1))) void*)g,
                                   (__attribute__((address_space(3))) void*)l, 4, 0, 0);
}
__device__ __forceinline__ void glds16(const float* g, float* l) {
  __builtin_amdgcn_global_load_lds((const __attribute__((address_space(1))) void*)g,
                                   (__attribute__((address_space(3))) void*)l, 16, 0, 0);
}

// --------------------------- K0: setup -------------------------------------
__global__ __launch_bounds__(256) void setup_kernel(const float* __restrict__ P,
                                                    float* __restrict__ ws) {
  const int t = threadIdx.x;
  const int elem = blockIdx.x * 256 + t; // < 64*272 exactly (grid 68)
  const int td = elem / 272, mm = elem % 272;
  ws[OFF_PT + (size_t)td * 272 + mm] = (mm < 266) ? NORM * P[mm * 64 + td] : 0.0f;
  if (blockIdx.x == 0 && t == 0) ((unsigned*)(ws + OFF_S))[0] = 0x007FFFFFu; // enc(-inf)
}

// per-row GEMM1 micro-step: row acc a1r[4] += K4 components * p0..p3, sq += K4.K4
#define KQ_ROW(A1R, SQ, K4, P0, P1, P2, P3)                                     \
  {                                                                             \
    SQ = fmaf((K4).x, (K4).x, SQ);                                              \
    SQ = fmaf((K4).y, (K4).y, SQ);                                              \
    SQ = fmaf((K4).z, (K4).z, SQ);                                              \
    SQ = fmaf((K4).w, (K4).w, SQ);                                              \
    A1R[0] = fmaf((K4).x, (P0).x, A1R[0]);                                      \
    A1R[1] = fmaf((K4).x, (P0).y, A1R[1]);                                      \
    A1R[2] = fmaf((K4).x, (P0).z, A1R[2]);                                      \
    A1R[3] = fmaf((K4).x, (P0).w, A1R[3]);                                      \
    A1R[0] = fmaf((K4).y, (P1).x, A1R[0]);                                      \
    A1R[1] = fmaf((K4).y, (P1).y, A1R[1]);                                      \
    A1R[2] = fmaf((K4).y, (P1).z, A1R[2]);                                      \
    A1R[3] = fmaf((K4).y, (P1).w, A1R[3]);                                      \
    A1R[0] = fmaf((K4).z, (P2).x, A1R[0]);                                      \
    A1R[1] = fmaf((K4).z, (P2).y, A1R[1]);                                      \
    A1R[2] = fmaf((K4).z, (P2).z, A1R[2]);                                      \
    A1R[3] = fmaf((K4).z, (P2).w, A1R[3]);                                      \
    A1R[0] = fmaf((K4).w, (P3).x, A1R[0]);                                      \
    A1R[1] = fmaf((K4).w, (P3).y, A1R[1]);                                      \
    A1R[2] = fmaf((K4).w, (P3).z, A1R[2]);                                      \
    A1R[3] = fmaf((K4).w, (P3).w, A1R[3]);                                      \
  }

// GEMM2 micro-step: row acc AR[4] += Q4 components * c0..c3 (no sq)
#define QC_ROW(AR, Q4, C0, C1, C2, C3)                                          \
  {                                                                             \
    AR[0] = fmaf((Q4).x, (C0).x, AR[0]);                                        \
    AR[1] = fmaf((Q4).x, (C0).y, AR[1]);                                        \
    AR[2] = fmaf((Q4).x, (C0).z, AR[2]);                                        \
    AR[3] = fmaf((Q4).x, (C0).w, AR[3]);                                        \
    AR[0] = fmaf((Q4).y, (C1).x, AR[0]);                                        \
    AR[1] = fmaf((Q4).y, (C1).y, AR[1]);                                        \
    AR[2] = fmaf((Q4).y, (C1).z, AR[2]);                                        \
    AR[3] = fmaf((Q4).y, (C1).w, AR[3]);                                        \
    AR[0] = fmaf((Q4).z, (C2).x, AR[0]);                                        \
    AR[1] = fmaf((Q4).z, (C2).y, AR[1]);                                        \
    AR[2] = fmaf((Q4).z, (C2).z, AR[2]);                                        \
    AR[3] = fmaf((Q4).z, (C2).w, AR[3]);                                        \
    AR[0] = fmaf((Q4).w, (C3).x, AR[0]);                                        \
    AR[1] = fmaf((Q4).w, (C3).y, AR[1]);                                        \
    AR[2] = fmaf((Q4).w, (C3).z, AR[2]);                                        \
    AR[3] = fmaf((Q4).w, (C3).w, AR[3]);                                        \
  }

// --------------------------- K1: fused k-side pass ---------------------------
// grid (5, 32, 8):
//   x in [0,4)  : main k-pass, m-block = x (m in [0,256)), 512 rows per z
//   x == 4      : tail k-pass (m in [256,266)) + sv accumulation
__global__ __launch_bounds__(256) void pass_k_fused(const float* __restrict__ kg,
                                                    const float* __restrict__ vg,
                                                    float* __restrict__ ws) {
  __shared__ __align__(16) float pool[12544]; // PTs[4096] | kS[64][68] | vS[64][64]
  __shared__ float redb[4];

  const int t = threadIdx.x;
  const int mb = blockIdx.x, bh = blockIdx.y, bz = blockIdx.z;
  const int lane = t & 63, wv = t >> 6;

  float* PTs = pool;          // main: PT tile [td 64][m 64]; tail: PT_t[td 64][16]
  float* kS  = pool + 4096;   // k rows [row 64][d] stride 68; reused as kp
  float* vS  = pool + 8448;   // v rows [row 64][e 64] stride 64

  const size_t base = ((size_t)bh * 4096 + (size_t)bz * 512) * 64;

  if (mb == 4) {
    // =================== tail path: m in [256, 272) + sv ===================
    const int m4 = t & 3, rg1 = t >> 2;          // GEMM1: 1 row, 4 m's
    const int eg = (t >> 2) & 15, rs = t >> 6;   // GEMM2: 4m x 4e x 4 n-quarters

    // stage PT_t[64][16] once
    {
      const int td = t >> 2, m4i = t & 3;
      *(float4*)(PTs + td * 16 + m4i * 4) =
          *(const float4*)(ws + OFF_PT + (size_t)td * 272 + 256 + m4i * 4);
    }

    float acc2[4][4];
#pragma unroll
    for (int i = 0; i < 4; ++i) { acc2[i][0] = acc2[i][1] = acc2[i][2] = acc2[i][3] = 0.f; }
    float uacc[4] = {0, 0, 0, 0};
    float vsum[4] = {0, 0, 0, 0};
    float smax = -INFINITY;

    for (int sc = 0; sc < 8; ++sc) {
      const float* kgp = kg + base + (size_t)sc * 64 * 64;
      const float* vgp = vg + base + (size_t)sc * 64 * 64;
      __syncthreads(); // previous iter's LDS reads complete
      {
        const int r0 = wv * 16;
#pragma unroll
        for (int r = 0; r < 16; ++r) glds4(kgp + (r0 + r) * 64 + lane, kS + (r0 + r) * 68);
#pragma unroll
        for (int r4 = 0; r4 < 4; ++r4)
          glds16(vgp + (r0 + r4 * 4) * 64 + lane * 4, vS + (r0 + r4 * 4) * 64);
      }
      __syncthreads(); // staged
      // GEMM1: row rg1, m-quad m4; diag accumulated as k^2
      float a1[4] = {0, 0, 0, 0};
      float sqt = 0.f;
#pragma unroll
      for (int tb = 0; tb < 16; ++tb) {
        const int td = tb * 4;
        const float4 kv4 = *(const float4*)(kS + rg1 * 68 + td);
        const float4 p0 = *(const float4*)(PTs + (td + 0) * 16 + m4 * 4);
        const float4 p1 = *(const float4*)(PTs + (td + 1) * 16 + m4 * 4);
        const float4 p2 = *(const float4*)(PTs + (td + 2) * 16 + m4 * 4);
        const float4 p3 = *(const float4*)(PTs + (td + 3) * 16 + m4 * 4);
        KQ_ROW(a1, sqt, kv4, p0, p1, p2, p3);
      }
      float vals[4];
      {
        const float dg = sqt * DIAG_SCALE;
#pragma unroll
        for (int j = 0; j < 4; ++j) {
          const int m = 256 + m4 * 4 + j;
          float e = 0.f;
          if (m < 266) {
            smax = fmaxf(smax, a1[j]);
            e = __expf(a1[j] - dg);
          }
          vals[j] = e;
        }
      }
      __syncthreads(); // all kS reads done -> overwrite with kp (stride 20)
      {
        float4 st;
        st.x = vals[0]; st.y = vals[1]; st.z = vals[2]; st.w = vals[3];
        *(float4*)(kS + rg1 * 20 + m4 * 4) = st;
      }
      __syncthreads(); // kp ready
#pragma unroll 2
      for (int nn = 0; nn < 16; ++nn) {
        const int n = rs * 16 + nn;
        const float4 kk4 = *(const float4*)(kS + n * 20 + m4 * 4);
        const float4 vv4 = *(const float4*)(vS + n * 64 + eg * 4);
        const float kk[4] = {kk4.x, kk4.y, kk4.z, kk4.w};
        const float vv[4] = {vv4.x, vv4.y, vv4.z, vv4.w};
#pragma unroll
        for (int i = 0; i < 4; ++i)
#pragma unroll
          for (int j = 0; j < 4; ++j) acc2[i][j] = fmaf(kk[i], vv[j], acc2[i][j]);
        if (eg == 0) {
#pragma unroll
          for (int i = 0; i < 4; ++i) uacc[i] += kk[i];
        }
        if (m4 == 0) {
          vsum[0] += vv[0]; vsum[1] += vv[1]; vsum[2] += vv[2]; vsum[3] += vv[3];
        }
      }
    }
    {
      float* Ub = ws + OFF_U + ((size_t)bh * 272 + 256 + m4 * 4) * 64 + eg * 4;
#pragma unroll
      for (int i = 0; i < 4; ++i)
#pragma unroll
        for (int j = 0; j < 4; ++j) atomicAdd(Ub + (size_t)i * 64 + j, acc2[i][j]);
      if (eg == 0) {
#pragma unroll
        for (int i = 0; i < 4; ++i)
          atomicAdd(ws + OFF_u + (size_t)bh * 272 + 256 + m4 * 4 + i, uacc[i]);
      }
      if (m4 == 0) {
#pragma unroll
        for (int j = 0; j < 4; ++j)
          atomicAdd(ws + OFF_SV + bh * 64 + eg * 4 + j, vsum[j]);
      }
    }
#pragma unroll
    for (int o = 32; o > 0; o >>= 1) smax = fmaxf(smax, __shfl_xor(smax, o));
    if (lane == 0) redb[wv] = smax;
    __syncthreads();
    if (t == 0) {
      const float m = fmaxf(fmaxf(redb[0], redb[1]), fmaxf(redb[2], redb[3]));
      atomicMax((unsigned*)(ws + OFF_S), fenc(m));
    }
    return;
  }

  // =================== main path: m-block mb, m in [0,256) ===================
  const int mq = t & 15, rg = t >> 4;          // GEMM1: 16 m-quads x 16 row-groups(4)
  const int mo = t & 7, eo = (t >> 3) & 7;     // GEMM2: 8 m-octs x 8 e-octs
  const int rs = t >> 6;                       // GEMM2: n quarter (= wave id)

  // stage PTs[td 64][m 64] once (invariant over sc)
#pragma unroll
  for (int c = 0; c < 4; ++c) {
    const int f4 = c * 256 + t;
    const int td = f4 >> 4, mi = f4 & 15;
    *(float4*)(PTs + td * 64 + mi * 4) =
        *(const float4*)(ws + OFF_PT + (size_t)td * 272 + mb * 64 + mi * 4);
  }

  float acc2[8][8];
#pragma unroll
  for (int i = 0; i < 8; ++i)
#pragma unroll
    for (int j = 0; j < 8; ++j) acc2[i][j] = 0.f;
  float uacc[8] = {0, 0, 0, 0, 0, 0, 0, 0};
  float smax = -INFINITY;

  for (int sc = 0; sc < 8; ++sc) {
    const float* kgp = kg + base + (size_t)sc * 64 * 64;
    const float* vgp = vg + base + (size_t)sc * 64 * 64;
    __syncthreads(); // previous iter's LDS reads complete (also covers PTs staging)
    {
      const int r0 = wv * 16;
#pragma unroll
      for (int r = 0; r < 16; ++r) glds4(kgp + (r0 + r) * 64 + lane, kS + (r0 + r) * 68);
#pragma unroll
      for (int r4 = 0; r4 < 4; ++r4)
        glds16(vgp + (r0 + r4 * 4) * 64 + lane * 4, vS + (r0 + r4 * 4) * 64);
    }
    __syncthreads(); // staged (vmcnt drained by barrier)

    // GEMM1: kd[rows 4][m 4]; diag accumulated as k^2 in-loop (components only)
    float a1[4][4];
#pragma unroll
    for (int i = 0; i < 4; ++i) { a1[i][0] = a1[i][1] = a1[i][2] = a1[i][3] = 0.f; }
    float sq[4] = {0, 0, 0, 0};
#pragma unroll
    for (int tb = 0; tb < 16; ++tb) {
      const int td = tb * 4;
      const float4 kA = *(const float4*)(kS + (rg * 4 + 0) * 68 + td);
      const float4 kB = *(const float4*)(kS + (rg * 4 + 1) * 68 + td);
      const float4 kC = *(const float4*)(kS + (rg * 4 + 2) * 68 + td);
      const float4 kD = *(const float4*)(kS + (rg * 4 + 3) * 68 + td);
      const float4 p0 = *(const float4*)(PTs + (td + 0) * 64 + mq * 4);
      const float4 p1 = *(const float4*)(PTs + (td + 1) * 64 + mq * 4);
      const float4 p2 = *(const float4*)(PTs + (td + 2) * 64 + mq * 4);
      const float4 p3 = *(const float4*)(PTs + (td + 3) * 64 + mq * 4);
      KQ_ROW(a1[0], sq[0], kA, p0, p1, p2, p3);
      KQ_ROW(a1[1], sq[1], kB, p0, p1, p2, p3);
      KQ_ROW(a1[2], sq[2], kC, p0, p1, p2, p3);
      KQ_ROW(a1[3], sq[3], kD, p0, p1, p2, p3);
    }
    // smax on raw kd, then exp in-place
#pragma unroll
    for (int i = 0; i < 4; ++i) {
      const float dg = sq[i] * DIAG_SCALE;
      smax = fmaxf(smax, fmaxf(fmaxf(a1[i][0], a1[i][1]), fmaxf(a1[i][2], a1[i][3])));
      a1[i][0] = __expf(a1[i][0] - dg);
      a1[i][1] = __expf(a1[i][1] - dg);
      a1[i][2] = __expf(a1[i][2] - dg);
      a1[i][3] = __expf(a1[i][3] - dg);
    }
    __syncthreads(); // all kS reads done -> overwrite with kp
#pragma unroll
    for (int i = 0; i < 4; ++i) {
      float4 st;
      st.x = a1[i][0]; st.y = a1[i][1]; st.z = a1[i][2]; st.w = a1[i][3];
      *(float4*)(kS + (rg * 4 + i) * 68 + mq * 4) = st; // kp[row][m] stride 68
    }
    __syncthreads(); // kp ready
    // GEMM2: U_partial[8m][8e] += kp^T * v (n split by wave)
#pragma unroll 2
    for (int nn = 0; nn < 16; ++nn) {
      const int n = rs * 16 + nn;
      const float4 ka = *(const float4*)(kS + n * 68 + mo * 8);
      const float4 kb = *(const float4*)(kS + n * 68 + mo * 8 + 4);
      const float4 va = *(const float4*)(vS + n * 64 + eo * 8);
      const float4 vb = *(const float4*)(vS + n * 64 + eo * 8 + 4);
      const float kk[8] = {ka.x, ka.y, ka.z, ka.w, kb.x, kb.y, kb.z, kb.w};
      const float vv[8] = {va.x, va.y, va.z, va.w, vb.x, vb.y, vb.z, vb.w};
#pragma unroll
      for (int i = 0; i < 8; ++i)
#pragma unroll
        for (int j = 0; j < 8; ++j) acc2[i][j] = fmaf(kk[i], vv[j], acc2[i][j]);
      if (eo == 0) {
#pragma unroll
        for (int i = 0; i < 8; ++i) uacc[i] += kk[i];
      }
    }
  }

  // ---- epilogue: fold 4 waves' acc2 in LDS, then spread atomics ----
  __syncthreads(); // all GEMM2 reads done; kS/vS/PTs free as scratch
  {
    float* A = kS;  // col-major [idx 64][lane 64]
    float* B = PTs; // col-major [idx 64][lane 64]
    if (wv == 1) {
#pragma unroll
      for (int i = 0; i < 8; ++i)
#pragma unroll
        for (int j = 0; j < 8; ++j) A[(i * 8 + j) * 64 + lane] = acc2[i][j];
    }
    if (wv == 3) {
#pragma unroll
      for (int i = 0; i < 8; ++i)
#pragma unroll
        for (int j = 0; j < 8; ++j) B[(i * 8 + j) * 64 + lane] = acc2[i][j];
    }
    __syncthreads();
    if (wv == 0) {
#pragma unroll
      for (int i = 0; i < 8; ++i)
#pragma unroll
        for (int j = 0; j < 8; ++j) acc2[i][j] += A[(i * 8 + j) * 64 + lane];
    }
    if (wv == 2) {
#pragma unroll
      for (int i = 0; i < 8; ++i)
#pragma unroll
        for (int j = 0; j < 8; ++j) acc2[i][j] += B[(i * 8 + j) * 64 + lane];
    }
    __syncthreads();
    if (wv == 2) {
#pragma unroll
      for (int i = 0; i < 8; ++i)
#pragma unroll
        for (int j = 0; j < 8; ++j) A[(i * 8 + j) * 64 + lane] = acc2[i][j];
    }
    __syncthreads();
    if (wv == 0) {
#pragma unroll
      for (int i = 0; i < 8; ++i)
#pragma unroll
        for (int j = 0; j < 8; ++j) {
          acc2[i][j] += A[(i * 8 + j) * 64 + lane];
          A[(i * 8 + j) * 64 + lane] = acc2[i][j];
        }
    }
    __syncthreads();
    // spread atomics: 16 per thread, 4096 per block
    {
      const int l = t & 63, idxb = (t >> 6) * 16;
      float* Ub = ws + OFF_U + ((size_t)bh * 272 + mb * 64) * 64;
#pragma unroll
      for (int c = 0; c < 16; ++c) {
        const int idx = idxb + c;
        const int ml = (l & 7) * 8 + (idx >> 3);
        const int e  = (l >> 3) * 8 + (idx & 7);
        atomicAdd(Ub + (size_t)ml * 64 + e, A[idx * 64 + l]);
      }
    }
    if (eo == 0) {
#pragma unroll
      for (int i = 0; i < 8; ++i)
        atomicAdd(ws + OFF_u + (size_t)bh * 272 + mb * 64 + mo * 8 + i, uacc[i]);
    }
  }
#pragma unroll
  for (int o = 32; o > 0; o >>= 1) smax = fmaxf(smax, __shfl_xor(smax, o));
  if (lane == 0) redb[wv] = smax;
  __syncthreads();
  if (t == 0) {
    const float m = fmaxf(fmaxf(redb[0], redb[1]), fmaxf(redb[2], redb[3]));
    atomicMax((unsigned*)(ws + OFF_S), fenc(m));
  }
}

// --------------------------- K3: combine -> ctx_ext, Sc, Sk -----------------
__global__ __launch_bounds__(256) void combine_kernel(float* __restrict__ ws) {
  __shared__ float red[256];
  const int t = threadIdx.x;
  const int bh = blockIdx.x;
  const float S = fdec(((unsigned*)(ws + OFF_S))[0]);
  const float es = __expf(-S);
  const int e = t & 63, mr = t >> 6;
  const float svv = ws[OFF_SV + bh * 64 + e];
  float scp = 0.f;
  for (int mm = mr; mm < 272; mm += 4) {
    float val = 0.f;
    if (mm < 266)
      val = (es * ws[OFF_U + ((size_t)bh * 272 + mm) * 64 + e] + EPSV * svv) * INV_L;
    ws[OFF_CTX + ((size_t)bh * 272 + mm) * 68 + e] = val;
    scp += val;
  }
  red[t] = scp;
  __syncthreads();
  if (t < 64) ws[OFF_SC + bh * 64 + t] = red[t] + red[t + 64] + red[t + 128] + red[t + 192];
  __syncthreads();
  float skp = 0.f;
  for (int mm = t; mm < 272; mm += 256) {
    float km = 0.f;
    if (mm < 266) km = es * ws[OFF_u + (size_t)bh * 272 + mm] * INV_L + EPSV;
    float* cx = ws + OFF_CTX + ((size_t)bh * 272 + mm) * 68;
    cx[64] = km; cx[65] = 0.f; cx[66] = 0.f; cx[67] = 0.f;
    skp += km;
  }
  red[t] = skp;
  __syncthreads();
  for (int s = 128; s > 0; s >>= 1) {
    if (t < s) red[t] += red[t + s];
    __syncthreads();
  }
  if (t == 0) ws[OFF_SK + bh] = red[0];
}

// --------------------------- K4: q-pass -> out ------------------------------
// LDS: uni = qS[32][68] + PTt[64][16]@2176 during GEMM1, then qph[32][276],
// then reduction scratch for GEMM2.
__global__ __launch_bounds__(256) void pass_q(const float* __restrict__ qg,
                                              float* __restrict__ outg,
                                              const float* __restrict__ ws) {
  __shared__ __align__(16) float uni[8832];
  __shared__ unsigned rmx[32];
  __shared__ float Bl[32];

  const int t = threadIdx.x;
  const int nt = blockIdx.x, bh = blockIdx.y;
  const int lane = t & 63, wv = t >> 6;
  const float* qgp = qg + ((size_t)bh * 4096 + (size_t)nt * 32) * 64;

  if (t < 32) rmx[t] = 0x007FFFFFu; // enc(-inf)

  // stage qS[32][68] via GLDS (rows wv*8..wv*8+7); qS occupies uni[0..2172)
#pragma unroll
  for (int r = 0; r < 8; ++r)
    glds4(qgp + (wv * 8 + r) * 64 + lane, uni + (wv * 8 + r) * 68);
  // stage tail PT[64][16] into uni[2176..3200) (spare space above qS)
  {
    const int td = t >> 2, j4 = t & 3;
    *(float4*)(uni + 2176 + td * 16 + j4 * 4) =
        *(const float4*)(ws + OFF_PT + (size_t)td * 272 + 256 + j4 * 4);
  }
  __syncthreads();

  // GEMM1 main: mq = lane (64 m-quads, m<256); rows wv*8..+7; PT ring-2 (8 rows)
  const int mq = t & 63;
  float a1[8][4];
  float sq[8] = {0, 0, 0, 0, 0, 0, 0, 0};
#pragma unroll
  for (int i = 0; i < 8; ++i) { a1[i][0] = a1[i][1] = a1[i][2] = a1[i][3] = 0.f; }
  {
    const float* ptm = ws + OFF_PT + mq * 4;
    float4 pfA0, pfA1, pfA2, pfA3, pfB0, pfB1, pfB2, pfB3;
    pfA0 = *(const float4*)(ptm + (size_t)0 * 272);
    pfA1 = *(const float4*)(ptm + (size_t)1 * 272);
    pfA2 = *(const float4*)(ptm + (size_t)2 * 272);
    pfA3 = *(const float4*)(ptm + (size_t)3 * 272);
    pfB0 = *(const float4*)(ptm + (size_t)4 * 272);
    pfB1 = *(const float4*)(ptm + (size_t)5 * 272);
    pfB2 = *(const float4*)(ptm + (size_t)6 * 272);
    pfB3 = *(const float4*)(ptm + (size_t)7 * 272);
#pragma unroll
    for (int tb = 0; tb < 16; tb += 2) {
      {
        const int td = tb * 4;
#pragma unroll
        for (int i = 0; i < 8; ++i) {
          const float4 q4 = *(const float4*)(uni + (wv * 8 + i) * 68 + td);
          KQ_ROW(a1[i], sq[i], q4, pfA0, pfA1, pfA2, pfA3);
        }
        if (tb < 14) {
          pfA0 = *(const float4*)(ptm + (size_t)(td + 8) * 272);
          pfA1 = *(const float4*)(ptm + (size_t)(td + 9) * 272);
          pfA2 = *(const float4*)(ptm + (size_t)(td + 10) * 272);
          pfA3 = *(const float4*)(ptm + (size_t)(td + 11) * 272);
        }
      }
      {
        const int td = tb * 4 + 4;
#pragma unroll
        for (int i = 0; i < 8; ++i) {
          const float4 q4 = *(const float4*)(uni + (wv * 8 + i) * 68 + td);
          KQ_ROW(a1[i], sq[i], q4, pfB0, pfB1, pfB2, pfB3);
        }
        if (tb < 14) {
          pfB0 = *(const float4*)(ptm + (size_t)(td + 8) * 272);
          pfB1 = *(const float4*)(ptm + (size_t)(td + 9) * 272);
          pfB2 = *(const float4*)(ptm + (size_t)(td + 10) * 272);
          pfB3 = *(const float4*)(ptm + (size_t)(td + 11) * 272);
        }
      }
    }
  }
  // GEMM1 tail: m_t = 256 + (t&15), rows r2, r2+1; PTt from LDS
  float at[2] = {0.f, 0.f};
  float sqt[2] = {0.f, 0.f};
  const int mtl = t & 15;
  const int mt = 256 + mtl;
  const int r2 = (t >> 4) * 2;
  {
    const float* pts = uni + 2176 + mtl;
#pragma unroll
    for (int tb = 0; tb < 16; ++tb) {
      const int td = tb * 4;
      const float4 qx4 = *(const float4*)(uni + r2 * 68 + td);
      const float4 qy4 = *(const float4*)(uni + (r2 + 1) * 68 + td);
      const float p0 = pts[(td + 0) * 16];
      const float p1 = pts[(td + 1) * 16];
      const float p2 = pts[(td + 2) * 16];
      const float p3 = pts[(td + 3) * 16];
      sqt[0] = fmaf(qx4.x, qx4.x, sqt[0]);
      sqt[0] = fmaf(qx4.y, qx4.y, sqt[0]);
      sqt[0] = fmaf(qx4.z, qx4.z, sqt[0]);
      sqt[0] = fmaf(qx4.w, qx4.w, sqt[0]);
      sqt[1] = fmaf(qy4.x, qy4.x, sqt[1]);
      sqt[1] = fmaf(qy4.y, qy4.y, sqt[1]);
      sqt[1] = fmaf(qy4.z, qy4.z, sqt[1]);
      sqt[1] = fmaf(qy4.w, qy4.w, sqt[1]);
      at[0] = fmaf(qx4.x, p0, at[0]);
      at[0] = fmaf(qx4.y, p1, at[0]);
      at[0] = fmaf(qx4.z, p2, at[0]);
      at[0] = fmaf(qx4.w, p3, at[0]);
      at[1] = fmaf(qy4.x, p0, at[1]);
      at[1] = fmaf(qy4.y, p1, at[1]);
      at[1] = fmaf(qy4.z, p2, at[1]);
      at[1] = fmaf(qy4.w, p3, at[1]);
    }
  }
  __syncthreads(); // all qS/PTt reads complete -> uni can be rewritten as qph

  // rowmax (raw qd): main butterfly + tail group-reduce, into LDS atomicMax
#pragma unroll
  for (int i = 0; i < 8; ++i) {
    float lm = fmaxf(fmaxf(a1[i][0], a1[i][1]), fmaxf(a1[i][2], a1[i][3]));
#pragma unroll
    for (int o = 32; o > 0; o >>= 1) lm = fmaxf(lm, __shfl_xor(lm, o));
    if (lane == i) atomicMax(&rmx[wv * 8 + i], fenc(lm));
  }
#pragma unroll
  for (int s = 0; s < 2; ++s) {
    float v = (mt < 266) ? at[s] : -INFINITY;
#pragma unroll
    for (int o = 8; o > 0; o >>= 1) v = fmaxf(v, __shfl_xor(v, o));
    if ((t & 15) == 0) atomicMax(&rmx[r2 + s], fenc(v));
  }
  // exp (unstabilized, diag from registers) + store qph
#pragma unroll
  for (int i = 0; i < 8; ++i) {
    const int row = wv * 8 + i;
    const float dg = sq[i] * DIAG_SCALE;
    float4 st;
    st.x = __expf(a1[i][0] - dg);
    st.y = __expf(a1[i][1] - dg);
    st.z = __expf(a1[i][2] - dg);
    st.w = __expf(a1[i][3] - dg);
    *(float4*)(uni + row * 276 + mq * 4) = st;
  }
#pragma unroll
  for (int s = 0; s < 2; ++s) {
    const int row = r2 + s;
    uni[row * 276 + mt] = (mt < 266) ? __expf(at[s] - sqt[s] * DIAG_SCALE) : 0.f;
  }
  __syncthreads();

  // GEMM2: 4 rows x 4 cols x m-split(2). cq2 = e-quad, rg2 = 4-row group,
  // ms = m-half. ctx streamed from global (L2-resident) with ring-1 prefetch.
  const int cq2 = t & 15, rg2 = (t >> 4) & 7, ms = t >> 7;
  const float* ctxg = ws + OFF_CTX + (size_t)bh * 272 * 68;
  const float* crow = ctxg + cq2 * 4;
  const int mb0 = ms * 136;
  float acc[4][4];
#pragma unroll
  for (int i = 0; i < 4; ++i) { acc[i][0] = acc[i][1] = acc[i][2] = acc[i][3] = 0.f; }
  float accB[4] = {0, 0, 0, 0};
  float4 c0, c1, c2, c3, n0, n1, n2, n3;
  float cb0 = 0, cb1 = 0, cb2 = 0, cb3 = 0, nb0 = 0, nb1 = 0, nb2 = 0, nb3 = 0;
  c0 = *(const float4*)(crow + (size_t)(mb0 + 0) * 68);
  c1 = *(const float4*)(crow + (size_t)(mb0 + 1) * 68);
  c2 = *(const float4*)(crow + (size_t)(mb0 + 2) * 68);
  c3 = *(const float4*)(crow + (size_t)(mb0 + 3) * 68);
  if (cq2 == 0) {
    cb0 = ctxg[(size_t)(mb0 + 0) * 68 + 64];
    cb1 = ctxg[(size_t)(mb0 + 1) * 68 + 64];
    cb2 = ctxg[(size_t)(mb0 + 2) * 68 + 64];
    cb3 = ctxg[(size_t)(mb0 + 3) * 68 + 64];
  }
  for (int mc = 0; mc < 34; ++mc) {
    const int mm = mb0 + mc * 4;
    if (mc < 33) {
      n0 = *(const float4*)(crow + (size_t)(mm + 4) * 68);
      n1 = *(const float4*)(crow + (size_t)(mm + 5) * 68);
      n2 = *(const float4*)(crow + (size_t)(mm + 6) * 68);
      n3 = *(const float4*)(crow + (size_t)(mm + 7) * 68);
      if (cq2 == 0) {
        nb0 = ctxg[(size_t)(mm + 4) * 68 + 64];
        nb1 = ctxg[(size_t)(mm + 5) * 68 + 64];
        nb2 = ctxg[(size_t)(mm + 6) * 68 + 64];
        nb3 = ctxg[(size_t)(mm + 7) * 68 + 64];
      }
    }
    const float4 q0 = *(const float4*)(uni + (rg2 * 4 + 0) * 276 + mm);
    const float4 q1 = *(const float4*)(uni + (rg2 * 4 + 1) * 276 + mm);
    const float4 q2 = *(const float4*)(uni + (rg2 * 4 + 2) * 276 + mm);
    const float4 q3 = *(const float4*)(uni + (rg2 * 4 + 3) * 276 + mm);
    QC_ROW(acc[0], q0, c0, c1, c2, c3);
    QC_ROW(acc[1], q1, c0, c1, c2, c3);
    QC_ROW(acc[2], q2, c0, c1, c2, c3);
    QC_ROW(acc[3], q3, c0, c1, c2, c3);
    if (cq2 == 0) {
      accB[0] = fmaf(q0.x, cb0, accB[0]);
      accB[0] = fmaf(q0.y, cb1, accB[0]);
      accB[0] = fmaf(q0.z, cb2, accB[0]);
      accB[0] = fmaf(q0.w, cb3, accB[0]);
      accB[1] = fmaf(q1.x, cb0, accB[1]);
      accB[1] = fmaf(q1.y, cb1, accB[1]);
      accB[1] = fmaf(q1.z, cb2, accB[1]);
      accB[1] = fmaf(q1.w, cb3, accB[1]);
      accB[2] = fmaf(q2.x, cb0, accB[2]);
      accB[2] = fmaf(q2.y, cb1, accB[2]);
      accB[2] = fmaf(q2.z, cb2, accB[2]);
      accB[2] = fmaf(q2.w, cb3, accB[2]);
      accB[3] = fmaf(q3.x, cb0, accB[3]);
      accB[3] = fmaf(q3.y, cb1, accB[3]);
      accB[3] = fmaf(q3.z, cb2, accB[3]);
      accB[3] = fmaf(q3.w, cb3, accB[3]);
    }
    if (mc < 33) {
      c0 = n0; c1 = n1; c2 = n2; c3 = n3;
      cb0 = nb0; cb1 = nb1; cb2 = nb2; cb3 = nb3;
    }
  }

  // reduce the two m-halves through LDS (qph dead now), stride-1 layout
  __syncthreads(); // all qph reads complete
  if (ms == 1) {
    const int p = t - 128;
#pragma unroll
    for (int i = 0; i < 4; ++i)
#pragma unroll
      for (int j = 0; j < 4; ++j) uni[(i * 4 + j) * 128 + p] = acc[i][j];
    if (cq2 == 0) {
#pragma unroll
      for (int i = 0; i < 4; ++i) uni[2048 + rg2 * 4 + i] = accB[i];
    }
  }
  __syncthreads();
  if (ms == 0) {
#pragma unroll
    for (int i = 0; i < 4; ++i)
#pragma unroll
      for (int j = 0; j < 4; ++j) acc[i][j] += uni[(i * 4 + j) * 128 + t];
    if (cq2 == 0) {
#pragma unroll
      for (int i = 0; i < 4; ++i) Bl[rg2 * 4 + i] = accB[i] + uni[2048 + rg2 * 4 + i];
    }
  }
  __syncthreads(); // Bl ready

  if (ms == 0) {
    const float4 sc4 = *(const float4*)(ws + OFF_SC + bh * 64 + cq2 * 4);
    const float skv = ws[OFF_SK + bh];
    float* op = outg + ((size_t)bh * 4096 + (size_t)nt * 32) * 64;
#pragma unroll
    for (int i = 0; i < 4; ++i) {
      const int row = rg2 * 4 + i;
      const float rm = fdec(rmx[row]);
      const float tt = EPSV * __expf(rm);
      const float inv = 1.0f / (Bl[row] + tt * skv);
      float4 o;
      o.x = (acc[i][0] + tt * sc4.x) * inv;
      o.y = (acc[i][1] + tt * sc4.y) * inv;
      o.z = (acc[i][2] + tt * sc4.z) * inv;
      o.w = (acc[i][3] + tt * sc4.w) * inv;
      *(float4*)(op + row * 64 + cq2 * 4) = o;
    }
  }
}

// --------------------------- launch -----------------------------------------
extern "C" void kernel_launch(void* const* d_in, const int* in_sizes, int n_in,
                              void* d_out, int out_size, void* d_ws, size_t ws_size,
                              hipStream_t stream) {
  (void)in_sizes; (void)n_in; (void)out_size; (void)ws_size;
  const float* q = (const float*)d_in[0];
  const float* k = (const float*)d_in[1];
  const float* v = (const float*)d_in[2];
  const float* P = (const float*)d_in[3];
  float* out = (float*)d_out;
  float* ws = (float*)d_ws;

  // zero only the accumulated region [OFF_U, OFF_CTX)
  hipMemsetAsync((void*)(ws + OFF_U), 0, (OFF_CTX - OFF_U) * sizeof(float), stream);
  setup_kernel<<<68, 256, 0, stream>>>(P, ws);
  pass_k_fused<<<dim3(5, 32, 8), 256, 0, stream>>>(k, v, ws);
  combine_kernel<<<32, 256, 0, stream>>>(ws);
  pass_q<<<dim3(128, 32), 256, 0, stream>>>(q, out, ws);
}

// Round 6
// 488.335 us; speedup vs baseline: 2.6701x; 1.1656x over previous
//
#include <hip/hip_runtime.h>
#include <cmath>

// ---------------------------------------------------------------------------
// Performer (FAVOR+) attention, fp32, MI355X.
// Algebra: ratio cancels; k-side stabilizer S applied post-hoc (exp range safe);
// q-side rowmax applied post-hoc.
//   qph = exp(qd - diag_q)                (unstabilized)
//   U[m][e] = sum_n exp(kd - diag_k) v ;  u[m] = sum_n exp(kd - diag_k)
//   ctx'[m][e] = (e^-S U + eps sv[e]) / L ; kmean'[m] = e^-S u / L + eps
//   out = (A + eps e^{rm} Sc) / (B + eps e^{rm} Sk)
//
// R6 changes:
//  - pass_k z-split 8->4: 640 blocks <= 768 resident slots (3/CU LDS cap) ->
//    single scheduling round; halves cross-XCD atomic contention.
//  - pass_k epilogue: final U written to padded LDS [64][65], then each wave
//    atomicAdds contiguous 256B rows (line-coalesced; was 16 scattered
//    lines/instr -> atomic line ping-pong was ~130MB of FETCH+WRITE).
//  - both kernels: removed duplicated per-row sq FMAs from GEMM1 (20% of its
//    VALU); diag computed once in a post-stage pre-phase (shuffle-reduce
//    into diagS[]).
//  - pass_q qph stride 276->272.
// ---------------------------------------------------------------------------

namespace {
constexpr float NORM       = 0.35355339059327379f; // 64^-0.25
constexpr float DIAG_SCALE = 0.0625f;              // 0.5 * 64^-0.5
constexpr float EPSV       = 1e-4f;
constexpr float INV_L      = 1.0f / 4096.0f;

// workspace layout (float offsets)
constexpr size_t OFF_PT  = 0;                          // PT[64][272]
constexpr size_t OFF_U   = OFF_PT + (size_t)64 * 272;  // U[32][272][64]
constexpr size_t OFF_u   = OFF_U + (size_t)32 * 272 * 64; // u[32][272]
constexpr size_t OFF_SV  = OFF_u + (size_t)32 * 272;   // sv[32][64]
constexpr size_t OFF_SC  = OFF_SV + (size_t)32 * 64;   // Sc[32][64]
constexpr size_t OFF_SK  = OFF_SC + (size_t)32 * 64;   // Sk[32]
constexpr size_t OFF_S   = OFF_SK + 32;                // S (1, encoded uint)
constexpr size_t OFF_CTX = OFF_S + 4;                  // ctx_ext[32][272][68]
constexpr size_t WS_FLOATS = OFF_CTX + (size_t)32 * 272 * 68;
} // namespace

__device__ __forceinline__ unsigned fenc(float f) {
  unsigned u = __float_as_uint(f);
  return (u & 0x80000000u) ? ~u : (u | 0x80000000u);
}
__device__ __forceinline__ float fdec(unsigned u) {
  return (u & 0x80000000u) ? __uint_as_float(u ^ 0x80000000u) : __uint_as_float(~u);
}

// async global->LDS: per-lane global src, wave-uniform LDS base (+lane*size)
__device__ __forceinline__ void glds4(const float* g, float* l) {
  __builtin_amdgcn_global_load_lds((const __attribute__((address_space(1))) void*)g,
                                   (__attribute__((address_space(3))) void*)l, 4, 0, 0);
}
__device__ __forceinline__ void glds16(const float* g, float* l) {
  __builtin_amdgcn_global_load_lds((const __attribute__((address_space(1))) void*)g,
                                   (__attribute__((address_space(3))) void*)l, 16, 0, 0);
}

// --------------------------- K0: setup -------------------------------------
__global__ __launch_bounds__(256) void setup_kernel(const float* __restrict__ P,
                                                    float* __restrict__ ws) {
  const int t = threadIdx.x;
  const int elem = blockIdx.x * 256 + t; // < 64*272 exactly (grid 68)
  const int td = elem / 272, mm = elem % 272;
  ws[OFF_PT + (size_t)td * 272 + mm] = (mm < 266) ? NORM * P[mm * 64 + td] : 0.0f;
  if (blockIdx.x == 0 && t == 0) ((unsigned*)(ws + OFF_S))[0] = 0x007FFFFFu; // enc(-inf)
}

// per-row GEMM1 micro-step: row acc a1r[4] += K4 components * p0..p3 (16 FMA)
#define KQ_ROW(A1R, K4, P0, P1, P2, P3)                                         \
  {                                                                             \
    A1R[0] = fmaf((K4).x, (P0).x, A1R[0]);                                      \
    A1R[1] = fmaf((K4).x, (P0).y, A1R[1]);                                      \
    A1R[2] = fmaf((K4).x, (P0).z, A1R[2]);                                      \
    A1R[3] = fmaf((K4).x, (P0).w, A1R[3]);                                      \
    A1R[0] = fmaf((K4).y, (P1).x, A1R[0]);                                      \
    A1R[1] = fmaf((K4).y, (P1).y, A1R[1]);                                      \
    A1R[2] = fmaf((K4).y, (P1).z, A1R[2]);                                      \
    A1R[3] = fmaf((K4).y, (P1).w, A1R[3]);                                      \
    A1R[0] = fmaf((K4).z, (P2).x, A1R[0]);                                      \
    A1R[1] = fmaf((K4).z, (P2).y, A1R[1]);                                      \
    A1R[2] = fmaf((K4).z, (P2).z, A1R[2]);                                      \
    A1R[3] = fmaf((K4).z, (P2).w, A1R[3]);                                      \
    A1R[0] = fmaf((K4).w, (P3).x, A1R[0]);                                      \
    A1R[1] = fmaf((K4).w, (P3).y, A1R[1]);                                      \
    A1R[2] = fmaf((K4).w, (P3).z, A1R[2]);                                      \
    A1R[3] = fmaf((K4).w, (P3).w, A1R[3]);                                      \
  }

// GEMM2 micro-step: row acc AR[4] += Q4 components * c0..c3
#define QC_ROW(AR, Q4, C0, C1, C2, C3)                                          \
  {                                                                             \
    AR[0] = fmaf((Q4).x, (C0).x, AR[0]);                                        \
    AR[1] = fmaf((Q4).x, (C0).y, AR[1]);                                        \
    AR[2] = fmaf((Q4).x, (C0).z, AR[2]);                                        \
    AR[3] = fmaf((Q4).x, (C0).w, AR[3]);                                        \
    AR[0] = fmaf((Q4).y, (C1).x, AR[0]);                                        \
    AR[1] = fmaf((Q4).y, (C1).y, AR[1]);                                        \
    AR[2] = fmaf((Q4).y, (C1).z, AR[2]);                                        \
    AR[3] = fmaf((Q4).y, (C1).w, AR[3]);                                        \
    AR[0] = fmaf((Q4).z, (C2).x, AR[0]);                                        \
    AR[1] = fmaf((Q4).z, (C2).y, AR[1]);                                        \
    AR[2] = fmaf((Q4).z, (C2).z, AR[2]);                                        \
    AR[3] = fmaf((Q4).z, (C2).w, AR[3]);                                        \
    AR[0] = fmaf((Q4).w, (C3).x, AR[0]);                                        \
    AR[1] = fmaf((Q4).w, (C3).y, AR[1]);                                        \
    AR[2] = fmaf((Q4).w, (C3).z, AR[2]);                                        \
    AR[3] = fmaf((Q4).w, (C3).w, AR[3]);                                        \
  }

// --------------------------- K1: fused k-side pass ---------------------------
// grid (5, 32, 4):
//   x in [0,4)  : main k-pass, m-block = x (m in [0,256)), 1024 rows per z
//   x == 4      : tail k-pass (m in [256,266)) + sv accumulation
__global__ __launch_bounds__(256) void pass_k_fused(const float* __restrict__ kg,
                                                    const float* __restrict__ vg,
                                                    float* __restrict__ ws) {
  __shared__ __align__(16) float pool[12544]; // PTs[4096] | kS[64*68] | vS[64*64]
  __shared__ float diagS[64];
  __shared__ float redb[4];

  const int t = threadIdx.x;
  const int mb = blockIdx.x, bh = blockIdx.y, bz = blockIdx.z;
  const int lane = t & 63, wv = t >> 6;

  float* PTs = pool;          // main: PT tile [td 64][m 64]; tail: PT_t[td 64][16]
  float* kS  = pool + 4096;   // k rows [row 64][d] stride 68; reused as kp / U-pad
  float* vS  = pool + 8448;   // v rows [row 64][e 64] stride 64

  const size_t base = ((size_t)bh * 4096 + (size_t)bz * 1024) * 64;

  if (mb == 4) {
    // =================== tail path: m in [256, 272) + sv ===================
    const int m4 = t & 3, rg1 = t >> 2;          // GEMM1: 1 row, 4 m's
    const int eg = (t >> 2) & 15, rs = t >> 6;   // GEMM2: 4m x 4e x 4 n-quarters

    // stage PT_t[64][16] once
    {
      const int td = t >> 2, m4i = t & 3;
      *(float4*)(PTs + td * 16 + m4i * 4) =
          *(const float4*)(ws + OFF_PT + (size_t)td * 272 + 256 + m4i * 4);
    }

    float acc2[4][4];
#pragma unroll
    for (int i = 0; i < 4; ++i) { acc2[i][0] = acc2[i][1] = acc2[i][2] = acc2[i][3] = 0.f; }
    float uacc[4] = {0, 0, 0, 0};
    float vsum[4] = {0, 0, 0, 0};
    float smax = -INFINITY;

    for (int sc = 0; sc < 16; ++sc) {
      const float* kgp = kg + base + (size_t)sc * 64 * 64;
      const float* vgp = vg + base + (size_t)sc * 64 * 64;
      __syncthreads(); // previous iter's LDS reads complete
      {
        const int r0 = wv * 16;
#pragma unroll
        for (int r = 0; r < 16; ++r) glds4(kgp + (r0 + r) * 64 + lane, kS + (r0 + r) * 68);
#pragma unroll
        for (int r4 = 0; r4 < 4; ++r4)
          glds16(vgp + (r0 + r4 * 4) * 64 + lane * 4, vS + (r0 + r4 * 4) * 64);
      }
      __syncthreads(); // staged
      // diag pre-phase: row t>>2, quarter t&3
      {
        const int dr = t >> 2, dq = t & 3;
        const float4 s0 = *(const float4*)(kS + dr * 68 + dq * 16);
        const float4 s1 = *(const float4*)(kS + dr * 68 + dq * 16 + 4);
        const float4 s2 = *(const float4*)(kS + dr * 68 + dq * 16 + 8);
        const float4 s3 = *(const float4*)(kS + dr * 68 + dq * 16 + 12);
        float s = s0.x * s0.x;
        s = fmaf(s0.y, s0.y, s); s = fmaf(s0.z, s0.z, s); s = fmaf(s0.w, s0.w, s);
        s = fmaf(s1.x, s1.x, s); s = fmaf(s1.y, s1.y, s); s = fmaf(s1.z, s1.z, s);
        s = fmaf(s1.w, s1.w, s);
        s = fmaf(s2.x, s2.x, s); s = fmaf(s2.y, s2.y, s); s = fmaf(s2.z, s2.z, s);
        s = fmaf(s2.w, s2.w, s);
        s = fmaf(s3.x, s3.x, s); s = fmaf(s3.y, s3.y, s); s = fmaf(s3.z, s3.z, s);
        s = fmaf(s3.w, s3.w, s);
        s += __shfl_xor(s, 1);
        s += __shfl_xor(s, 2);
        if (dq == 0) diagS[dr] = s * DIAG_SCALE;
      }
      __syncthreads(); // diagS ready
      // GEMM1: row rg1, m-quad m4
      float a1[4] = {0, 0, 0, 0};
#pragma unroll
      for (int tb = 0; tb < 16; ++tb) {
        const int td = tb * 4;
        const float4 kv4 = *(const float4*)(kS + rg1 * 68 + td);
        const float4 p0 = *(const float4*)(PTs + (td + 0) * 16 + m4 * 4);
        const float4 p1 = *(const float4*)(PTs + (td + 1) * 16 + m4 * 4);
        const float4 p2 = *(const float4*)(PTs + (td + 2) * 16 + m4 * 4);
        const float4 p3 = *(const float4*)(PTs + (td + 3) * 16 + m4 * 4);
        KQ_ROW(a1, kv4, p0, p1, p2, p3);
      }
      float vals[4];
      {
        const float dg = diagS[rg1];
#pragma unroll
        for (int j = 0; j < 4; ++j) {
          const int m = 256 + m4 * 4 + j;
          float e = 0.f;
          if (m < 266) {
            smax = fmaxf(smax, a1[j]);
            e = __expf(a1[j] - dg);
          }
          vals[j] = e;
        }
      }
      __syncthreads(); // all kS reads done -> overwrite with kp (stride 20)
      {
        float4 st;
        st.x = vals[0]; st.y = vals[1]; st.z = vals[2]; st.w = vals[3];
        *(float4*)(kS + rg1 * 20 + m4 * 4) = st;
      }
      __syncthreads(); // kp ready
#pragma unroll 2
      for (int nn = 0; nn < 16; ++nn) {
        const int n = rs * 16 + nn;
        const float4 kk4 = *(const float4*)(kS + n * 20 + m4 * 4);
        const float4 vv4 = *(const float4*)(vS + n * 64 + eg * 4);
        const float kk[4] = {kk4.x, kk4.y, kk4.z, kk4.w};
        const float vv[4] = {vv4.x, vv4.y, vv4.z, vv4.w};
#pragma unroll
        for (int i = 0; i < 4; ++i)
#pragma unroll
          for (int j = 0; j < 4; ++j) acc2[i][j] = fmaf(kk[i], vv[j], acc2[i][j]);
        if (eg == 0) {
#pragma unroll
          for (int i = 0; i < 4; ++i) uacc[i] += kk[i];
        }
        if (m4 == 0) {
          vsum[0] += vv[0]; vsum[1] += vv[1]; vsum[2] += vv[2]; vsum[3] += vv[3];
        }
      }
    }
    {
      float* Ub = ws + OFF_U + ((size_t)bh * 272 + 256 + m4 * 4) * 64 + eg * 4;
#pragma unroll
      for (int i = 0; i < 4; ++i)
#pragma unroll
        for (int j = 0; j < 4; ++j) atomicAdd(Ub + (size_t)i * 64 + j, acc2[i][j]);
      if (eg == 0) {
#pragma unroll
        for (int i = 0; i < 4; ++i)
          atomicAdd(ws + OFF_u + (size_t)bh * 272 + 256 + m4 * 4 + i, uacc[i]);
      }
      if (m4 == 0) {
#pragma unroll
        for (int j = 0; j < 4; ++j)
          atomicAdd(ws + OFF_SV + bh * 64 + eg * 4 + j, vsum[j]);
      }
    }
#pragma unroll
    for (int o = 32; o > 0; o >>= 1) smax = fmaxf(smax, __shfl_xor(smax, o));
    if (lane == 0) redb[wv] = smax;
    __syncthreads();
    if (t == 0) {
      const float m = fmaxf(fmaxf(redb[0], redb[1]), fmaxf(redb[2], redb[3]));
      atomicMax((unsigned*)(ws + OFF_S), fenc(m));
    }
    return;
  }

  // =================== main path: m-block mb, m in [0,256) ===================
  const int mq = t & 15, rg = t >> 4;          // GEMM1: 16 m-quads x 16 row-groups(4)
  const int mo = t & 7, eo = (t >> 3) & 7;     // GEMM2: 8 m-octs x 8 e-octs
  const int rs = t >> 6;                       // GEMM2: n quarter (= wave id)

  // stage PTs[td 64][m 64] once (invariant over sc)
#pragma unroll
  for (int c = 0; c < 4; ++c) {
    const int f4 = c * 256 + t;
    const int td = f4 >> 4, mi = f4 & 15;
    *(float4*)(PTs + td * 64 + mi * 4) =
        *(const float4*)(ws + OFF_PT + (size_t)td * 272 + mb * 64 + mi * 4);
  }

  float acc2[8][8];
#pragma unroll
  for (int i = 0; i < 8; ++i)
#pragma unroll
    for (int j = 0; j < 8; ++j) acc2[i][j] = 0.f;
  float uacc[8] = {0, 0, 0, 0, 0, 0, 0, 0};
  float smax = -INFINITY;

  for (int sc = 0; sc < 16; ++sc) {
    const float* kgp = kg + base + (size_t)sc * 64 * 64;
    const float* vgp = vg + base + (size_t)sc * 64 * 64;
    __syncthreads(); // previous iter's LDS reads complete (also covers PTs staging)
    {
      const int r0 = wv * 16;
#pragma unroll
      for (int r = 0; r < 16; ++r) glds4(kgp + (r0 + r) * 64 + lane, kS + (r0 + r) * 68);
#pragma unroll
      for (int r4 = 0; r4 < 4; ++r4)
        glds16(vgp + (r0 + r4 * 4) * 64 + lane * 4, vS + (r0 + r4 * 4) * 64);
    }
    __syncthreads(); // staged (vmcnt drained by barrier)
    // diag pre-phase: row t>>2, quarter t&3
    {
      const int dr = t >> 2, dq = t & 3;
      const float4 s0 = *(const float4*)(kS + dr * 68 + dq * 16);
      const float4 s1 = *(const float4*)(kS + dr * 68 + dq * 16 + 4);
      const float4 s2 = *(const float4*)(kS + dr * 68 + dq * 16 + 8);
      const float4 s3 = *(const float4*)(kS + dr * 68 + dq * 16 + 12);
      float s = s0.x * s0.x;
      s = fmaf(s0.y, s0.y, s); s = fmaf(s0.z, s0.z, s); s = fmaf(s0.w, s0.w, s);
      s = fmaf(s1.x, s1.x, s); s = fmaf(s1.y, s1.y, s); s = fmaf(s1.z, s1.z, s);
      s = fmaf(s1.w, s1.w, s);
      s = fmaf(s2.x, s2.x, s); s = fmaf(s2.y, s2.y, s); s = fmaf(s2.z, s2.z, s);
      s = fmaf(s2.w, s2.w, s);
      s = fmaf(s3.x, s3.x, s); s = fmaf(s3.y, s3.y, s); s = fmaf(s3.z, s3.z, s);
      s = fmaf(s3.w, s3.w, s);
      s += __shfl_xor(s, 1);
      s += __shfl_xor(s, 2);
      if (dq == 0) diagS[dr] = s * DIAG_SCALE;
    }
    __syncthreads(); // diagS ready

    // GEMM1: kd[rows 4][m 4]
    float a1[4][4];
#pragma unroll
    for (int i = 0; i < 4; ++i) { a1[i][0] = a1[i][1] = a1[i][2] = a1[i][3] = 0.f; }
#pragma unroll
    for (int tb = 0; tb < 16; ++tb) {
      const int td = tb * 4;
      const float4 kA = *(const float4*)(kS + (rg * 4 + 0) * 68 + td);
      const float4 kB = *(const float4*)(kS + (rg * 4 + 1) * 68 + td);
      const float4 kC = *(const float4*)(kS + (rg * 4 + 2) * 68 + td);
      const float4 kD = *(const float4*)(kS + (rg * 4 + 3) * 68 + td);
      const float4 p0 = *(const float4*)(PTs + (td + 0) * 64 + mq * 4);
      const float4 p1 = *(const float4*)(PTs + (td + 1) * 64 + mq * 4);
      const float4 p2 = *(const float4*)(PTs + (td + 2) * 64 + mq * 4);
      const float4 p3 = *(const float4*)(PTs + (td + 3) * 64 + mq * 4);
      KQ_ROW(a1[0], kA, p0, p1, p2, p3);
      KQ_ROW(a1[1], kB, p0, p1, p2, p3);
      KQ_ROW(a1[2], kC, p0, p1, p2, p3);
      KQ_ROW(a1[3], kD, p0, p1, p2, p3);
    }
    // smax on raw kd, then exp in-place
#pragma unroll
    for (int i = 0; i < 4; ++i) {
      const float dg = diagS[rg * 4 + i];
      smax = fmaxf(smax, fmaxf(fmaxf(a1[i][0], a1[i][1]), fmaxf(a1[i][2], a1[i][3])));
      a1[i][0] = __expf(a1[i][0] - dg);
      a1[i][1] = __expf(a1[i][1] - dg);
      a1[i][2] = __expf(a1[i][2] - dg);
      a1[i][3] = __expf(a1[i][3] - dg);
    }
    __syncthreads(); // all kS reads done -> overwrite with kp
#pragma unroll
    for (int i = 0; i < 4; ++i) {
      float4 st;
      st.x = a1[i][0]; st.y = a1[i][1]; st.z = a1[i][2]; st.w = a1[i][3];
      *(float4*)(kS + (rg * 4 + i) * 68 + mq * 4) = st; // kp[row][m] stride 68
    }
    __syncthreads(); // kp ready
    // GEMM2: U_partial[8m][8e] += kp^T * v (n split by wave)
#pragma unroll 2
    for (int nn = 0; nn < 16; ++nn) {
      const int n = rs * 16 + nn;
      const float4 ka = *(const float4*)(kS + n * 68 + mo * 8);
      const float4 kb = *(const float4*)(kS + n * 68 + mo * 8 + 4);
      const float4 va = *(const float4*)(vS + n * 64 + eo * 8);
      const float4 vb = *(const float4*)(vS + n * 64 + eo * 8 + 4);
      const float kk[8] = {ka.x, ka.y, ka.z, ka.w, kb.x, kb.y, kb.z, kb.w};
      const float vv[8] = {va.x, va.y, va.z, va.w, vb.x, vb.y, vb.z, vb.w};
#pragma unroll
      for (int i = 0; i < 8; ++i)
#pragma unroll
        for (int j = 0; j < 8; ++j) acc2[i][j] = fmaf(kk[i], vv[j], acc2[i][j]);
      if (eo == 0) {
#pragma unroll
        for (int i = 0; i < 8; ++i) uacc[i] += kk[i];
      }
    }
  }

  // ---- epilogue: fold 4 waves' acc2 in LDS, then line-coalesced atomics ----
  __syncthreads(); // all GEMM2 reads done; kS/vS/PTs free as scratch
  {
    float* FA = vS;  // fold scratch [accidx 64][lane 64]
    float* FB = PTs; // fold scratch [accidx 64][lane 64]
    if (wv == 1) {
#pragma unroll
      for (int i = 0; i < 8; ++i)
#pragma unroll
        for (int j = 0; j < 8; ++j) FA[(i * 8 + j) * 64 + lane] = acc2[i][j];
    }
    if (wv == 3) {
#pragma unroll
      for (int i = 0; i < 8; ++i)
#pragma unroll
        for (int j = 0; j < 8; ++j) FB[(i * 8 + j) * 64 + lane] = acc2[i][j];
    }
    __syncthreads();
    if (wv == 0) {
#pragma unroll
      for (int i = 0; i < 8; ++i)
#pragma unroll
        for (int j = 0; j < 8; ++j) acc2[i][j] += FA[(i * 8 + j) * 64 + lane];
    }
    if (wv == 2) {
#pragma unroll
      for (int i = 0; i < 8; ++i)
#pragma unroll
        for (int j = 0; j < 8; ++j) acc2[i][j] += FB[(i * 8 + j) * 64 + lane];
    }
    __syncthreads();
    if (wv == 2) {
#pragma unroll
      for (int i = 0; i < 8; ++i)
#pragma unroll
        for (int j = 0; j < 8; ++j) FA[(i * 8 + j) * 64 + lane] = acc2[i][j];
    }
    __syncthreads();
    if (wv == 0) {
      // final sums -> U-layout padded [row 64][65] in kS (row = mo*8+i, e = eo*8+j)
      const int mo8 = (lane & 7) * 8, eo8 = (lane >> 3) * 8;
#pragma unroll
      for (int i = 0; i < 8; ++i)
#pragma unroll
        for (int j = 0; j < 8; ++j) {
          acc2[i][j] += FA[(i * 8 + j) * 64 + lane];
          kS[(mo8 + i) * 65 + eo8 + j] = acc2[i][j];
        }
    }
    __syncthreads();
    // line-coalesced atomics: each wave handles 16 contiguous U rows
    {
      float* Ub = ws + OFF_U + ((size_t)bh * 272 + mb * 64) * 64;
#pragma unroll
      for (int r = 0; r < 16; ++r) {
        const int row = wv * 16 + r;
        atomicAdd(Ub + (size_t)row * 64 + lane, kS[row * 65 + lane]);
      }
    }
    if (eo == 0) {
#pragma unroll
      for (int i = 0; i < 8; ++i)
        atomicAdd(ws + OFF_u + (size_t)bh * 272 + mb * 64 + mo * 8 + i, uacc[i]);
    }
  }
#pragma unroll
  for (int o = 32; o > 0; o >>= 1) smax = fmaxf(smax, __shfl_xor(smax, o));
  if (lane == 0) redb[wv] = smax;
  __syncthreads();
  if (t == 0) {
    const float m = fmaxf(fmaxf(redb[0], redb[1]), fmaxf(redb[2], redb[3]));
    atomicMax((unsigned*)(ws + OFF_S), fenc(m));
  }
}

// --------------------------- K3: combine -> ctx_ext, Sc, Sk -----------------
__global__ __launch_bounds__(256) void combine_kernel(float* __restrict__ ws) {
  __shared__ float red[256];
  const int t = threadIdx.x;
  const int bh = blockIdx.x;
  const float S = fdec(((unsigned*)(ws + OFF_S))[0]);
  const float es = __expf(-S);
  const int e = t & 63, mr = t >> 6;
  const float svv = ws[OFF_SV + bh * 64 + e];
  float scp = 0.f;
  for (int mm = mr; mm < 272; mm += 4) {
    float val = 0.f;
    if (mm < 266)
      val = (es * ws[OFF_U + ((size_t)bh * 272 + mm) * 64 + e] + EPSV * svv) * INV_L;
    ws[OFF_CTX + ((size_t)bh * 272 + mm) * 68 + e] = val;
    scp += val;
  }
  red[t] = scp;
  __syncthreads();
  if (t < 64) ws[OFF_SC + bh * 64 + t] = red[t] + red[t + 64] + red[t + 128] + red[t + 192];
  __syncthreads();
  float skp = 0.f;
  for (int mm = t; mm < 272; mm += 256) {
    float km = 0.f;
    if (mm < 266) km = es * ws[OFF_u + (size_t)bh * 272 + mm] * INV_L + EPSV;
    float* cx = ws + OFF_CTX + ((size_t)bh * 272 + mm) * 68;
    cx[64] = km; cx[65] = 0.f; cx[66] = 0.f; cx[67] = 0.f;
    skp += km;
  }
  red[t] = skp;
  __syncthreads();
  for (int s = 128; s > 0; s >>= 1) {
    if (t < s) red[t] += red[t + s];
    __syncthreads();
  }
  if (t == 0) ws[OFF_SK + bh] = red[0];
}

// --------------------------- K4: q-pass -> out ------------------------------
// LDS: uni = qS[32][68] + PTt[64][16]@2176 during GEMM1, then qph[32][272],
// then reduction scratch for GEMM2.
__global__ __launch_bounds__(256) void pass_q(const float* __restrict__ qg,
                                              float* __restrict__ outg,
                                              const float* __restrict__ ws) {
  __shared__ __align__(16) float uni[8704];
  __shared__ float diagS[32];
  __shared__ unsigned rmx[32];
  __shared__ float Bl[32];

  const int t = threadIdx.x;
  const int nt = blockIdx.x, bh = blockIdx.y;
  const int lane = t & 63, wv = t >> 6;
  const float* qgp = qg + ((size_t)bh * 4096 + (size_t)nt * 32) * 64;

  if (t < 32) rmx[t] = 0x007FFFFFu; // enc(-inf)

  // stage qS[32][68] via GLDS (rows wv*8..wv*8+7); qS occupies uni[0..2172)
#pragma unroll
  for (int r = 0; r < 8; ++r)
    glds4(qgp + (wv * 8 + r) * 64 + lane, uni + (wv * 8 + r) * 68);
  // stage tail PT[64][16] into uni[2176..3200)
  {
    const int td = t >> 2, j4 = t & 3;
    *(float4*)(uni + 2176 + td * 16 + j4 * 4) =
        *(const float4*)(ws + OFF_PT + (size_t)td * 272 + 256 + j4 * 4);
  }
  __syncthreads();

  // diag pre-phase: row t>>3 (32 rows), eighth t&7
  {
    const int dr = t >> 3, d8 = t & 7;
    const float4 s0 = *(const float4*)(uni + dr * 68 + d8 * 8);
    const float4 s1 = *(const float4*)(uni + dr * 68 + d8 * 8 + 4);
    float s = s0.x * s0.x;
    s = fmaf(s0.y, s0.y, s); s = fmaf(s0.z, s0.z, s); s = fmaf(s0.w, s0.w, s);
    s = fmaf(s1.x, s1.x, s); s = fmaf(s1.y, s1.y, s); s = fmaf(s1.z, s1.z, s);
    s = fmaf(s1.w, s1.w, s);
    s += __shfl_xor(s, 1);
    s += __shfl_xor(s, 2);
    s += __shfl_xor(s, 4);
    if (d8 == 0) diagS[dr] = s * DIAG_SCALE;
  }
  __syncthreads();

  // GEMM1 main: mq = lane (64 m-quads, m<256); rows wv*8..+7; PT ring-2 (8 rows)
  const int mq = t & 63;
  float a1[8][4];
#pragma unroll
  for (int i = 0; i < 8; ++i) { a1[i][0] = a1[i][1] = a1[i][2] = a1[i][3] = 0.f; }
  {
    const float* ptm = ws + OFF_PT + mq * 4;
    float4 pfA0, pfA1, pfA2, pfA3, pfB0, pfB1, pfB2, pfB3;
    pfA0 = *(const float4*)(ptm + (size_t)0 * 272);
    pfA1 = *(const float4*)(ptm + (size_t)1 * 272);
    pfA2 = *(const float4*)(ptm + (size_t)2 * 272);
    pfA3 = *(const float4*)(ptm + (size_t)3 * 272);
    pfB0 = *(const float4*)(ptm + (size_t)4 * 272);
    pfB1 = *(const float4*)(ptm + (size_t)5 * 272);
    pfB2 = *(const float4*)(ptm + (size_t)6 * 272);
    pfB3 = *(const float4*)(ptm + (size_t)7 * 272);
#pragma unroll
    for (int tb = 0; tb < 16; tb += 2) {
      {
        const int td = tb * 4;
#pragma unroll
        for (int i = 0; i < 8; ++i) {
          const float4 q4 = *(const float4*)(uni + (wv * 8 + i) * 68 + td);
          KQ_ROW(a1[i], q4, pfA0, pfA1, pfA2, pfA3);
        }
        if (tb < 14) {
          pfA0 = *(const float4*)(ptm + (size_t)(td + 8) * 272);
          pfA1 = *(const float4*)(ptm + (size_t)(td + 9) * 272);
          pfA2 = *(const float4*)(ptm + (size_t)(td + 10) * 272);
          pfA3 = *(const float4*)(ptm + (size_t)(td + 11) * 272);
        }
      }
      {
        const int td = tb * 4 + 4;
#pragma unroll
        for (int i = 0; i < 8; ++i) {
          const float4 q4 = *(const float4*)(uni + (wv * 8 + i) * 68 + td);
          KQ_ROW(a1[i], q4, pfB0, pfB1, pfB2, pfB3);
        }
        if (tb < 14) {
          pfB0 = *(const float4*)(ptm + (size_t)(td + 8) * 272);
          pfB1 = *(const float4*)(ptm + (size_t)(td + 9) * 272);
          pfB2 = *(const float4*)(ptm + (size_t)(td + 10) * 272);
          pfB3 = *(const float4*)(ptm + (size_t)(td + 11) * 272);
        }
      }
    }
  }
  // GEMM1 tail: m_t = 256 + (t&15), rows r2, r2+1; PTt from LDS
  float at[2] = {0.f, 0.f};
  const int mtl = t & 15;
  const int mt = 256 + mtl;
  const int r2 = (t >> 4) * 2;
  {
    const float* pts = uni + 2176 + mtl;
#pragma unroll
    for (int tb = 0; tb < 16; ++tb) {
      const int td = tb * 4;
      const float4 qx4 = *(const float4*)(uni + r2 * 68 + td);
      const float4 qy4 = *(const float4*)(uni + (r2 + 1) * 68 + td);
      const float p0 = pts[(td + 0) * 16];
      const float p1 = pts[(td + 1) * 16];
      const float p2 = pts[(td + 2) * 16];
      const float p3 = pts[(td + 3) * 16];
      at[0] = fmaf(qx4.x, p0, at[0]);
      at[0] = fmaf(qx4.y, p1, at[0]);
      at[0] = fmaf(qx4.z, p2, at[0]);
      at[0] = fmaf(qx4.w, p3, at[0]);
      at[1] = fmaf(qy4.x, p0, at[1]);
      at[1] = fmaf(qy4.y, p1, at[1]);
      at[1] = fmaf(qy4.z, p2, at[1]);
      at[1] = fmaf(qy4.w, p3, at[1]);
    }
  }
  __syncthreads(); // all qS/PTt reads complete -> uni can be rewritten as qph

  // rowmax (raw qd): main butterfly + tail group-reduce, into LDS atomicMax
#pragma unroll
  for (int i = 0; i < 8; ++i) {
    float lm = fmaxf(fmaxf(a1[i][0], a1[i][1]), fmaxf(a1[i][2], a1[i][3]));
#pragma unroll
    for (int o = 32; o > 0; o >>= 1) lm = fmaxf(lm, __shfl_xor(lm, o));
    if (lane == i) atomicMax(&rmx[wv * 8 + i], fenc(lm));
  }
#pragma unroll
  for (int s = 0; s < 2; ++s) {
    float v = (mt < 266) ? at[s] : -INFINITY;
#pragma unroll
    for (int o = 8; o > 0; o >>= 1) v = fmaxf(v, __shfl_xor(v, o));
    if ((t & 15) == 0) atomicMax(&rmx[r2 + s], fenc(v));
  }
  // exp (unstabilized, diag from LDS) + store qph (stride 272)
#pragma unroll
  for (int i = 0; i < 8; ++i) {
    const int row = wv * 8 + i;
    const float dg = diagS[row];
    float4 st;
    st.x = __expf(a1[i][0] - dg);
    st.y = __expf(a1[i][1] - dg);
    st.z = __expf(a1[i][2] - dg);
    st.w = __expf(a1[i][3] - dg);
    *(float4*)(uni + row * 272 + mq * 4) = st;
  }
#pragma unroll
  for (int s = 0; s < 2; ++s) {
    const int row = r2 + s;
    uni[row * 272 + mt] = (mt < 266) ? __expf(at[s] - diagS[row]) : 0.f;
  }
  __syncthreads();

  // GEMM2: 4 rows x 4 cols x m-split(2). cq2 = e-quad, rg2 = 4-row group,
  // ms = m-half. ctx streamed from global (L2-resident) with ring-1 prefetch.
  const int cq2 = t & 15, rg2 = (t >> 4) & 7, ms = t >> 7;
  const float* ctxg = ws + OFF_CTX + (size_t)bh * 272 * 68;
  const float* crow = ctxg + cq2 * 4;
  const int mb0 = ms * 136;
  float acc[4][4];
#pragma unroll
  for (int i = 0; i < 4; ++i) { acc[i][0] = acc[i][1] = acc[i][2] = acc[i][3] = 0.f; }
  float accB[4] = {0, 0, 0, 0};
  float4 c0, c1, c2, c3, n0, n1, n2, n3;
  float cb0 = 0, cb1 = 0, cb2 = 0, cb3 = 0, nb0 = 0, nb1 = 0, nb2 = 0, nb3 = 0;
  c0 = *(const float4*)(crow + (size_t)(mb0 + 0) * 68);
  c1 = *(const float4*)(crow + (size_t)(mb0 + 1) * 68);
  c2 = *(const float4*)(crow + (size_t)(mb0 + 2) * 68);
  c3 = *(const float4*)(crow + (size_t)(mb0 + 3) * 68);
  if (cq2 == 0) {
    cb0 = ctxg[(size_t)(mb0 + 0) * 68 + 64];
    cb1 = ctxg[(size_t)(mb0 + 1) * 68 + 64];
    cb2 = ctxg[(size_t)(mb0 + 2) * 68 + 64];
    cb3 = ctxg[(size_t)(mb0 + 3) * 68 + 64];
  }
  for (int mc = 0; mc < 34; ++mc) {
    const int mm = mb0 + mc * 4;
    if (mc < 33) {
      n0 = *(const float4*)(crow + (size_t)(mm + 4) * 68);
      n1 = *(const float4*)(crow + (size_t)(mm + 5) * 68);
      n2 = *(const float4*)(crow + (size_t)(mm + 6) * 68);
      n3 = *(const float4*)(crow + (size_t)(mm + 7) * 68);
      if (cq2 == 0) {
        nb0 = ctxg[(size_t)(mm + 4) * 68 + 64];
        nb1 = ctxg[(size_t)(mm + 5) * 68 + 64];
        nb2 = ctxg[(size_t)(mm + 6) * 68 + 64];
        nb3 = ctxg[(size_t)(mm + 7) * 68 + 64];
      }
    }
    const float4 q0 = *(const float4*)(uni + (rg2 * 4 + 0) * 272 + mm);
    const float4 q1 = *(const float4*)(uni + (rg2 * 4 + 1) * 272 + mm);
    const float4 q2 = *(const float4*)(uni + (rg2 * 4 + 2) * 272 + mm);
    const float4 q3 = *(const float4*)(uni + (rg2 * 4 + 3) * 272 + mm);
    QC_ROW(acc[0], q0, c0, c1, c2, c3);
    QC_ROW(acc[1], q1, c0, c1, c2, c3);
    QC_ROW(acc[2], q2, c0, c1, c2, c3);
    QC_ROW(acc[3], q3, c0, c1, c2, c3);
    if (cq2 == 0) {
      accB[0] = fmaf(q0.x, cb0, accB[0]);
      accB[0] = fmaf(q0.y, cb1, accB[0]);
      accB[0] = fmaf(q0.z, cb2, accB[0]);
      accB[0] = fmaf(q0.w, cb3, accB[0]);
      accB[1] = fmaf(q1.x, cb0, accB[1]);
      accB[1] = fmaf(q1.y, cb1, accB[1]);
      accB[1] = fmaf(q1.z, cb2, accB[1]);
      accB[1] = fmaf(q1.w, cb3, accB[1]);
      accB[2] = fmaf(q2.x, cb0, accB[2]);
      accB[2] = fmaf(q2.y, cb1, accB[2]);
      accB[2] = fmaf(q2.z, cb2, accB[2]);
      accB[2] = fmaf(q2.w, cb3, accB[2]);
      accB[3] = fmaf(q3.x, cb0, accB[3]);
      accB[3] = fmaf(q3.y, cb1, accB[3]);
      accB[3] = fmaf(q3.z, cb2, accB[3]);
      accB[3] = fmaf(q3.w, cb3, accB[3]);
    }
    if (mc < 33) {
      c0 = n0; c1 = n1; c2 = n2; c3 = n3;
      cb0 = nb0; cb1 = nb1; cb2 = nb2; cb3 = nb3;
    }
  }

  // reduce the two m-halves through LDS (qph dead now), stride-1 layout
  __syncthreads(); // all qph reads complete
  if (ms == 1) {
    const int p = t - 128;
#pragma unroll
    for (int i = 0; i < 4; ++i)
#pragma unroll
      for (int j = 0; j < 4; ++j) uni[(i * 4 + j) * 128 + p] = acc[i][j];
    if (cq2 == 0) {
#pragma unroll
      for (int i = 0; i < 4; ++i) uni[2048 + rg2 * 4 + i] = accB[i];
    }
  }
  __syncthreads();
  if (ms == 0) {
#pragma unroll
    for (int i = 0; i < 4; ++i)
#pragma unroll
      for (int j = 0; j < 4; ++j) acc[i][j] += uni[(i * 4 + j) * 128 + t];
    if (cq2 == 0) {
#pragma unroll
      for (int i = 0; i < 4; ++i) Bl[rg2 * 4 + i] = accB[i] + uni[2048 + rg2 * 4 + i];
    }
  }
  __syncthreads(); // Bl ready

  if (ms == 0) {
    const float4 sc4 = *(const float4*)(ws + OFF_SC + bh * 64 + cq2 * 4);
    const float skv = ws[OFF_SK + bh];
    float* op = outg + ((size_t)bh * 4096 + (size_t)nt * 32) * 64;
#pragma unroll
    for (int i = 0; i < 4; ++i) {
      const int row = rg2 * 4 + i;
      const float rm = fdec(rmx[row]);
      const float tt = EPSV * __expf(rm);
      const float inv = 1.0f / (Bl[row] + tt * skv);
      float4 o;
      o.x = (acc[i][0] + tt * sc4.x) * inv;
      o.y = (acc[i][1] + tt * sc4.y) * inv;
      o.z = (acc[i][2] + tt * sc4.z) * inv;
      o.w = (acc[i][3] + tt * sc4.w) * inv;
      *(float4*)(op + row * 64 + cq2 * 4) = o;
    }
  }
}

// --------------------------- launch -----------------------------------------
extern "C" void kernel_launch(void* const* d_in, const int* in_sizes, int n_in,
                              void* d_out, int out_size, void* d_ws, size_t ws_size,
                              hipStream_t stream) {
  (void)in_sizes; (void)n_in; (void)out_size; (void)ws_size;
  const float* q = (const float*)d_in[0];
  const float* k = (const float*)d_in[1];
  const float* v = (const float*)d_in[2];
  const float* P = (const float*)d_in[3];
  float* out = (float*)d_out;
  float* ws = (float*)d_ws;

  // zero only the accumulated region [OFF_U, OFF_CTX)
  hipMemsetAsync((void*)(ws + OFF_U), 0, (OFF_CTX - OFF_U) * sizeof(float), stream);
  setup_kernel<<<68, 256, 0, stream>>>(P, ws);
  pass_k_fused<<<dim3(5, 32, 4), 256, 0, stream>>>(k, v, ws);
  combine_kernel<<<32, 256, 0, stream>>>(ws);
  pass_q<<<dim3(128, 32), 256, 0, stream>>>(q, out, ws);
}